// Round 1
// baseline (2727.585 us; speedup 1.0000x reference)
//
#include <hip/hip_runtime.h>
#include <cstddef>

#define D_M 1024
#define NH 16
#define HD 64
#define FFD 4096
#define SQ 2048
#define BB 2
#define TOK (BB*SQ)   // 4096
#define EPS 1e-5f

// ---------------- reductions ----------------
__device__ inline float wave_max(float v) {
  #pragma unroll
  for (int m = 32; m >= 1; m >>= 1) v = fmaxf(v, __shfl_xor(v, m));
  return v;
}
__device__ inline float wave_sum(float v) {
  #pragma unroll
  for (int m = 32; m >= 1; m >>= 1) v += __shfl_xor(v, m);
  return v;
}

// ---------------- generic GEMM + bias: C[M,N] = A[M,K]@W[K,N] + b ----------------
// tile 64x64, BK=16, 256 threads, 4x4 per thread. All dims multiples of 64/16.
__global__ __launch_bounds__(256)
void gemm_bias_kernel(const float* __restrict__ A, const float* __restrict__ W,
                      const float* __restrict__ bias, float* __restrict__ C,
                      int M, int N, int K) {
  __shared__ float AsT[16][68];   // [k][m]
  __shared__ float Ws[16][68];    // [k][n]
  const int tid = threadIdx.x;
  const int tx = tid & 15, ty = tid >> 4;
  const int bm = blockIdx.x * 64, bn = blockIdx.y * 64;

  float acc[4][4] = {};
  for (int k0 = 0; k0 < K; k0 += 16) {
    // A tile 64x16 -> transposed
    {
      const int r = tid >> 2, c4 = (tid & 3) * 4;
      float4 t = *(const float4*)&A[(size_t)(bm + r) * K + k0 + c4];
      AsT[c4 + 0][r] = t.x; AsT[c4 + 1][r] = t.y;
      AsT[c4 + 2][r] = t.z; AsT[c4 + 3][r] = t.w;
    }
    // W tile 16x64 direct
    {
      const int kr = tid >> 4, nc = (tid & 15) * 4;
      float4 t = *(const float4*)&W[(size_t)(k0 + kr) * N + bn + nc];
      *(float4*)&Ws[kr][nc] = t;
    }
    __syncthreads();
    #pragma unroll
    for (int kk = 0; kk < 16; ++kk) {
      float4 a = *(float4*)&AsT[kk][ty * 4];
      float4 w = *(float4*)&Ws[kk][tx * 4];
      const float av[4] = {a.x, a.y, a.z, a.w};
      const float wv[4] = {w.x, w.y, w.z, w.w};
      #pragma unroll
      for (int i = 0; i < 4; ++i)
        #pragma unroll
        for (int j = 0; j < 4; ++j) acc[i][j] += av[i] * wv[j];
    }
    __syncthreads();
  }
  const float4 bv = *(const float4*)&bias[bn + tx * 4];
  #pragma unroll
  for (int i = 0; i < 4; ++i) {
    float4 o = {acc[i][0] + bv.x, acc[i][1] + bv.y, acc[i][2] + bv.z, acc[i][3] + bv.w};
    *(float4*)&C[(size_t)(bm + ty * 4 + i) * N + bn + tx * 4] = o;
  }
}

// ---------------- scores: attn_raw[b,h,q,k] = (q . k) / 8 ----------------
__global__ __launch_bounds__(256)
void scores_kernel(const float* __restrict__ q, const float* __restrict__ k,
                   float* __restrict__ attn) {
  __shared__ float Qs[64][68];   // [d][m]
  __shared__ float Ks[64][68];   // [d][n]
  const int tid = threadIdx.x;
  const int tx = tid & 15, ty = tid >> 4;
  const int bh = blockIdx.z;            // b*16 + h
  const int b = bh >> 4, h = bh & 15;
  const int m0 = blockIdx.x * 64, n0 = blockIdx.y * 64;

  {
    const int r = tid >> 2, cb = (tid & 3) * 4;
    #pragma unroll
    for (int cc = 0; cc < 4; ++cc) {
      const int c = cb + cc * 16;
      float4 t = *(const float4*)&q[(size_t)(b * SQ + m0 + r) * D_M + h * HD + c];
      Qs[c + 0][r] = t.x; Qs[c + 1][r] = t.y; Qs[c + 2][r] = t.z; Qs[c + 3][r] = t.w;
      float4 u = *(const float4*)&k[(size_t)(b * SQ + n0 + r) * D_M + h * HD + c];
      Ks[c + 0][r] = u.x; Ks[c + 1][r] = u.y; Ks[c + 2][r] = u.z; Ks[c + 3][r] = u.w;
    }
  }
  __syncthreads();
  float acc[4][4] = {};
  #pragma unroll
  for (int d = 0; d < 64; ++d) {
    float4 a = *(float4*)&Qs[d][ty * 4];
    float4 w = *(float4*)&Ks[d][tx * 4];
    const float av[4] = {a.x, a.y, a.z, a.w};
    const float wv[4] = {w.x, w.y, w.z, w.w};
    #pragma unroll
    for (int i = 0; i < 4; ++i)
      #pragma unroll
      for (int j = 0; j < 4; ++j) acc[i][j] += av[i] * wv[j];
  }
  const float scale = 0.125f;  // 1/sqrt(64)
  #pragma unroll
  for (int i = 0; i < 4; ++i) {
    float4 o = {acc[i][0] * scale, acc[i][1] * scale, acc[i][2] * scale, acc[i][3] * scale};
    *(float4*)&attn[((size_t)bh * SQ + m0 + ty * 4 + i) * SQ + n0 + tx * 4] = o;
  }
}

// ---------------- softmax in place over rows of length SQ ----------------
__global__ __launch_bounds__(256)
void softmax_kernel(float* __restrict__ attn) {
  const size_t row = blockIdx.x;
  float* p = attn + row * (size_t)SQ;
  const int tid = threadIdx.x;
  __shared__ float redm[4];
  __shared__ float reds[4];

  float4 a = ((float4*)p)[tid];
  float4 b = ((float4*)p)[tid + 256];
  float mx = fmaxf(fmaxf(fmaxf(a.x, a.y), fmaxf(a.z, a.w)),
                   fmaxf(fmaxf(b.x, b.y), fmaxf(b.z, b.w)));
  mx = wave_max(mx);
  if ((tid & 63) == 0) redm[tid >> 6] = mx;
  __syncthreads();
  mx = fmaxf(fmaxf(redm[0], redm[1]), fmaxf(redm[2], redm[3]));

  a.x = __expf(a.x - mx); a.y = __expf(a.y - mx); a.z = __expf(a.z - mx); a.w = __expf(a.w - mx);
  b.x = __expf(b.x - mx); b.y = __expf(b.y - mx); b.z = __expf(b.z - mx); b.w = __expf(b.w - mx);
  float s = a.x + a.y + a.z + a.w + b.x + b.y + b.z + b.w;
  s = wave_sum(s);
  if ((tid & 63) == 0) reds[tid >> 6] = s;
  __syncthreads();
  s = reds[0] + reds[1] + reds[2] + reds[3];
  const float inv = 1.0f / s;
  a.x *= inv; a.y *= inv; a.z *= inv; a.w *= inv;
  b.x *= inv; b.y *= inv; b.z *= inv; b.w *= inv;
  ((float4*)p)[tid] = a;
  ((float4*)p)[tid + 256] = b;
}

// ---------------- ctx[b,q,h,:] = attn_row @ V ----------------
__global__ __launch_bounds__(256)
void ctx_kernel(const float* __restrict__ attn, const float* __restrict__ v,
                float* __restrict__ ctx) {
  __shared__ float AtT[64][68];  // [k][m]
  __shared__ float Vt[64][68];   // [k][d]
  const int tid = threadIdx.x;
  const int tx = tid & 15, ty = tid >> 4;
  const int bh = blockIdx.y;
  const int b = bh >> 4, h = bh & 15;
  const int m0 = blockIdx.x * 64;

  float acc[4][4] = {};
  for (int k0 = 0; k0 < SQ; k0 += 64) {
    {
      const int r = tid >> 2, cb = (tid & 3) * 4;
      #pragma unroll
      for (int cc = 0; cc < 4; ++cc) {
        const int c = cb + cc * 16;
        float4 t = *(const float4*)&attn[((size_t)bh * SQ + m0 + r) * SQ + k0 + c];
        AtT[c + 0][r] = t.x; AtT[c + 1][r] = t.y; AtT[c + 2][r] = t.z; AtT[c + 3][r] = t.w;
        float4 u = *(const float4*)&v[(size_t)(b * SQ + k0 + r) * D_M + h * HD + c];
        Vt[r][c + 0] = u.x; Vt[r][c + 1] = u.y; Vt[r][c + 2] = u.z; Vt[r][c + 3] = u.w;
      }
    }
    __syncthreads();
    #pragma unroll
    for (int kk = 0; kk < 64; ++kk) {
      float4 a = *(float4*)&AtT[kk][ty * 4];
      float4 w = *(float4*)&Vt[kk][tx * 4];
      const float av[4] = {a.x, a.y, a.z, a.w};
      const float wv[4] = {w.x, w.y, w.z, w.w};
      #pragma unroll
      for (int i = 0; i < 4; ++i)
        #pragma unroll
        for (int j = 0; j < 4; ++j) acc[i][j] += av[i] * wv[j];
    }
    __syncthreads();
  }
  #pragma unroll
  for (int i = 0; i < 4; ++i) {
    float4 o = {acc[i][0], acc[i][1], acc[i][2], acc[i][3]};
    *(float4*)&ctx[(size_t)(b * SQ + m0 + ty * 4 + i) * D_M + h * HD + tx * 4] = o;
  }
}

// ---------------- out = LayerNorm(a + r) * g + be ----------------
__global__ __launch_bounds__(256)
void add_ln_kernel(const float* __restrict__ a, const float* __restrict__ r,
                   const float* __restrict__ g, const float* __restrict__ be,
                   float* __restrict__ out) {
  const size_t row = blockIdx.x;
  const int tid = threadIdx.x;
  __shared__ float red1[4];
  __shared__ float red2[4];

  float4 va = ((const float4*)(a + row * D_M))[tid];
  float4 vr = ((const float4*)(r + row * D_M))[tid];
  float v0 = va.x + vr.x, v1 = va.y + vr.y, v2 = va.z + vr.z, v3 = va.w + vr.w;
  float s = v0 + v1 + v2 + v3;
  float sq = v0 * v0 + v1 * v1 + v2 * v2 + v3 * v3;
  s = wave_sum(s);
  sq = wave_sum(sq);
  if ((tid & 63) == 0) { red1[tid >> 6] = s; red2[tid >> 6] = sq; }
  __syncthreads();
  s = red1[0] + red1[1] + red1[2] + red1[3];
  sq = red2[0] + red2[1] + red2[2] + red2[3];
  const float mu = s * (1.0f / D_M);
  const float var = sq * (1.0f / D_M) - mu * mu;
  float x = var + EPS;
  float rs = rsqrtf(x);
  rs = rs * (1.5f - 0.5f * x * rs * rs);   // one Newton step
  float4 gg = ((const float4*)g)[tid];
  float4 bb = ((const float4*)be)[tid];
  float4 o = {(v0 - mu) * rs * gg.x + bb.x, (v1 - mu) * rs * gg.y + bb.y,
              (v2 - mu) * rs * gg.z + bb.z, (v3 - mu) * rs * gg.w + bb.w};
  ((float4*)(out + row * D_M))[tid] = o;
}

// ---------------- per-head FF: ff = relu(Xh@W1h^T + b1) @ W2h^T + b2 ----------------
__global__ __launch_bounds__(256)
void ff_kernel(const float* __restrict__ x1, const float* __restrict__ W1,
               const float* __restrict__ b1, const float* __restrict__ W2,
               const float* __restrict__ b2, float* __restrict__ ffout) {
  __shared__ float Xs[64][68];   // [d][m]
  __shared__ float W1s[64][68];  // [d][f]
  __shared__ float Hs[64][68];   // [f][m]
  __shared__ float W2s[64][68];  // [f][d]
  const int tid = threadIdx.x;
  const int tx = tid & 15, ty = tid >> 4;
  const int h = blockIdx.y;
  const int m0 = blockIdx.x * 64;

  {
    const int r = tid >> 2, cb = (tid & 3) * 4;
    #pragma unroll
    for (int cc = 0; cc < 4; ++cc) {
      const int c = cb + cc * 16;
      float4 t = *(const float4*)&x1[(size_t)(m0 + r) * D_M + h * HD + c];
      Xs[c + 0][r] = t.x; Xs[c + 1][r] = t.y; Xs[c + 2][r] = t.z; Xs[c + 3][r] = t.w;
    }
  }
  const float* W1h = W1 + (size_t)h * FFD * HD;
  const float* W2h = W2 + (size_t)h * HD * FFD;
  const float* b1h = b1 + (size_t)h * FFD;

  float ffacc[4][4] = {};
  for (int f0 = 0; f0 < FFD; f0 += 64) {
    {
      const int r = tid >> 2, cb = (tid & 3) * 4;
      #pragma unroll
      for (int cc = 0; cc < 4; ++cc) {
        const int c = cb + cc * 16;
        float4 t = *(const float4*)&W1h[(size_t)(f0 + r) * HD + c];
        W1s[c + 0][r] = t.x; W1s[c + 1][r] = t.y; W1s[c + 2][r] = t.z; W1s[c + 3][r] = t.w;
        float4 u = *(const float4*)&W2h[(size_t)r * FFD + f0 + c];
        W2s[c + 0][r] = u.x; W2s[c + 1][r] = u.y; W2s[c + 2][r] = u.z; W2s[c + 3][r] = u.w;
      }
    }
    __syncthreads();
    // phase A: H = relu(X @ W1^T + b1)
    float ha[4][4] = {};
    #pragma unroll
    for (int d = 0; d < 64; ++d) {
      float4 a = *(float4*)&Xs[d][ty * 4];
      float4 w = *(float4*)&W1s[d][tx * 4];
      const float av[4] = {a.x, a.y, a.z, a.w};
      const float wv[4] = {w.x, w.y, w.z, w.w};
      #pragma unroll
      for (int i = 0; i < 4; ++i)
        #pragma unroll
        for (int j = 0; j < 4; ++j) ha[i][j] += av[i] * wv[j];
    }
    {
      const float4 b1v = *(const float4*)&b1h[f0 + tx * 4];
      const float bvv[4] = {b1v.x, b1v.y, b1v.z, b1v.w};
      #pragma unroll
      for (int j = 0; j < 4; ++j)
        #pragma unroll
        for (int i = 0; i < 4; ++i)
          Hs[tx * 4 + j][ty * 4 + i] = fmaxf(ha[i][j] + bvv[j], 0.0f);
    }
    __syncthreads();
    // phase B: ffacc += H @ W2^T
    #pragma unroll
    for (int f = 0; f < 64; ++f) {
      float4 a = *(float4*)&Hs[f][ty * 4];
      float4 w = *(float4*)&W2s[f][tx * 4];
      const float av[4] = {a.x, a.y, a.z, a.w};
      const float wv[4] = {w.x, w.y, w.z, w.w};
      #pragma unroll
      for (int i = 0; i < 4; ++i)
        #pragma unroll
        for (int j = 0; j < 4; ++j) ffacc[i][j] += av[i] * wv[j];
    }
    __syncthreads();
  }
  const float4 b2v = *(const float4*)&b2[h * HD + tx * 4];
  const float bvv[4] = {b2v.x, b2v.y, b2v.z, b2v.w};
  #pragma unroll
  for (int i = 0; i < 4; ++i) {
    float4 o = {ffacc[i][0] + bvv[0], ffacc[i][1] + bvv[1],
                ffacc[i][2] + bvv[2], ffacc[i][3] + bvv[3]};
    *(float4*)&ffout[(size_t)(m0 + ty * 4 + i) * D_M + h * HD + tx * 4] = o;
  }
}

extern "C" void kernel_launch(void* const* d_in, const int* in_sizes, int n_in,
                              void* d_out, int out_size, void* d_ws, size_t ws_size,
                              hipStream_t stream) {
  const float* x   = (const float*)d_in[0];
  const float* Wq  = (const float*)d_in[1];
  const float* bq  = (const float*)d_in[2];
  const float* Wk  = (const float*)d_in[3];
  const float* bk  = (const float*)d_in[4];
  const float* Wv  = (const float*)d_in[5];
  const float* bv  = (const float*)d_in[6];
  const float* Wo  = (const float*)d_in[7];
  const float* bo  = (const float*)d_in[8];
  const float* W1  = (const float*)d_in[9];
  const float* b1  = (const float*)d_in[10];
  const float* W2  = (const float*)d_in[11];
  const float* b2  = (const float*)d_in[12];
  const float* g1  = (const float*)d_in[13];
  const float* be1 = (const float*)d_in[14];
  const float* g2  = (const float*)d_in[15];
  const float* be2 = (const float*)d_in[16];

  float* y_out = (float*)d_out;                       // [TOK, D]
  float* attn  = (float*)d_out + (size_t)TOK * D_M;   // [B,H,S,S]

  float* ws   = (float*)d_ws;
  const size_t NB = (size_t)TOK * D_M;                // 4,194,304
  float* qb   = ws;            // also reused as ff output later
  float* kb   = ws + NB;       // also reused as Wo-proj output later
  float* vb   = ws + 2 * NB;
  float* ctxb = ws + 3 * NB;
  float* x1b  = ws + 4 * NB;

  const dim3 blk(256);

  // QKV projections
  gemm_bias_kernel<<<dim3(TOK / 64, D_M / 64), blk, 0, stream>>>(x, Wq, bq, qb, TOK, D_M, D_M);
  gemm_bias_kernel<<<dim3(TOK / 64, D_M / 64), blk, 0, stream>>>(x, Wk, bk, kb, TOK, D_M, D_M);
  gemm_bias_kernel<<<dim3(TOK / 64, D_M / 64), blk, 0, stream>>>(x, Wv, bv, vb, TOK, D_M, D_M);
  // scores -> attn (raw), softmax in place, ctx
  scores_kernel<<<dim3(SQ / 64, SQ / 64, BB * NH), blk, 0, stream>>>(qb, kb, attn);
  softmax_kernel<<<dim3(BB * NH * SQ), blk, 0, stream>>>(attn);
  ctx_kernel<<<dim3(SQ / 64, BB * NH), blk, 0, stream>>>(attn, vb, ctxb);
  // Wo projection + residual LN -> x1
  gemm_bias_kernel<<<dim3(TOK / 64, D_M / 64), blk, 0, stream>>>(ctxb, Wo, bo, kb, TOK, D_M, D_M);
  add_ln_kernel<<<dim3(TOK), blk, 0, stream>>>(x, kb, g1, be1, x1b);
  // per-head FF -> qb (reuse), then final LN -> y
  ff_kernel<<<dim3(TOK / 64, NH), blk, 0, stream>>>(x1b, W1, b1, W2, b2, qb);
  add_ln_kernel<<<dim3(TOK), blk, 0, stream>>>(x1b, qb, g2, be2, y_out);
}

// Round 3
// 1253.504 us; speedup vs baseline: 2.1760x; 2.1760x over previous
//
#include <hip/hip_runtime.h>
#include <cstddef>

#define D_M 1024
#define NH 16
#define HD 64
#define FFD 4096
#define SQ 2048
#define BB 2
#define TOK (BB*SQ)   // 4096
#define EPS 1e-5f

typedef __attribute__((ext_vector_type(8))) short bf16x8;
typedef __attribute__((ext_vector_type(4))) float f32x4;

__device__ inline unsigned short f32_bf16_rne(float f) {
  unsigned int u = __float_as_uint(f);
  unsigned int r = (u + 0x7fffu + ((u >> 16) & 1u)) >> 16;
  return (unsigned short)r;
}
__device__ inline float bf16_f32(unsigned short h) {
  return __uint_as_float(((unsigned int)h) << 16);
}
__device__ inline void split_f4(float4 v, ushort4& h, ushort4& l) {
  h.x = f32_bf16_rne(v.x); l.x = f32_bf16_rne(v.x - bf16_f32(h.x));
  h.y = f32_bf16_rne(v.y); l.y = f32_bf16_rne(v.y - bf16_f32(h.y));
  h.z = f32_bf16_rne(v.z); l.z = f32_bf16_rne(v.z - bf16_f32(h.z));
  h.w = f32_bf16_rne(v.w); l.w = f32_bf16_rne(v.w - bf16_f32(h.w));
}
__device__ inline void split_f8(float4 a, float4 b, bf16x8& hi, bf16x8& lo) {
  float s[8] = {a.x, a.y, a.z, a.w, b.x, b.y, b.z, b.w};
  #pragma unroll
  for (int i = 0; i < 8; ++i) {
    unsigned short h = f32_bf16_rne(s[i]);
    hi[i] = (short)h;
    lo[i] = (short)f32_bf16_rne(s[i] - bf16_f32(h));
  }
}

// ---------------- reductions ----------------
__device__ inline float wave_max(float v) {
  #pragma unroll
  for (int m = 32; m >= 1; m >>= 1) v = fmaxf(v, __shfl_xor(v, m));
  return v;
}
__device__ inline float wave_sum(float v) {
  #pragma unroll
  for (int m = 32; m >= 1; m >>= 1) v += __shfl_xor(v, m);
  return v;
}

// ---------------- W[K=1024][N=1024] fp32 -> WT hi/lo bf16 [N][K] ----------------
__global__ __launch_bounds__(256)
void transp_convert_k(const float* __restrict__ W, unsigned short* __restrict__ hiT,
                      unsigned short* __restrict__ loT) {
  __shared__ float tile[64][65];
  const int bn = blockIdx.x * 64;  // N base
  const int bk = blockIdx.y * 64;  // K base
  const int t = threadIdx.x;
  #pragma unroll
  for (int i = 0; i < 4; ++i) {
    int r = (t >> 4) + i * 16, c = (t & 15) * 4;
    float4 v = *(const float4*)&W[(size_t)(bk + r) * D_M + bn + c];
    tile[r][c] = v.x; tile[r][c + 1] = v.y; tile[r][c + 2] = v.z; tile[r][c + 3] = v.w;
  }
  __syncthreads();
  #pragma unroll
  for (int i = 0; i < 4; ++i) {
    int n = (t >> 4) + i * 16, k = (t & 15) * 4;
    float4 v = {tile[k][n], tile[k + 1][n], tile[k + 2][n], tile[k + 3][n]};
    ushort4 h, l;
    split_f4(v, h, l);
    *(ushort4*)&hiT[(size_t)(bn + n) * D_M + bk + k] = h;
    *(ushort4*)&loT[(size_t)(bn + n) * D_M + bk + k] = l;
  }
}

// ------- split-bf16 MFMA GEMM: C[M,N] = A(fp32) @ Bt^T + bias, Bt pre-split [N][K] -------
__global__ __launch_bounds__(256)
void gemm_split_k(const float* __restrict__ A,
                  const unsigned short* __restrict__ Bhi, const unsigned short* __restrict__ Blo,
                  const float* __restrict__ bias, float* __restrict__ C,
                  int M, int N, int K) {
  constexpr int LDK = 40;  // 32 + 8 pad
  __shared__ unsigned short Ah[128 * LDK], Al[128 * LDK];
  __shared__ unsigned short Bh[128 * LDK], Bl[128 * LDK];
  const int tid = threadIdx.x;
  const int wave = tid >> 6, lane = tid & 63;
  const int wr = (wave >> 1) * 64, wc = (wave & 1) * 64;
  const int bm = blockIdx.x * 128, bn = blockIdx.y * 128;

  f32x4 acc[4][4] = {};
  const int ar = tid >> 3, ak = (tid & 7) * 4;   // A: 32 rows x 32 k per pass, 4 passes
  const int br = tid >> 2, bk = (tid & 3) * 8;   // B: 64 rows x 32 k per pass, 2 passes
  const int row16 = lane & 15, k8 = (lane >> 4) * 8;

  for (int k0 = 0; k0 < K; k0 += 32) {
    #pragma unroll
    for (int c = 0; c < 4; ++c) {
      int r = ar + c * 32;
      float4 v = *(const float4*)&A[(size_t)(bm + r) * K + k0 + ak];
      ushort4 h, l;
      split_f4(v, h, l);
      *(ushort4*)&Ah[r * LDK + ak] = h;
      *(ushort4*)&Al[r * LDK + ak] = l;
    }
    #pragma unroll
    for (int c = 0; c < 2; ++c) {
      int r = br + c * 64;
      *(uint4*)&Bh[r * LDK + bk] = *(const uint4*)&Bhi[(size_t)(bn + r) * K + k0 + bk];
      *(uint4*)&Bl[r * LDK + bk] = *(const uint4*)&Blo[(size_t)(bn + r) * K + k0 + bk];
    }
    __syncthreads();
    bf16x8 af[4][2], bfr[4][2];
    #pragma unroll
    for (int m = 0; m < 4; ++m) {
      af[m][0] = *(bf16x8*)&Ah[(wr + m * 16 + row16) * LDK + k8];
      af[m][1] = *(bf16x8*)&Al[(wr + m * 16 + row16) * LDK + k8];
    }
    #pragma unroll
    for (int n = 0; n < 4; ++n) {
      bfr[n][0] = *(bf16x8*)&Bh[(wc + n * 16 + row16) * LDK + k8];
      bfr[n][1] = *(bf16x8*)&Bl[(wc + n * 16 + row16) * LDK + k8];
    }
    #pragma unroll
    for (int m = 0; m < 4; ++m)
      #pragma unroll
      for (int n = 0; n < 4; ++n) {
        acc[m][n] = __builtin_amdgcn_mfma_f32_16x16x32_bf16(af[m][0], bfr[n][0], acc[m][n], 0, 0, 0);
        acc[m][n] = __builtin_amdgcn_mfma_f32_16x16x32_bf16(af[m][0], bfr[n][1], acc[m][n], 0, 0, 0);
        acc[m][n] = __builtin_amdgcn_mfma_f32_16x16x32_bf16(af[m][1], bfr[n][0], acc[m][n], 0, 0, 0);
      }
    __syncthreads();
  }
  // D layout: col = lane&15, row = (lane>>4)*4 + r
  const int cl = lane & 15, rb = (lane >> 4) * 4;
  #pragma unroll
  for (int n = 0; n < 4; ++n) {
    int col = bn + wc + n * 16 + cl;
    float bv = bias[col];
    #pragma unroll
    for (int m = 0; m < 4; ++m) {
      #pragma unroll
      for (int r = 0; r < 4; ++r) {
        int row = bm + wr + m * 16 + rb + r;
        C[(size_t)row * N + col] = acc[m][n][r] + bv;
      }
    }
  }
}

// ---------------- per-head FF, split-bf16 MFMA, weights staged from fp32 ----------------
// x1 fp32 [TOK][1024], W1 fp32 [h][4096][64], W2 fp32 [h][64][4096], out fp32 [TOK][1024]
__global__ __launch_bounds__(256)
void ff_split_k(const float* __restrict__ x1,
                const float* __restrict__ W1f, const float* __restrict__ b1,
                const float* __restrict__ W2f, const float* __restrict__ b2,
                float* __restrict__ out) {
  constexpr int LDW = 72;  // 64+8 pad
  constexpr int LDH = 40;  // 32+8 pad
  __shared__ unsigned short W1sh[2][32 * LDW], W1sl[2][32 * LDW];
  __shared__ unsigned short W2sh[2][64 * LDH], W2sl[2][64 * LDH];
  __shared__ unsigned short Hh[128 * LDH], Hl[128 * LDH];

  const int tid = threadIdx.x;
  const int wave = tid >> 6, lane = tid & 63;
  const int wm = wave >> 1, wf = wave & 1, wd = wave & 1;
  const int h = blockIdx.y;
  const int m0 = blockIdx.x * 128;
  const int row16 = lane & 15, kq = lane >> 4;

  const float* W1h = W1f + (size_t)h * FFD * HD;
  const float* W2h = W2f + (size_t)h * HD * FFD;
  const int r1 = tid >> 3, k1 = (tid & 7) * 8;   // W1 chunk: 32 f-rows x 64 k
  const int r2 = tid >> 2, f2 = (tid & 3) * 8;   // W2 chunk: 64 d-rows x 32 f

  // X fragments in registers for the whole kernel (split from fp32)
  bf16x8 xf[4][2][2];
  #pragma unroll
  for (int m = 0; m < 4; ++m)
    #pragma unroll
    for (int ks = 0; ks < 2; ++ks) {
      const float* xp = &x1[(size_t)(m0 + wm * 64 + m * 16 + row16) * D_M + h * HD + ks * 32 + kq * 8];
      split_f8(*(const float4*)xp, *(const float4*)(xp + 4), xf[m][ks][0], xf[m][ks][1]);
    }

  // stage W chunk 0 into buf 0
  {
    float4 va = *(const float4*)&W1h[(size_t)r1 * HD + k1];
    float4 vb = *(const float4*)&W1h[(size_t)r1 * HD + k1 + 4];
    ushort4 ha, la, hb, lb;
    split_f4(va, ha, la); split_f4(vb, hb, lb);
    *(ushort4*)&W1sh[0][r1 * LDW + k1] = ha; *(ushort4*)&W1sh[0][r1 * LDW + k1 + 4] = hb;
    *(ushort4*)&W1sl[0][r1 * LDW + k1] = la; *(ushort4*)&W1sl[0][r1 * LDW + k1 + 4] = lb;
    float4 wa = *(const float4*)&W2h[(size_t)r2 * FFD + f2];
    float4 wb = *(const float4*)&W2h[(size_t)r2 * FFD + f2 + 4];
    split_f4(wa, ha, la); split_f4(wb, hb, lb);
    *(ushort4*)&W2sh[0][r2 * LDH + f2] = ha; *(ushort4*)&W2sh[0][r2 * LDH + f2 + 4] = hb;
    *(ushort4*)&W2sl[0][r2 * LDH + f2] = la; *(ushort4*)&W2sl[0][r2 * LDH + f2 + 4] = lb;
  }
  __syncthreads();

  f32x4 ffacc[4][2] = {};

  for (int ch = 0; ch < FFD / 32; ++ch) {
    const int buf = ch & 1;
    // prefetch next W chunk into buf^1 (fp32 -> split)
    if (ch + 1 < FFD / 32) {
      const int f0n = (ch + 1) * 32;
      float4 va = *(const float4*)&W1h[(size_t)(f0n + r1) * HD + k1];
      float4 vb = *(const float4*)&W1h[(size_t)(f0n + r1) * HD + k1 + 4];
      ushort4 ha, la, hb, lb;
      split_f4(va, ha, la); split_f4(vb, hb, lb);
      *(ushort4*)&W1sh[buf ^ 1][r1 * LDW + k1] = ha; *(ushort4*)&W1sh[buf ^ 1][r1 * LDW + k1 + 4] = hb;
      *(ushort4*)&W1sl[buf ^ 1][r1 * LDW + k1] = la; *(ushort4*)&W1sl[buf ^ 1][r1 * LDW + k1 + 4] = lb;
      float4 wa = *(const float4*)&W2h[(size_t)r2 * FFD + f0n + f2];
      float4 wb = *(const float4*)&W2h[(size_t)r2 * FFD + f0n + f2 + 4];
      split_f4(wa, ha, la); split_f4(wb, hb, lb);
      *(ushort4*)&W2sh[buf ^ 1][r2 * LDH + f2] = ha; *(ushort4*)&W2sh[buf ^ 1][r2 * LDH + f2 + 4] = hb;
      *(ushort4*)&W2sl[buf ^ 1][r2 * LDH + f2] = la; *(ushort4*)&W2sl[buf ^ 1][r2 * LDH + f2 + 4] = lb;
    }
    // phase 1: hacc = X @ W1_chunk^T (wave: 64 m x 16 f)
    f32x4 hacc[4] = {};
    #pragma unroll
    for (int ks = 0; ks < 2; ++ks) {
      bf16x8 w1h = *(bf16x8*)&W1sh[buf][(wf * 16 + row16) * LDW + ks * 32 + kq * 8];
      bf16x8 w1l = *(bf16x8*)&W1sl[buf][(wf * 16 + row16) * LDW + ks * 32 + kq * 8];
      #pragma unroll
      for (int m = 0; m < 4; ++m) {
        hacc[m] = __builtin_amdgcn_mfma_f32_16x16x32_bf16(xf[m][ks][0], w1h, hacc[m], 0, 0, 0);
        hacc[m] = __builtin_amdgcn_mfma_f32_16x16x32_bf16(xf[m][ks][0], w1l, hacc[m], 0, 0, 0);
        hacc[m] = __builtin_amdgcn_mfma_f32_16x16x32_bf16(xf[m][ks][1], w1h, hacc[m], 0, 0, 0);
      }
    }
    // bias + relu + split -> H in LDS
    {
      const int fl = wf * 16 + row16;
      const float b1v = b1[(size_t)h * FFD + ch * 32 + fl];
      #pragma unroll
      for (int m = 0; m < 4; ++m) {
        #pragma unroll
        for (int r = 0; r < 4; ++r) {
          float hv = fmaxf(hacc[m][r] + b1v, 0.0f);
          unsigned short hh = f32_bf16_rne(hv);
          unsigned short hl = f32_bf16_rne(hv - bf16_f32(hh));
          int rw = wm * 64 + m * 16 + kq * 4 + r;
          Hh[rw * LDH + fl] = hh;
          Hl[rw * LDH + fl] = hl;
        }
      }
    }
    __syncthreads();
    // phase 2: ffacc += H_chunk @ W2_chunk^T (wave: 64 m x 32 d)
    bf16x8 hfr[4][2];
    #pragma unroll
    for (int m = 0; m < 4; ++m) {
      hfr[m][0] = *(bf16x8*)&Hh[(wm * 64 + m * 16 + row16) * LDH + kq * 8];
      hfr[m][1] = *(bf16x8*)&Hl[(wm * 64 + m * 16 + row16) * LDH + kq * 8];
    }
    #pragma unroll
    for (int n = 0; n < 2; ++n) {
      bf16x8 w2h = *(bf16x8*)&W2sh[buf][(wd * 32 + n * 16 + row16) * LDH + kq * 8];
      bf16x8 w2l = *(bf16x8*)&W2sl[buf][(wd * 32 + n * 16 + row16) * LDH + kq * 8];
      #pragma unroll
      for (int m = 0; m < 4; ++m) {
        ffacc[m][n] = __builtin_amdgcn_mfma_f32_16x16x32_bf16(hfr[m][0], w2h, ffacc[m][n], 0, 0, 0);
        ffacc[m][n] = __builtin_amdgcn_mfma_f32_16x16x32_bf16(hfr[m][0], w2l, ffacc[m][n], 0, 0, 0);
        ffacc[m][n] = __builtin_amdgcn_mfma_f32_16x16x32_bf16(hfr[m][1], w2h, ffacc[m][n], 0, 0, 0);
      }
    }
    __syncthreads();
  }
  // epilogue
  const int rb = (lane >> 4) * 4;
  #pragma unroll
  for (int n = 0; n < 2; ++n) {
    int dl = wd * 32 + n * 16 + row16;
    float bv = b2[(size_t)h * HD + dl];
    #pragma unroll
    for (int m = 0; m < 4; ++m) {
      #pragma unroll
      for (int r = 0; r < 4; ++r) {
        int row = m0 + wm * 64 + m * 16 + rb + r;
        out[(size_t)row * D_M + h * HD + dl] = ffacc[m][n][r] + bv;
      }
    }
  }
}

// ---------------- scores: attn_raw[b,h,q,k] = (q . k) / 8 (fp32) ----------------
__global__ __launch_bounds__(256)
void scores_kernel(const float* __restrict__ q, const float* __restrict__ k,
                   float* __restrict__ attn) {
  __shared__ float Qs[64][68];
  __shared__ float Ks[64][68];
  const int tid = threadIdx.x;
  const int tx = tid & 15, ty = tid >> 4;
  const int bh = blockIdx.z;
  const int b = bh >> 4, h = bh & 15;
  const int m0 = blockIdx.x * 64, n0 = blockIdx.y * 64;
  {
    const int r = tid >> 2, cb = (tid & 3) * 4;
    #pragma unroll
    for (int cc = 0; cc < 4; ++cc) {
      const int c = cb + cc * 16;
      float4 t = *(const float4*)&q[(size_t)(b * SQ + m0 + r) * D_M + h * HD + c];
      Qs[c + 0][r] = t.x; Qs[c + 1][r] = t.y; Qs[c + 2][r] = t.z; Qs[c + 3][r] = t.w;
      float4 u = *(const float4*)&k[(size_t)(b * SQ + n0 + r) * D_M + h * HD + c];
      Ks[c + 0][r] = u.x; Ks[c + 1][r] = u.y; Ks[c + 2][r] = u.z; Ks[c + 3][r] = u.w;
    }
  }
  __syncthreads();
  float acc[4][4] = {};
  #pragma unroll
  for (int d = 0; d < 64; ++d) {
    float4 a = *(float4*)&Qs[d][ty * 4];
    float4 w = *(float4*)&Ks[d][tx * 4];
    const float av[4] = {a.x, a.y, a.z, a.w};
    const float wv[4] = {w.x, w.y, w.z, w.w};
    #pragma unroll
    for (int i = 0; i < 4; ++i)
      #pragma unroll
      for (int j = 0; j < 4; ++j) acc[i][j] += av[i] * wv[j];
  }
  const float scale = 0.125f;
  #pragma unroll
  for (int i = 0; i < 4; ++i) {
    float4 o = {acc[i][0] * scale, acc[i][1] * scale, acc[i][2] * scale, acc[i][3] * scale};
    *(float4*)&attn[((size_t)bh * SQ + m0 + ty * 4 + i) * SQ + n0 + tx * 4] = o;
  }
}

// ---------------- softmax in place ----------------
__global__ __launch_bounds__(256)
void softmax_kernel(float* __restrict__ attn) {
  const size_t row = blockIdx.x;
  float* p = attn + row * (size_t)SQ;
  const int tid = threadIdx.x;
  __shared__ float redm[4];
  __shared__ float reds[4];
  float4 a = ((float4*)p)[tid];
  float4 b = ((float4*)p)[tid + 256];
  float mx = fmaxf(fmaxf(fmaxf(a.x, a.y), fmaxf(a.z, a.w)),
                   fmaxf(fmaxf(b.x, b.y), fmaxf(b.z, b.w)));
  mx = wave_max(mx);
  if ((tid & 63) == 0) redm[tid >> 6] = mx;
  __syncthreads();
  mx = fmaxf(fmaxf(redm[0], redm[1]), fmaxf(redm[2], redm[3]));
  a.x = __expf(a.x - mx); a.y = __expf(a.y - mx); a.z = __expf(a.z - mx); a.w = __expf(a.w - mx);
  b.x = __expf(b.x - mx); b.y = __expf(b.y - mx); b.z = __expf(b.z - mx); b.w = __expf(b.w - mx);
  float s = a.x + a.y + a.z + a.w + b.x + b.y + b.z + b.w;
  s = wave_sum(s);
  if ((tid & 63) == 0) reds[tid >> 6] = s;
  __syncthreads();
  s = reds[0] + reds[1] + reds[2] + reds[3];
  const float inv = 1.0f / s;
  a.x *= inv; a.y *= inv; a.z *= inv; a.w *= inv;
  b.x *= inv; b.y *= inv; b.z *= inv; b.w *= inv;
  ((float4*)p)[tid] = a;
  ((float4*)p)[tid + 256] = b;
}

// ---------------- ctx = attn @ V (fp32) ----------------
__global__ __launch_bounds__(256)
void ctx_kernel(const float* __restrict__ attn, const float* __restrict__ v,
                float* __restrict__ ctx) {
  __shared__ float AtT[64][68];
  __shared__ float Vt[64][68];
  const int tid = threadIdx.x;
  const int tx = tid & 15, ty = tid >> 4;
  const int bh = blockIdx.y;
  const int b = bh >> 4, h = bh & 15;
  const int m0 = blockIdx.x * 64;
  float acc[4][4] = {};
  for (int k0 = 0; k0 < SQ; k0 += 64) {
    {
      const int r = tid >> 2, cb = (tid & 3) * 4;
      #pragma unroll
      for (int cc = 0; cc < 4; ++cc) {
        const int c = cb + cc * 16;
        float4 t = *(const float4*)&attn[((size_t)bh * SQ + m0 + r) * SQ + k0 + c];
        AtT[c + 0][r] = t.x; AtT[c + 1][r] = t.y; AtT[c + 2][r] = t.z; AtT[c + 3][r] = t.w;
        float4 u = *(const float4*)&v[(size_t)(b * SQ + k0 + r) * D_M + h * HD + c];
        Vt[r][c + 0] = u.x; Vt[r][c + 1] = u.y; Vt[r][c + 2] = u.z; Vt[r][c + 3] = u.w;
      }
    }
    __syncthreads();
    #pragma unroll
    for (int kk = 0; kk < 64; ++kk) {
      float4 a = *(float4*)&AtT[kk][ty * 4];
      float4 w = *(float4*)&Vt[kk][tx * 4];
      const float av[4] = {a.x, a.y, a.z, a.w};
      const float wv[4] = {w.x, w.y, w.z, w.w};
      #pragma unroll
      for (int i = 0; i < 4; ++i)
        #pragma unroll
        for (int j = 0; j < 4; ++j) acc[i][j] += av[i] * wv[j];
    }
    __syncthreads();
  }
  #pragma unroll
  for (int i = 0; i < 4; ++i) {
    float4 o = {acc[i][0], acc[i][1], acc[i][2], acc[i][3]};
    *(float4*)&ctx[(size_t)(b * SQ + m0 + ty * 4 + i) * D_M + h * HD + tx * 4] = o;
  }
}

// ---------------- out = LayerNorm(a + r) * g + be ----------------
__global__ __launch_bounds__(256)
void add_ln_kernel(const float* __restrict__ a, const float* __restrict__ r,
                   const float* __restrict__ g, const float* __restrict__ be,
                   float* __restrict__ out) {
  const size_t row = blockIdx.x;
  const int tid = threadIdx.x;
  __shared__ float red1[4];
  __shared__ float red2[4];
  float4 va = ((const float4*)(a + row * D_M))[tid];
  float4 vr = ((const float4*)(r + row * D_M))[tid];
  float v0 = va.x + vr.x, v1 = va.y + vr.y, v2 = va.z + vr.z, v3 = va.w + vr.w;
  float s = v0 + v1 + v2 + v3;
  float sq = v0 * v0 + v1 * v1 + v2 * v2 + v3 * v3;
  s = wave_sum(s);
  sq = wave_sum(sq);
  if ((tid & 63) == 0) { red1[tid >> 6] = s; red2[tid >> 6] = sq; }
  __syncthreads();
  s = red1[0] + red1[1] + red1[2] + red1[3];
  sq = red2[0] + red2[1] + red2[2] + red2[3];
  const float mu = s * (1.0f / D_M);
  const float var = sq * (1.0f / D_M) - mu * mu;
  float x = var + EPS;
  float rs = rsqrtf(x);
  rs = rs * (1.5f - 0.5f * x * rs * rs);
  float4 gg = ((const float4*)g)[tid];
  float4 bb = ((const float4*)be)[tid];
  float4 o = {(v0 - mu) * rs * gg.x + bb.x, (v1 - mu) * rs * gg.y + bb.y,
              (v2 - mu) * rs * gg.z + bb.z, (v3 - mu) * rs * gg.w + bb.w};
  ((float4*)(out + row * D_M))[tid] = o;
}

extern "C" void kernel_launch(void* const* d_in, const int* in_sizes, int n_in,
                              void* d_out, int out_size, void* d_ws, size_t ws_size,
                              hipStream_t stream) {
  const float* x   = (const float*)d_in[0];
  const float* Wq  = (const float*)d_in[1];
  const float* bq  = (const float*)d_in[2];
  const float* Wk  = (const float*)d_in[3];
  const float* bk  = (const float*)d_in[4];
  const float* Wv  = (const float*)d_in[5];
  const float* bv  = (const float*)d_in[6];
  const float* Wo  = (const float*)d_in[7];
  const float* bo  = (const float*)d_in[8];
  const float* W1  = (const float*)d_in[9];
  const float* b1  = (const float*)d_in[10];
  const float* W2  = (const float*)d_in[11];
  const float* b2  = (const float*)d_in[12];
  const float* g1  = (const float*)d_in[13];
  const float* be1 = (const float*)d_in[14];
  const float* g2  = (const float*)d_in[15];
  const float* be2 = (const float*)d_in[16];

  float* y_out = (float*)d_out;
  float* attn  = (float*)d_out + (size_t)TOK * D_M;

  // ---- workspace: exactly 80 MB ----
  char* p = (char*)d_ws;
  const size_t MB = 1024 * 1024;
  unsigned short* WqT_h = (unsigned short*)p; p += 2 * MB;
  unsigned short* WqT_l = (unsigned short*)p; p += 2 * MB;
  unsigned short* WkT_h = (unsigned short*)p; p += 2 * MB;
  unsigned short* WkT_l = (unsigned short*)p; p += 2 * MB;
  unsigned short* WvT_h = (unsigned short*)p; p += 2 * MB;
  unsigned short* WvT_l = (unsigned short*)p; p += 2 * MB;
  unsigned short* WoT_h = (unsigned short*)p; p += 2 * MB;
  unsigned short* WoT_l = (unsigned short*)p; p += 2 * MB;
  float* qb   = (float*)p; p += 16 * MB;
  float* kb   = (float*)p; p += 16 * MB;
  float* vb   = (float*)p; p += 16 * MB;
  float* ctxb = (float*)p; p += 16 * MB;
  // aliases for dead buffers
  float* resid = qb;   // q dead after scores
  float* x1b   = kb;   // k dead after scores
  float* ffb   = vb;   // v dead after ctx

  const dim3 blk(256);

  // ---- prep: weight transposes + split (16 MB) ----
  transp_convert_k<<<dim3(16, 16), blk, 0, stream>>>(Wq, WqT_h, WqT_l);
  transp_convert_k<<<dim3(16, 16), blk, 0, stream>>>(Wk, WkT_h, WkT_l);
  transp_convert_k<<<dim3(16, 16), blk, 0, stream>>>(Wv, WvT_h, WvT_l);
  transp_convert_k<<<dim3(16, 16), blk, 0, stream>>>(Wo, WoT_h, WoT_l);

  // ---- QKV projections (split-bf16 MFMA, A staged from fp32) ----
  gemm_split_k<<<dim3(TOK / 128, D_M / 128), blk, 0, stream>>>(x, WqT_h, WqT_l, bq, qb, TOK, D_M, D_M);
  gemm_split_k<<<dim3(TOK / 128, D_M / 128), blk, 0, stream>>>(x, WkT_h, WkT_l, bk, kb, TOK, D_M, D_M);
  gemm_split_k<<<dim3(TOK / 128, D_M / 128), blk, 0, stream>>>(x, WvT_h, WvT_l, bv, vb, TOK, D_M, D_M);

  // ---- attention core (fp32) ----
  scores_kernel<<<dim3(SQ / 64, SQ / 64, BB * NH), blk, 0, stream>>>(qb, kb, attn);
  softmax_kernel<<<dim3(BB * NH * SQ), blk, 0, stream>>>(attn);
  ctx_kernel<<<dim3(SQ / 64, BB * NH), blk, 0, stream>>>(attn, vb, ctxb);

  // ---- Wo projection + LN1 ----
  gemm_split_k<<<dim3(TOK / 128, D_M / 128), blk, 0, stream>>>(ctxb, WoT_h, WoT_l, bo, resid, TOK, D_M, D_M);
  add_ln_kernel<<<dim3(TOK), blk, 0, stream>>>(x, resid, g1, be1, x1b);

  // ---- per-head FF + LN2 ----
  ff_split_k<<<dim3(TOK / 128, NH), blk, 0, stream>>>(x1b, W1, b1, W2, b2, ffb);
  add_ln_kernel<<<dim3(TOK), blk, 0, stream>>>(x1b, ffb, g2, be2, y_out);
}

// Round 5
// 858.834 us; speedup vs baseline: 3.1759x; 1.4595x over previous
//
#include <hip/hip_runtime.h>
#include <cstddef>

#define D_M 1024
#define NH 16
#define HD 64
#define FFD 4096
#define SQ 2048
#define BB 2
#define TOK (BB*SQ)   // 4096
#define EPS 1e-5f

typedef __attribute__((ext_vector_type(8))) short bf16x8;
typedef __attribute__((ext_vector_type(4))) float f32x4;

__device__ inline unsigned short f32_bf16_rne(float f) {
  unsigned int u = __float_as_uint(f);
  unsigned int r = (u + 0x7fffu + ((u >> 16) & 1u)) >> 16;
  return (unsigned short)r;
}
__device__ inline float bf16_f32(unsigned short h) {
  return __uint_as_float(((unsigned int)h) << 16);
}
__device__ inline void split_f4(float4 v, ushort4& h, ushort4& l) {
  h.x = f32_bf16_rne(v.x); l.x = f32_bf16_rne(v.x - bf16_f32(h.x));
  h.y = f32_bf16_rne(v.y); l.y = f32_bf16_rne(v.y - bf16_f32(h.y));
  h.z = f32_bf16_rne(v.z); l.z = f32_bf16_rne(v.z - bf16_f32(h.z));
  h.w = f32_bf16_rne(v.w); l.w = f32_bf16_rne(v.w - bf16_f32(h.w));
}

__device__ inline float wave_sum16(float v) {
  v += __shfl_xor(v, 1); v += __shfl_xor(v, 2);
  v += __shfl_xor(v, 4); v += __shfl_xor(v, 8);
  return v;
}
__device__ inline float wave_sum(float v) {
  #pragma unroll
  for (int m = 32; m >= 1; m >>= 1) v += __shfl_xor(v, m);
  return v;
}

// ---------------- fp32 -> (hi,lo) bf16 split, layout-preserving ----------------
__global__ __launch_bounds__(256)
void convert_split_k(const float* __restrict__ src, unsigned short* __restrict__ hi,
                     unsigned short* __restrict__ lo, int n4) {
  int i = blockIdx.x * 256 + threadIdx.x;
  if (i >= n4) return;
  float4 v = ((const float4*)src)[i];
  ushort4 h, l;
  split_f4(v, h, l);
  ((ushort4*)hi)[i] = h;
  ((ushort4*)lo)[i] = l;
}

// ---------------- W[K=1024][N=1024] fp32 -> WT hi/lo bf16 [N][K] ----------------
__global__ __launch_bounds__(256)
void transp_convert_k(const float* __restrict__ W, unsigned short* __restrict__ hiT,
                      unsigned short* __restrict__ loT) {
  __shared__ float tile[64][65];
  const int bn = blockIdx.x * 64;
  const int bk = blockIdx.y * 64;
  const int t = threadIdx.x;
  #pragma unroll
  for (int i = 0; i < 4; ++i) {
    int r = (t >> 4) + i * 16, c = (t & 15) * 4;
    float4 v = *(const float4*)&W[(size_t)(bk + r) * D_M + bn + c];
    tile[r][c] = v.x; tile[r][c + 1] = v.y; tile[r][c + 2] = v.z; tile[r][c + 3] = v.w;
  }
  __syncthreads();
  #pragma unroll
  for (int i = 0; i < 4; ++i) {
    int n = (t >> 4) + i * 16, k = (t & 15) * 4;
    float4 v = {tile[k][n], tile[k + 1][n], tile[k + 2][n], tile[k + 3][n]};
    ushort4 h, l;
    split_f4(v, h, l);
    *(ushort4*)&hiT[(size_t)(bn + n) * D_M + bk + k] = h;
    *(ushort4*)&loT[(size_t)(bn + n) * D_M + bk + k] = l;
  }
}

// ------- split-bf16 MFMA GEMM: A(fp32 [M][K]) @ Bt^T (pre-split [N][K]) + bias -------
// MODE 0: C fp32 [M][N].  MODE 1: Ohi/Olo bf16 split [M][N].
// MODE 2: Ohi bf16 transposed V: [b][h][d][s] = [bh*64+d][2048]  (M=4096 tokens, N=1024)
template<int MODE>
__global__ __launch_bounds__(256)
void gemm_split_k(const float* __restrict__ A,
                  const unsigned short* __restrict__ Bhi, const unsigned short* __restrict__ Blo,
                  const float* __restrict__ bias, float* __restrict__ C,
                  unsigned short* __restrict__ Ohi, unsigned short* __restrict__ Olo,
                  int M, int N, int K) {
  constexpr int LDK = 40;
  __shared__ unsigned short Ah[128 * LDK], Al[128 * LDK];
  __shared__ unsigned short Bh[128 * LDK], Bl[128 * LDK];
  const int tid = threadIdx.x;
  const int wave = tid >> 6, lane = tid & 63;
  const int wr = (wave >> 1) * 64, wc = (wave & 1) * 64;
  const int bm = blockIdx.x * 128, bn = blockIdx.y * 128;

  f32x4 acc[4][4] = {};
  const int ar = tid >> 3, ak = (tid & 7) * 4;
  const int br = tid >> 2, bk = (tid & 3) * 8;
  const int row16 = lane & 15, k8 = (lane >> 4) * 8;

  for (int k0 = 0; k0 < K; k0 += 32) {
    #pragma unroll
    for (int c = 0; c < 4; ++c) {
      int r = ar + c * 32;
      float4 v = *(const float4*)&A[(size_t)(bm + r) * K + k0 + ak];
      ushort4 h, l;
      split_f4(v, h, l);
      *(ushort4*)&Ah[r * LDK + ak] = h;
      *(ushort4*)&Al[r * LDK + ak] = l;
    }
    #pragma unroll
    for (int c = 0; c < 2; ++c) {
      int r = br + c * 64;
      *(uint4*)&Bh[r * LDK + bk] = *(const uint4*)&Bhi[(size_t)(bn + r) * K + k0 + bk];
      *(uint4*)&Bl[r * LDK + bk] = *(const uint4*)&Blo[(size_t)(bn + r) * K + k0 + bk];
    }
    __syncthreads();
    bf16x8 af[4][2], bfr[4][2];
    #pragma unroll
    for (int m = 0; m < 4; ++m) {
      af[m][0] = *(bf16x8*)&Ah[(wr + m * 16 + row16) * LDK + k8];
      af[m][1] = *(bf16x8*)&Al[(wr + m * 16 + row16) * LDK + k8];
    }
    #pragma unroll
    for (int n = 0; n < 4; ++n) {
      bfr[n][0] = *(bf16x8*)&Bh[(wc + n * 16 + row16) * LDK + k8];
      bfr[n][1] = *(bf16x8*)&Bl[(wc + n * 16 + row16) * LDK + k8];
    }
    #pragma unroll
    for (int m = 0; m < 4; ++m)
      #pragma unroll
      for (int n = 0; n < 4; ++n) {
        acc[m][n] = __builtin_amdgcn_mfma_f32_16x16x32_bf16(af[m][0], bfr[n][0], acc[m][n], 0, 0, 0);
        acc[m][n] = __builtin_amdgcn_mfma_f32_16x16x32_bf16(af[m][0], bfr[n][1], acc[m][n], 0, 0, 0);
        acc[m][n] = __builtin_amdgcn_mfma_f32_16x16x32_bf16(af[m][1], bfr[n][0], acc[m][n], 0, 0, 0);
      }
    __syncthreads();
  }
  const int cl = lane & 15, rb = (lane >> 4) * 4;
  #pragma unroll
  for (int n = 0; n < 4; ++n) {
    int col = bn + wc + n * 16 + cl;
    float bv = bias[col];
    #pragma unroll
    for (int m = 0; m < 4; ++m) {
      if (MODE == 2) {
        int row0 = bm + wr + m * 16 + rb;
        ushort4 hv;
        float v0 = acc[m][n][0] + bv, v1 = acc[m][n][1] + bv;
        float v2 = acc[m][n][2] + bv, v3 = acc[m][n][3] + bv;
        hv.x = f32_bf16_rne(v0); hv.y = f32_bf16_rne(v1);
        hv.z = f32_bf16_rne(v2); hv.w = f32_bf16_rne(v3);
        size_t idx = (((size_t)(row0 >> 11) * NH + (col >> 6)) * HD + (col & 63)) * SQ + (row0 & 2047);
        *(ushort4*)&Ohi[idx] = hv;
      } else {
        #pragma unroll
        for (int r = 0; r < 4; ++r) {
          int row = bm + wr + m * 16 + rb + r;
          float v = acc[m][n][r] + bv;
          if (MODE == 0) {
            C[(size_t)row * N + col] = v;
          } else {
            unsigned short h = f32_bf16_rne(v);
            Ohi[(size_t)row * N + col] = h;
            Olo[(size_t)row * N + col] = f32_bf16_rne(v - bf16_f32(h));
          }
        }
      }
    }
  }
}

// ---------------- fused attention: scores -> softmax -> attn write + P@V ----------------
// qh/ql, kh/kl: split bf16 [TOK][1024]; vth: bf16 V transposed [bh*64+d][2048]
// attn out fp32 [B,H,S,S]; ctx out fp32 [TOK][1024]
__global__ __launch_bounds__(256)
void fused_attn_k(const unsigned short* __restrict__ qh, const unsigned short* __restrict__ ql,
                  const unsigned short* __restrict__ kh, const unsigned short* __restrict__ kl,
                  const unsigned short* __restrict__ vth,
                  float* __restrict__ attn, float* __restrict__ ctx) {
  constexpr int LDK = 72;
  __shared__ unsigned short Kth[64 * LDK], Ktl[64 * LDK];
  __shared__ unsigned short Vts[64 * LDK], Ph[64 * LDK];
  const int tid = threadIdx.x, wave = tid >> 6, lane = tid & 63;
  const int l15 = lane & 15, kq = lane >> 4;
  const int bh = blockIdx.y, b = bh >> 4;
  const int h = bh & 15;
  const int q0 = blockIdx.x * 64;

  // Q fragments (A operand: row = lane&15, k = (lane>>4)*8 + j + ks*32)
  const size_t qoff = (size_t)(b * SQ + q0 + wave * 16 + l15) * D_M + h * HD + kq * 8;
  bf16x8 qfh[2], qfl[2];
  qfh[0] = *(const bf16x8*)&qh[qoff];      qfh[1] = *(const bf16x8*)&qh[qoff + 32];
  qfl[0] = *(const bf16x8*)&ql[qoff];      qfl[1] = *(const bf16x8*)&ql[qoff + 32];

  const size_t kbase = (size_t)(b * SQ) * D_M + h * HD;
  const size_t vbase = (size_t)bh * HD * SQ;
  const int srow = tid >> 2, sc = (tid & 3) * 16;   // staging: row, 16-elem chunk

  // ---------- pass A: l[r] = sum_k exp(s) (hi-only scores; max==0 is safe & cancels) ----------
  float lsum[4] = {0.f, 0.f, 0.f, 0.f};
  for (int t = 0; t < SQ / 64; ++t) {
    const int k0 = t * 64;
    __syncthreads();
    {
      const unsigned short* src = &kh[kbase + (size_t)(k0 + srow) * D_M + sc];
      *(uint4*)&Kth[srow * LDK + sc] = *(const uint4*)src;
      *(uint4*)&Kth[srow * LDK + sc + 8] = *(const uint4*)(src + 8);
    }
    __syncthreads();
    #pragma unroll
    for (int n = 0; n < 4; ++n) {
      bf16x8 kb0 = *(bf16x8*)&Kth[(n * 16 + l15) * LDK + kq * 8];
      bf16x8 kb1 = *(bf16x8*)&Kth[(n * 16 + l15) * LDK + 32 + kq * 8];
      f32x4 s = {};
      s = __builtin_amdgcn_mfma_f32_16x16x32_bf16(qfh[0], kb0, s, 0, 0, 0);
      s = __builtin_amdgcn_mfma_f32_16x16x32_bf16(qfh[1], kb1, s, 0, 0, 0);
      #pragma unroll
      for (int r = 0; r < 4; ++r) lsum[r] += __expf(s[r] * 0.125f);
    }
  }
  float invl[4];
  #pragma unroll
  for (int r = 0; r < 4; ++r) invl[r] = 1.0f / wave_sum16(lsum[r]);

  // ---------- pass B: split scores, write attn, accumulate ctx ----------
  f32x4 cacc[4] = {};
  const size_t abase = ((size_t)bh * SQ + q0 + wave * 16) * SQ;
  for (int t = 0; t < SQ / 64; ++t) {
    const int k0 = t * 64;
    __syncthreads();
    {
      const unsigned short* srch = &kh[kbase + (size_t)(k0 + srow) * D_M + sc];
      const unsigned short* srcl = &kl[kbase + (size_t)(k0 + srow) * D_M + sc];
      const unsigned short* srcv = &vth[vbase + (size_t)srow * SQ + k0 + sc];
      *(uint4*)&Kth[srow * LDK + sc] = *(const uint4*)srch;
      *(uint4*)&Kth[srow * LDK + sc + 8] = *(const uint4*)(srch + 8);
      *(uint4*)&Ktl[srow * LDK + sc] = *(const uint4*)srcl;
      *(uint4*)&Ktl[srow * LDK + sc + 8] = *(const uint4*)(srcl + 8);
      *(uint4*)&Vts[srow * LDK + sc] = *(const uint4*)srcv;
      *(uint4*)&Vts[srow * LDK + sc + 8] = *(const uint4*)(srcv + 8);
    }
    __syncthreads();
    #pragma unroll
    for (int n = 0; n < 4; ++n) {
      bf16x8 kbh0 = *(bf16x8*)&Kth[(n * 16 + l15) * LDK + kq * 8];
      bf16x8 kbh1 = *(bf16x8*)&Kth[(n * 16 + l15) * LDK + 32 + kq * 8];
      bf16x8 kbl0 = *(bf16x8*)&Ktl[(n * 16 + l15) * LDK + kq * 8];
      bf16x8 kbl1 = *(bf16x8*)&Ktl[(n * 16 + l15) * LDK + 32 + kq * 8];
      f32x4 s = {};
      s = __builtin_amdgcn_mfma_f32_16x16x32_bf16(qfh[0], kbh0, s, 0, 0, 0);
      s = __builtin_amdgcn_mfma_f32_16x16x32_bf16(qfh[1], kbh1, s, 0, 0, 0);
      s = __builtin_amdgcn_mfma_f32_16x16x32_bf16(qfh[0], kbl0, s, 0, 0, 0);
      s = __builtin_amdgcn_mfma_f32_16x16x32_bf16(qfh[1], kbl1, s, 0, 0, 0);
      s = __builtin_amdgcn_mfma_f32_16x16x32_bf16(qfl[0], kbh0, s, 0, 0, 0);
      s = __builtin_amdgcn_mfma_f32_16x16x32_bf16(qfl[1], kbh1, s, 0, 0, 0);
      #pragma unroll
      for (int r = 0; r < 4; ++r) {
        const int qrl = kq * 4 + r;
        float p = __expf(s[r] * 0.125f) * invl[r];
        attn[abase + (size_t)qrl * SQ + k0 + n * 16 + l15] = p;
        Ph[(wave * 16 + qrl) * LDK + n * 16 + l15] = f32_bf16_rne(p);
      }
    }
    __syncthreads();
    bf16x8 pa0 = *(bf16x8*)&Ph[(wave * 16 + l15) * LDK + kq * 8];
    bf16x8 pa1 = *(bf16x8*)&Ph[(wave * 16 + l15) * LDK + 32 + kq * 8];
    #pragma unroll
    for (int n = 0; n < 4; ++n) {
      bf16x8 vb0 = *(bf16x8*)&Vts[(n * 16 + l15) * LDK + kq * 8];
      bf16x8 vb1 = *(bf16x8*)&Vts[(n * 16 + l15) * LDK + 32 + kq * 8];
      cacc[n] = __builtin_amdgcn_mfma_f32_16x16x32_bf16(pa0, vb0, cacc[n], 0, 0, 0);
      cacc[n] = __builtin_amdgcn_mfma_f32_16x16x32_bf16(pa1, vb1, cacc[n], 0, 0, 0);
    }
  }
  #pragma unroll
  for (int n = 0; n < 4; ++n)
    #pragma unroll
    for (int r = 0; r < 4; ++r)
      ctx[(size_t)(b * SQ + q0 + wave * 16 + kq * 4 + r) * D_M + h * HD + n * 16 + l15] = cacc[n][r];
}

// ---------------- per-head FF, split-bf16 MFMA, all inputs pre-split ----------------
__global__ __launch_bounds__(256)
void ff_split_k(const unsigned short* __restrict__ x1h, const unsigned short* __restrict__ x1l,
                const unsigned short* __restrict__ W1h_, const unsigned short* __restrict__ W1l_,
                const float* __restrict__ b1,
                const unsigned short* __restrict__ W2h_, const unsigned short* __restrict__ W2l_,
                const float* __restrict__ b2, float* __restrict__ out) {
  constexpr int LDW = 72;
  constexpr int LDH = 40;
  __shared__ unsigned short W1sh[2][32 * LDW], W1sl[2][32 * LDW];
  __shared__ unsigned short W2sh[2][64 * LDH], W2sl[2][64 * LDH];
  __shared__ unsigned short Hh[128 * LDH], Hl[128 * LDH];

  const int tid = threadIdx.x;
  const int wave = tid >> 6, lane = tid & 63;
  const int wm = wave >> 1, wf = wave & 1, wd = wave & 1;
  const int h = blockIdx.y;
  const int m0 = blockIdx.x * 128;
  const int row16 = lane & 15, kq = lane >> 4;

  const size_t w1base = (size_t)h * FFD * HD;
  const size_t w2base = (size_t)h * HD * FFD;
  const int r1 = tid >> 3, k1 = (tid & 7) * 8;
  const int r2 = tid >> 2, f2 = (tid & 3) * 8;

  bf16x8 xf[4][2][2];
  #pragma unroll
  for (int m = 0; m < 4; ++m)
    #pragma unroll
    for (int ks = 0; ks < 2; ++ks) {
      size_t gof = (size_t)(m0 + wm * 64 + m * 16 + row16) * D_M + h * HD + ks * 32 + kq * 8;
      xf[m][ks][0] = *(const bf16x8*)&x1h[gof];
      xf[m][ks][1] = *(const bf16x8*)&x1l[gof];
    }

  {
    *(uint4*)&W1sh[0][r1 * LDW + k1] = *(const uint4*)&W1h_[w1base + (size_t)r1 * HD + k1];
    *(uint4*)&W1sl[0][r1 * LDW + k1] = *(const uint4*)&W1l_[w1base + (size_t)r1 * HD + k1];
    *(uint4*)&W2sh[0][r2 * LDH + f2] = *(const uint4*)&W2h_[w2base + (size_t)r2 * FFD + f2];
    *(uint4*)&W2sl[0][r2 * LDH + f2] = *(const uint4*)&W2l_[w2base + (size_t)r2 * FFD + f2];
  }
  __syncthreads();

  f32x4 ffacc[4][2] = {};

  for (int ch = 0; ch < FFD / 32; ++ch) {
    const int buf = ch & 1;
    if (ch + 1 < FFD / 32) {
      const int f0n = (ch + 1) * 32;
      *(uint4*)&W1sh[buf ^ 1][r1 * LDW + k1] = *(const uint4*)&W1h_[w1base + (size_t)(f0n + r1) * HD + k1];
      *(uint4*)&W1sl[buf ^ 1][r1 * LDW + k1] = *(const uint4*)&W1l_[w1base + (size_t)(f0n + r1) * HD + k1];
      *(uint4*)&W2sh[buf ^ 1][r2 * LDH + f2] = *(const uint4*)&W2h_[w2base + (size_t)r2 * FFD + f0n + f2];
      *(uint4*)&W2sl[buf ^ 1][r2 * LDH + f2] = *(const uint4*)&W2l_[w2base + (size_t)r2 * FFD + f0n + f2];
    }
    f32x4 hacc[4] = {};
    #pragma unroll
    for (int ks = 0; ks < 2; ++ks) {
      bf16x8 w1h = *(bf16x8*)&W1sh[buf][(wf * 16 + row16) * LDW + ks * 32 + kq * 8];
      bf16x8 w1l = *(bf16x8*)&W1sl[buf][(wf * 16 + row16) * LDW + ks * 32 + kq * 8];
      #pragma unroll
      for (int m = 0; m < 4; ++m) {
        hacc[m] = __builtin_amdgcn_mfma_f32_16x16x32_bf16(xf[m][ks][0], w1h, hacc[m], 0, 0, 0);
        hacc[m] = __builtin_amdgcn_mfma_f32_16x16x32_bf16(xf[m][ks][0], w1l, hacc[m], 0, 0, 0);
        hacc[m] = __builtin_amdgcn_mfma_f32_16x16x32_bf16(xf[m][ks][1], w1h, hacc[m], 0, 0, 0);
      }
    }
    {
      const int fl = wf * 16 + row16;
      const float b1v = b1[(size_t)h * FFD + ch * 32 + fl];
      #pragma unroll
      for (int m = 0; m < 4; ++m) {
        #pragma unroll
        for (int r = 0; r < 4; ++r) {
          float hv = fmaxf(hacc[m][r] + b1v, 0.0f);
          unsigned short hh = f32_bf16_rne(hv);
          unsigned short hl = f32_bf16_rne(hv - bf16_f32(hh));
          int rw = wm * 64 + m * 16 + kq * 4 + r;
          Hh[rw * LDH + fl] = hh;
          Hl[rw * LDH + fl] = hl;
        }
      }
    }
    __syncthreads();
    bf16x8 hfr[4][2];
    #pragma unroll
    for (int m = 0; m < 4; ++m) {
      hfr[m][0] = *(bf16x8*)&Hh[(wm * 64 + m * 16 + row16) * LDH + kq * 8];
      hfr[m][1] = *(bf16x8*)&Hl[(wm * 64 + m * 16 + row16) * LDH + kq * 8];
    }
    #pragma unroll
    for (int n = 0; n < 2; ++n) {
      bf16x8 w2h = *(bf16x8*)&W2sh[buf][(wd * 32 + n * 16 + row16) * LDH + kq * 8];
      bf16x8 w2l = *(bf16x8*)&W2sl[buf][(wd * 32 + n * 16 + row16) * LDH + kq * 8];
      #pragma unroll
      for (int m = 0; m < 4; ++m) {
        ffacc[m][n] = __builtin_amdgcn_mfma_f32_16x16x32_bf16(hfr[m][0], w2h, ffacc[m][n], 0, 0, 0);
        ffacc[m][n] = __builtin_amdgcn_mfma_f32_16x16x32_bf16(hfr[m][0], w2l, ffacc[m][n], 0, 0, 0);
        ffacc[m][n] = __builtin_amdgcn_mfma_f32_16x16x32_bf16(hfr[m][1], w2h, ffacc[m][n], 0, 0, 0);
      }
    }
    __syncthreads();
  }
  const int rb = (lane >> 4) * 4;
  #pragma unroll
  for (int n = 0; n < 2; ++n) {
    int dl = wd * 32 + n * 16 + row16;
    float bv = b2[(size_t)h * HD + dl];
    #pragma unroll
    for (int m = 0; m < 4; ++m) {
      #pragma unroll
      for (int r = 0; r < 4; ++r) {
        int row = m0 + wm * 64 + m * 16 + rb + r;
        out[(size_t)row * D_M + h * HD + dl] = ffacc[m][n][r] + bv;
      }
    }
  }
}

// ---------------- out = LayerNorm(a + r) * g + be ----------------
__global__ __launch_bounds__(256)
void add_ln_kernel(const float* __restrict__ a, const float* __restrict__ r,
                   const float* __restrict__ g, const float* __restrict__ be,
                   float* __restrict__ out) {
  const size_t row = blockIdx.x;
  const int tid = threadIdx.x;
  __shared__ float red1[4];
  __shared__ float red2[4];
  float4 va = ((const float4*)(a + row * D_M))[tid];
  float4 vr = ((const float4*)(r + row * D_M))[tid];
  float v0 = va.x + vr.x, v1 = va.y + vr.y, v2 = va.z + vr.z, v3 = va.w + vr.w;
  float s = v0 + v1 + v2 + v3;
  float sq = v0 * v0 + v1 * v1 + v2 * v2 + v3 * v3;
  s = wave_sum(s);
  sq = wave_sum(sq);
  if ((tid & 63) == 0) { red1[tid >> 6] = s; red2[tid >> 6] = sq; }
  __syncthreads();
  s = red1[0] + red1[1] + red1[2] + red1[3];
  sq = red2[0] + red2[1] + red2[2] + red2[3];
  const float mu = s * (1.0f / D_M);
  const float var = sq * (1.0f / D_M) - mu * mu;
  float x = var + EPS;
  float rs = rsqrtf(x);
  rs = rs * (1.5f - 0.5f * x * rs * rs);
  float4 gg = ((const float4*)g)[tid];
  float4 bb = ((const float4*)be)[tid];
  float4 o = {(v0 - mu) * rs * gg.x + bb.x, (v1 - mu) * rs * gg.y + bb.y,
              (v2 - mu) * rs * gg.z + bb.z, (v3 - mu) * rs * gg.w + bb.w};
  ((float4*)(out + row * D_M))[tid] = o;
}

extern "C" void kernel_launch(void* const* d_in, const int* in_sizes, int n_in,
                              void* d_out, int out_size, void* d_ws, size_t ws_size,
                              hipStream_t stream) {
  const float* x   = (const float*)d_in[0];
  const float* Wq  = (const float*)d_in[1];
  const float* bq  = (const float*)d_in[2];
  const float* Wk  = (const float*)d_in[3];
  const float* bk  = (const float*)d_in[4];
  const float* Wv  = (const float*)d_in[5];
  const float* bv  = (const float*)d_in[6];
  const float* Wo  = (const float*)d_in[7];
  const float* bo  = (const float*)d_in[8];
  const float* W1  = (const float*)d_in[9];
  const float* b1  = (const float*)d_in[10];
  const float* W2  = (const float*)d_in[11];
  const float* b2  = (const float*)d_in[12];
  const float* g1  = (const float*)d_in[13];
  const float* be1 = (const float*)d_in[14];
  const float* g2  = (const float*)d_in[15];
  const float* be2 = (const float*)d_in[16];

  float* y_out = (float*)d_out;
  float* attn  = (float*)d_out + (size_t)TOK * D_M;

  // ---- workspace: 80 MB ----
  char* p = (char*)d_ws;
  const size_t MB = 1024 * 1024;
  unsigned short* WqT_h = (unsigned short*)(p + 0 * MB);
  unsigned short* WqT_l = (unsigned short*)(p + 2 * MB);
  unsigned short* WkT_h = (unsigned short*)(p + 4 * MB);
  unsigned short* WkT_l = (unsigned short*)(p + 6 * MB);
  unsigned short* WvT_h = (unsigned short*)(p + 8 * MB);
  unsigned short* WvT_l = (unsigned short*)(p + 10 * MB);
  unsigned short* WoT_h = (unsigned short*)(p + 12 * MB);
  unsigned short* WoT_l = (unsigned short*)(p + 14 * MB);
  unsigned short* qh  = (unsigned short*)(p + 16 * MB);
  unsigned short* ql  = (unsigned short*)(p + 24 * MB);
  unsigned short* kh  = (unsigned short*)(p + 32 * MB);
  unsigned short* kl  = (unsigned short*)(p + 40 * MB);
  unsigned short* vth = (unsigned short*)(p + 48 * MB);
  float*          ctxb = (float*)(p + 56 * MB);          // 16 MB
  // spare: p + 72MB .. 80MB
  // phase-2 aliases (after attention):
  float* resid = (float*)(p + 16 * MB);                  // qh+ql (16 MB)
  float* x1b   = (float*)(p + 32 * MB);                  // kh+kl (16 MB)
  unsigned short* x1c_h = (unsigned short*)(p + 48 * MB); // vth
  unsigned short* x1c_l = (unsigned short*)(p + 16 * MB); // qh   (resid dead after LN1)
  unsigned short* W1c_h = (unsigned short*)(p + 56 * MB); // ctxb (dead after Wo gemm)
  unsigned short* W1c_l = (unsigned short*)(p + 64 * MB);
  unsigned short* W2c_h = (unsigned short*)(p + 24 * MB); // ql
  unsigned short* W2c_l = (unsigned short*)(p + 72 * MB); // spare
  float* ffb = (float*)(p + 0 * MB);                     // weight region (dead after Wo gemm)

  const dim3 blk(256);

  // ---- prep: weight transposes + split ----
  transp_convert_k<<<dim3(16, 16), blk, 0, stream>>>(Wq, WqT_h, WqT_l);
  transp_convert_k<<<dim3(16, 16), blk, 0, stream>>>(Wk, WkT_h, WkT_l);
  transp_convert_k<<<dim3(16, 16), blk, 0, stream>>>(Wv, WvT_h, WvT_l);
  transp_convert_k<<<dim3(16, 16), blk, 0, stream>>>(Wo, WoT_h, WoT_l);

  // ---- QKV projections: Q,K -> split bf16; V -> transposed bf16 ----
  gemm_split_k<1><<<dim3(TOK / 128, D_M / 128), blk, 0, stream>>>(
      x, WqT_h, WqT_l, bq, nullptr, qh, ql, TOK, D_M, D_M);
  gemm_split_k<1><<<dim3(TOK / 128, D_M / 128), blk, 0, stream>>>(
      x, WkT_h, WkT_l, bk, nullptr, kh, kl, TOK, D_M, D_M);
  gemm_split_k<2><<<dim3(TOK / 128, D_M / 128), blk, 0, stream>>>(
      x, WvT_h, WvT_l, bv, nullptr, vth, nullptr, TOK, D_M, D_M);

  // ---- fused attention ----
  fused_attn_k<<<dim3(SQ / 64, BB * NH), blk, 0, stream>>>(qh, ql, kh, kl, vth, attn, ctxb);

  // ---- Wo projection + LN1 ----
  gemm_split_k<0><<<dim3(TOK / 128, D_M / 128), blk, 0, stream>>>(
      ctxb, WoT_h, WoT_l, bo, resid, nullptr, nullptr, TOK, D_M, D_M);
  add_ln_kernel<<<dim3(TOK), blk, 0, stream>>>(x, resid, g1, be1, x1b);

  // ---- pre-split x1, W1, W2; per-head FF + LN2 ----
  const int n4_act = TOK * D_M / 4;   // 1,048,576
  convert_split_k<<<dim3(n4_act / 256), blk, 0, stream>>>(x1b, x1c_h, x1c_l, n4_act);
  convert_split_k<<<dim3(n4_act / 256), blk, 0, stream>>>(W1, W1c_h, W1c_l, n4_act);
  convert_split_k<<<dim3(n4_act / 256), blk, 0, stream>>>(W2, W2c_h, W2c_l, n4_act);
  ff_split_k<<<dim3(TOK / 128, NH), blk, 0, stream>>>(x1c_h, x1c_l, W1c_h, W1c_l, b1,
                                                      W2c_h, W2c_l, b2, ffb);
  add_ln_kernel<<<dim3(TOK), blk, 0, stream>>>(x1b, ffb, g2, be2, y_out);
}

// Round 6
// 809.951 us; speedup vs baseline: 3.3676x; 1.0604x over previous
//
#include <hip/hip_runtime.h>
#include <cstddef>

#define D_M 1024
#define NH 16
#define HD 64
#define FFD 4096
#define SQ 2048
#define BB 2
#define TOK (BB*SQ)   // 4096
#define EPS 1e-5f

typedef __attribute__((ext_vector_type(8))) short bf16x8;
typedef __attribute__((ext_vector_type(4))) float f32x4;

__device__ inline unsigned short f32_bf16_rne(float f) {
  unsigned int u = __float_as_uint(f);
  unsigned int r = (u + 0x7fffu + ((u >> 16) & 1u)) >> 16;
  return (unsigned short)r;
}
__device__ inline float bf16_f32(unsigned short h) {
  return __uint_as_float(((unsigned int)h) << 16);
}
__device__ inline void split_f4(float4 v, ushort4& h, ushort4& l) {
  h.x = f32_bf16_rne(v.x); l.x = f32_bf16_rne(v.x - bf16_f32(h.x));
  h.y = f32_bf16_rne(v.y); l.y = f32_bf16_rne(v.y - bf16_f32(h.y));
  h.z = f32_bf16_rne(v.z); l.z = f32_bf16_rne(v.z - bf16_f32(h.z));
  h.w = f32_bf16_rne(v.w); l.w = f32_bf16_rne(v.w - bf16_f32(h.w));
}

__device__ inline float wave_sum16(float v) {
  v += __shfl_xor(v, 1); v += __shfl_xor(v, 2);
  v += __shfl_xor(v, 4); v += __shfl_xor(v, 8);
  return v;
}
__device__ inline float wave_sum(float v) {
  #pragma unroll
  for (int m = 32; m >= 1; m >>= 1) v += __shfl_xor(v, m);
  return v;
}

// ---------------- fp32 -> (hi,lo) bf16 split, layout-preserving ----------------
__global__ __launch_bounds__(256)
void convert_split_k(const float* __restrict__ src, unsigned short* __restrict__ hi,
                     unsigned short* __restrict__ lo, int n4) {
  int i = blockIdx.x * 256 + threadIdx.x;
  if (i >= n4) return;
  float4 v = ((const float4*)src)[i];
  ushort4 h, l;
  split_f4(v, h, l);
  ((ushort4*)hi)[i] = h;
  ((ushort4*)lo)[i] = l;
}

// ---------------- W[K=1024][N=1024] fp32 -> WT hi/lo bf16 [N][K] ----------------
__global__ __launch_bounds__(256)
void transp_convert_k(const float* __restrict__ W, unsigned short* __restrict__ hiT,
                      unsigned short* __restrict__ loT) {
  __shared__ float tile[64][65];
  const int bn = blockIdx.x * 64;
  const int bk = blockIdx.y * 64;
  const int t = threadIdx.x;
  #pragma unroll
  for (int i = 0; i < 4; ++i) {
    int r = (t >> 4) + i * 16, c = (t & 15) * 4;
    float4 v = *(const float4*)&W[(size_t)(bk + r) * D_M + bn + c];
    tile[r][c] = v.x; tile[r][c + 1] = v.y; tile[r][c + 2] = v.z; tile[r][c + 3] = v.w;
  }
  __syncthreads();
  #pragma unroll
  for (int i = 0; i < 4; ++i) {
    int n = (t >> 4) + i * 16, k = (t & 15) * 4;
    float4 v = {tile[k][n], tile[k + 1][n], tile[k + 2][n], tile[k + 3][n]};
    ushort4 h, l;
    split_f4(v, h, l);
    *(ushort4*)&hiT[(size_t)(bn + n) * D_M + bk + k] = h;
    *(ushort4*)&loT[(size_t)(bn + n) * D_M + bk + k] = l;
  }
}

// ------- projection GEMM, 64x128 tile, all operands pre-split bf16 hi/lo -------
// A [M][K] hi/lo, B [N][K] hi/lo. MODE 0: C fp32. MODE 1: split hi/lo out.
// MODE 2: hi-only, V-transposed [b][h][d][s].
template<int MODE>
__global__ __launch_bounds__(256)
void proj_gemm_k(const unsigned short* __restrict__ Ahi_g, const unsigned short* __restrict__ Alo_g,
                 const unsigned short* __restrict__ Bhi, const unsigned short* __restrict__ Blo,
                 const float* __restrict__ bias, float* __restrict__ C,
                 unsigned short* __restrict__ Ohi, unsigned short* __restrict__ Olo,
                 int M, int N, int K) {
  constexpr int LDK = 40;
  __shared__ unsigned short Ah[64 * LDK], Al[64 * LDK];
  __shared__ unsigned short Bh[128 * LDK], Bl[128 * LDK];
  const int tid = threadIdx.x;
  const int wave = tid >> 6, lane = tid & 63;
  const int wm = (wave >> 1) * 32, wn = (wave & 1) * 64;
  const int bm = blockIdx.x * 64, bn = blockIdx.y * 128;

  f32x4 acc[2][4] = {};
  const int sr = tid >> 2, sk = (tid & 3) * 8;
  const int l15 = lane & 15, k8 = (lane >> 4) * 8;

  for (int k0 = 0; k0 < K; k0 += 32) {
    *(uint4*)&Ah[sr * LDK + sk] = *(const uint4*)&Ahi_g[(size_t)(bm + sr) * K + k0 + sk];
    *(uint4*)&Al[sr * LDK + sk] = *(const uint4*)&Alo_g[(size_t)(bm + sr) * K + k0 + sk];
    #pragma unroll
    for (int c = 0; c < 2; ++c) {
      int r = sr + c * 64;
      *(uint4*)&Bh[r * LDK + sk] = *(const uint4*)&Bhi[(size_t)(bn + r) * K + k0 + sk];
      *(uint4*)&Bl[r * LDK + sk] = *(const uint4*)&Blo[(size_t)(bn + r) * K + k0 + sk];
    }
    __syncthreads();
    bf16x8 af[2][2], bfr[4][2];
    #pragma unroll
    for (int m = 0; m < 2; ++m) {
      af[m][0] = *(bf16x8*)&Ah[(wm + m * 16 + l15) * LDK + k8];
      af[m][1] = *(bf16x8*)&Al[(wm + m * 16 + l15) * LDK + k8];
    }
    #pragma unroll
    for (int n = 0; n < 4; ++n) {
      bfr[n][0] = *(bf16x8*)&Bh[(wn + n * 16 + l15) * LDK + k8];
      bfr[n][1] = *(bf16x8*)&Bl[(wn + n * 16 + l15) * LDK + k8];
    }
    #pragma unroll
    for (int m = 0; m < 2; ++m)
      #pragma unroll
      for (int n = 0; n < 4; ++n) {
        acc[m][n] = __builtin_amdgcn_mfma_f32_16x16x32_bf16(af[m][0], bfr[n][0], acc[m][n], 0, 0, 0);
        acc[m][n] = __builtin_amdgcn_mfma_f32_16x16x32_bf16(af[m][0], bfr[n][1], acc[m][n], 0, 0, 0);
        acc[m][n] = __builtin_amdgcn_mfma_f32_16x16x32_bf16(af[m][1], bfr[n][0], acc[m][n], 0, 0, 0);
      }
    __syncthreads();
  }
  // C layout: col = lane&15, row = (lane>>4)*4 + r
  const int cl = lane & 15, rb = (lane >> 4) * 4;
  #pragma unroll
  for (int n = 0; n < 4; ++n) {
    int col = bn + wn + n * 16 + cl;
    float bv = bias[col];
    #pragma unroll
    for (int m = 0; m < 2; ++m) {
      if (MODE == 2) {
        int row0 = bm + wm + m * 16 + rb;
        ushort4 hv;
        hv.x = f32_bf16_rne(acc[m][n][0] + bv); hv.y = f32_bf16_rne(acc[m][n][1] + bv);
        hv.z = f32_bf16_rne(acc[m][n][2] + bv); hv.w = f32_bf16_rne(acc[m][n][3] + bv);
        size_t idx = (((size_t)(row0 >> 11) * NH + (col >> 6)) * HD + (col & 63)) * SQ + (row0 & 2047);
        *(ushort4*)&Ohi[idx] = hv;
      } else {
        #pragma unroll
        for (int r = 0; r < 4; ++r) {
          int row = bm + wm + m * 16 + rb + r;
          float v = acc[m][n][r] + bv;
          if (MODE == 0) {
            C[(size_t)row * N + col] = v;
          } else {
            unsigned short h = f32_bf16_rne(v);
            Ohi[(size_t)row * N + col] = h;
            Olo[(size_t)row * N + col] = f32_bf16_rne(v - bf16_f32(h));
          }
        }
      }
    }
  }
}

// ---------------- fused attention: scores -> softmax -> attn write + P@V ----------------
// qh/ql, kh/kl: split bf16 [TOK][1024]; vth: bf16 V transposed [bh*64+d][2048]
// attn out fp32 [B,H,S,S]; ctx out split bf16 hi/lo [TOK][1024]
__global__ __launch_bounds__(256)
void fused_attn_k(const unsigned short* __restrict__ qh, const unsigned short* __restrict__ ql,
                  const unsigned short* __restrict__ kh, const unsigned short* __restrict__ kl,
                  const unsigned short* __restrict__ vth,
                  float* __restrict__ attn,
                  unsigned short* __restrict__ ctxh, unsigned short* __restrict__ ctxl) {
  constexpr int LDK = 72;
  __shared__ unsigned short Kth[64 * LDK], Ktl[64 * LDK];
  __shared__ unsigned short Vts[64 * LDK], Ph[64 * LDK];
  const int tid = threadIdx.x, wave = tid >> 6, lane = tid & 63;
  const int l15 = lane & 15, kq = lane >> 4;
  const int bh = blockIdx.y, b = bh >> 4;
  const int h = bh & 15;
  const int q0 = blockIdx.x * 64;

  const size_t qoff = (size_t)(b * SQ + q0 + wave * 16 + l15) * D_M + h * HD + kq * 8;
  bf16x8 qfh[2], qfl[2];
  qfh[0] = *(const bf16x8*)&qh[qoff];      qfh[1] = *(const bf16x8*)&qh[qoff + 32];
  qfl[0] = *(const bf16x8*)&ql[qoff];      qfl[1] = *(const bf16x8*)&ql[qoff + 32];

  const size_t kbase = (size_t)(b * SQ) * D_M + h * HD;
  const size_t vbase = (size_t)bh * HD * SQ;
  const int srow = tid >> 2, sc = (tid & 3) * 16;

  // ---------- pass A: l[r] = sum_k exp(s) (hi-only scores; max term cancels) ----------
  float lsum[4] = {0.f, 0.f, 0.f, 0.f};
  for (int t = 0; t < SQ / 64; ++t) {
    const int k0 = t * 64;
    __syncthreads();
    {
      const unsigned short* src = &kh[kbase + (size_t)(k0 + srow) * D_M + sc];
      *(uint4*)&Kth[srow * LDK + sc] = *(const uint4*)src;
      *(uint4*)&Kth[srow * LDK + sc + 8] = *(const uint4*)(src + 8);
    }
    __syncthreads();
    #pragma unroll
    for (int n = 0; n < 4; ++n) {
      bf16x8 kb0 = *(bf16x8*)&Kth[(n * 16 + l15) * LDK + kq * 8];
      bf16x8 kb1 = *(bf16x8*)&Kth[(n * 16 + l15) * LDK + 32 + kq * 8];
      f32x4 s = {};
      s = __builtin_amdgcn_mfma_f32_16x16x32_bf16(qfh[0], kb0, s, 0, 0, 0);
      s = __builtin_amdgcn_mfma_f32_16x16x32_bf16(qfh[1], kb1, s, 0, 0, 0);
      #pragma unroll
      for (int r = 0; r < 4; ++r) lsum[r] += __expf(s[r] * 0.125f);
    }
  }
  float invl[4];
  #pragma unroll
  for (int r = 0; r < 4; ++r) invl[r] = 1.0f / wave_sum16(lsum[r]);

  // ---------- pass B: split scores, write attn, accumulate ctx ----------
  f32x4 cacc[4] = {};
  const size_t abase = ((size_t)bh * SQ + q0 + wave * 16) * SQ;
  for (int t = 0; t < SQ / 64; ++t) {
    const int k0 = t * 64;
    __syncthreads();
    {
      const unsigned short* srch = &kh[kbase + (size_t)(k0 + srow) * D_M + sc];
      const unsigned short* srcl = &kl[kbase + (size_t)(k0 + srow) * D_M + sc];
      const unsigned short* srcv = &vth[vbase + (size_t)srow * SQ + k0 + sc];
      *(uint4*)&Kth[srow * LDK + sc] = *(const uint4*)srch;
      *(uint4*)&Kth[srow * LDK + sc + 8] = *(const uint4*)(srch + 8);
      *(uint4*)&Ktl[srow * LDK + sc] = *(const uint4*)srcl;
      *(uint4*)&Ktl[srow * LDK + sc + 8] = *(const uint4*)(srcl + 8);
      *(uint4*)&Vts[srow * LDK + sc] = *(const uint4*)srcv;
      *(uint4*)&Vts[srow * LDK + sc + 8] = *(const uint4*)(srcv + 8);
    }
    __syncthreads();
    #pragma unroll
    for (int n = 0; n < 4; ++n) {
      bf16x8 kbh0 = *(bf16x8*)&Kth[(n * 16 + l15) * LDK + kq * 8];
      bf16x8 kbh1 = *(bf16x8*)&Kth[(n * 16 + l15) * LDK + 32 + kq * 8];
      bf16x8 kbl0 = *(bf16x8*)&Ktl[(n * 16 + l15) * LDK + kq * 8];
      bf16x8 kbl1 = *(bf16x8*)&Ktl[(n * 16 + l15) * LDK + 32 + kq * 8];
      f32x4 s = {};
      s = __builtin_amdgcn_mfma_f32_16x16x32_bf16(qfh[0], kbh0, s, 0, 0, 0);
      s = __builtin_amdgcn_mfma_f32_16x16x32_bf16(qfh[1], kbh1, s, 0, 0, 0);
      s = __builtin_amdgcn_mfma_f32_16x16x32_bf16(qfh[0], kbl0, s, 0, 0, 0);
      s = __builtin_amdgcn_mfma_f32_16x16x32_bf16(qfh[1], kbl1, s, 0, 0, 0);
      s = __builtin_amdgcn_mfma_f32_16x16x32_bf16(qfl[0], kbh0, s, 0, 0, 0);
      s = __builtin_amdgcn_mfma_f32_16x16x32_bf16(qfl[1], kbh1, s, 0, 0, 0);
      #pragma unroll
      for (int r = 0; r < 4; ++r) {
        const int qrl = kq * 4 + r;
        float p = __expf(s[r] * 0.125f) * invl[r];
        attn[abase + (size_t)qrl * SQ + k0 + n * 16 + l15] = p;
        Ph[(wave * 16 + qrl) * LDK + n * 16 + l15] = f32_bf16_rne(p);
      }
    }
    __syncthreads();
    bf16x8 pa0 = *(bf16x8*)&Ph[(wave * 16 + l15) * LDK + kq * 8];
    bf16x8 pa1 = *(bf16x8*)&Ph[(wave * 16 + l15) * LDK + 32 + kq * 8];
    #pragma unroll
    for (int n = 0; n < 4; ++n) {
      bf16x8 vb0 = *(bf16x8*)&Vts[(n * 16 + l15) * LDK + kq * 8];
      bf16x8 vb1 = *(bf16x8*)&Vts[(n * 16 + l15) * LDK + 32 + kq * 8];
      // swapped operands: D[d][q] -> lane col = q, rows = d (contiguous stores)
      cacc[n] = __builtin_amdgcn_mfma_f32_16x16x32_bf16(vb0, pa0, cacc[n], 0, 0, 0);
      cacc[n] = __builtin_amdgcn_mfma_f32_16x16x32_bf16(vb1, pa1, cacc[n], 0, 0, 0);
    }
  }
  // ctx epilogue: q = wave*16 + l15, d = n*16 + kq*4 + r (contiguous in r)
  #pragma unroll
  for (int n = 0; n < 4; ++n) {
    float4 v = {cacc[n][0], cacc[n][1], cacc[n][2], cacc[n][3]};
    ushort4 hh, ll;
    split_f4(v, hh, ll);
    size_t off = (size_t)(b * SQ + q0 + wave * 16 + l15) * D_M + h * HD + n * 16 + kq * 4;
    *(ushort4*)&ctxh[off] = hh;
    *(ushort4*)&ctxl[off] = ll;
  }
}

// ---------------- per-head FF, split-bf16 MFMA, all inputs pre-split ----------------
__global__ __launch_bounds__(256)
void ff_split_k(const unsigned short* __restrict__ x1h, const unsigned short* __restrict__ x1l,
                const unsigned short* __restrict__ W1h_, const unsigned short* __restrict__ W1l_,
                const float* __restrict__ b1,
                const unsigned short* __restrict__ W2h_, const unsigned short* __restrict__ W2l_,
                const float* __restrict__ b2, float* __restrict__ out) {
  constexpr int LDW = 72;
  constexpr int LDH = 40;
  __shared__ unsigned short W1sh[2][32 * LDW], W1sl[2][32 * LDW];
  __shared__ unsigned short W2sh[2][64 * LDH], W2sl[2][64 * LDH];
  __shared__ unsigned short Hh[128 * LDH], Hl[128 * LDH];

  const int tid = threadIdx.x;
  const int wave = tid >> 6, lane = tid & 63;
  const int wm = wave >> 1, wf = wave & 1, wd = wave & 1;
  const int h = blockIdx.y;
  const int m0 = blockIdx.x * 128;
  const int row16 = lane & 15, kq = lane >> 4;

  const size_t w1base = (size_t)h * FFD * HD;
  const size_t w2base = (size_t)h * HD * FFD;
  const int r1 = tid >> 3, k1 = (tid & 7) * 8;
  const int r2 = tid >> 2, f2 = (tid & 3) * 8;

  bf16x8 xf[4][2][2];
  #pragma unroll
  for (int m = 0; m < 4; ++m)
    #pragma unroll
    for (int ks = 0; ks < 2; ++ks) {
      size_t gof = (size_t)(m0 + wm * 64 + m * 16 + row16) * D_M + h * HD + ks * 32 + kq * 8;
      xf[m][ks][0] = *(const bf16x8*)&x1h[gof];
      xf[m][ks][1] = *(const bf16x8*)&x1l[gof];
    }

  {
    *(uint4*)&W1sh[0][r1 * LDW + k1] = *(const uint4*)&W1h_[w1base + (size_t)r1 * HD + k1];
    *(uint4*)&W1sl[0][r1 * LDW + k1] = *(const uint4*)&W1l_[w1base + (size_t)r1 * HD + k1];
    *(uint4*)&W2sh[0][r2 * LDH + f2] = *(const uint4*)&W2h_[w2base + (size_t)r2 * FFD + f2];
    *(uint4*)&W2sl[0][r2 * LDH + f2] = *(const uint4*)&W2l_[w2base + (size_t)r2 * FFD + f2];
  }
  __syncthreads();

  f32x4 ffacc[4][2] = {};

  for (int ch = 0; ch < FFD / 32; ++ch) {
    const int buf = ch & 1;
    if (ch + 1 < FFD / 32) {
      const int f0n = (ch + 1) * 32;
      *(uint4*)&W1sh[buf ^ 1][r1 * LDW + k1] = *(const uint4*)&W1h_[w1base + (size_t)(f0n + r1) * HD + k1];
      *(uint4*)&W1sl[buf ^ 1][r1 * LDW + k1] = *(const uint4*)&W1l_[w1base + (size_t)(f0n + r1) * HD + k1];
      *(uint4*)&W2sh[buf ^ 1][r2 * LDH + f2] = *(const uint4*)&W2h_[w2base + (size_t)r2 * FFD + f0n + f2];
      *(uint4*)&W2sl[buf ^ 1][r2 * LDH + f2] = *(const uint4*)&W2l_[w2base + (size_t)r2 * FFD + f0n + f2];
    }
    f32x4 hacc[4] = {};
    #pragma unroll
    for (int ks = 0; ks < 2; ++ks) {
      bf16x8 w1h = *(bf16x8*)&W1sh[buf][(wf * 16 + row16) * LDW + ks * 32 + kq * 8];
      bf16x8 w1l = *(bf16x8*)&W1sl[buf][(wf * 16 + row16) * LDW + ks * 32 + kq * 8];
      #pragma unroll
      for (int m = 0; m < 4; ++m) {
        hacc[m] = __builtin_amdgcn_mfma_f32_16x16x32_bf16(xf[m][ks][0], w1h, hacc[m], 0, 0, 0);
        hacc[m] = __builtin_amdgcn_mfma_f32_16x16x32_bf16(xf[m][ks][0], w1l, hacc[m], 0, 0, 0);
        hacc[m] = __builtin_amdgcn_mfma_f32_16x16x32_bf16(xf[m][ks][1], w1h, hacc[m], 0, 0, 0);
      }
    }
    {
      const int fl = wf * 16 + row16;
      const float b1v = b1[(size_t)h * FFD + ch * 32 + fl];
      #pragma unroll
      for (int m = 0; m < 4; ++m) {
        #pragma unroll
        for (int r = 0; r < 4; ++r) {
          float hv = fmaxf(hacc[m][r] + b1v, 0.0f);
          unsigned short hh = f32_bf16_rne(hv);
          unsigned short hl = f32_bf16_rne(hv - bf16_f32(hh));
          int rw = wm * 64 + m * 16 + kq * 4 + r;
          Hh[rw * LDH + fl] = hh;
          Hl[rw * LDH + fl] = hl;
        }
      }
    }
    __syncthreads();
    bf16x8 hfr[4][2];
    #pragma unroll
    for (int m = 0; m < 4; ++m) {
      hfr[m][0] = *(bf16x8*)&Hh[(wm * 64 + m * 16 + row16) * LDH + kq * 8];
      hfr[m][1] = *(bf16x8*)&Hl[(wm * 64 + m * 16 + row16) * LDH + kq * 8];
    }
    #pragma unroll
    for (int n = 0; n < 2; ++n) {
      bf16x8 w2h = *(bf16x8*)&W2sh[buf][(wd * 32 + n * 16 + row16) * LDH + kq * 8];
      bf16x8 w2l = *(bf16x8*)&W2sl[buf][(wd * 32 + n * 16 + row16) * LDH + kq * 8];
      #pragma unroll
      for (int m = 0; m < 4; ++m) {
        ffacc[m][n] = __builtin_amdgcn_mfma_f32_16x16x32_bf16(hfr[m][0], w2h, ffacc[m][n], 0, 0, 0);
        ffacc[m][n] = __builtin_amdgcn_mfma_f32_16x16x32_bf16(hfr[m][0], w2l, ffacc[m][n], 0, 0, 0);
        ffacc[m][n] = __builtin_amdgcn_mfma_f32_16x16x32_bf16(hfr[m][1], w2h, ffacc[m][n], 0, 0, 0);
      }
    }
    __syncthreads();
  }
  const int rb = (lane >> 4) * 4;
  #pragma unroll
  for (int n = 0; n < 2; ++n) {
    int dl = wd * 32 + n * 16 + row16;
    float bv = b2[(size_t)h * HD + dl];
    #pragma unroll
    for (int m = 0; m < 4; ++m) {
      #pragma unroll
      for (int r = 0; r < 4; ++r) {
        int row = m0 + wm * 64 + m * 16 + rb + r;
        out[(size_t)row * D_M + h * HD + dl] = ffacc[m][n][r] + bv;
      }
    }
  }
}

// ---------------- out = LayerNorm(a + r) * g + be (optionally + split bf16 out) ----------------
template<int SPLIT>
__global__ __launch_bounds__(256)
void add_ln_kernel(const float* __restrict__ a, const float* __restrict__ r,
                   const float* __restrict__ g, const float* __restrict__ be,
                   float* __restrict__ out,
                   unsigned short* __restrict__ oh, unsigned short* __restrict__ ol) {
  const size_t row = blockIdx.x;
  const int tid = threadIdx.x;
  __shared__ float red1[4];
  __shared__ float red2[4];
  float4 va = ((const float4*)(a + row * D_M))[tid];
  float4 vr = ((const float4*)(r + row * D_M))[tid];
  float v0 = va.x + vr.x, v1 = va.y + vr.y, v2 = va.z + vr.z, v3 = va.w + vr.w;
  float s = v0 + v1 + v2 + v3;
  float sq = v0 * v0 + v1 * v1 + v2 * v2 + v3 * v3;
  s = wave_sum(s);
  sq = wave_sum(sq);
  if ((tid & 63) == 0) { red1[tid >> 6] = s; red2[tid >> 6] = sq; }
  __syncthreads();
  s = red1[0] + red1[1] + red1[2] + red1[3];
  sq = red2[0] + red2[1] + red2[2] + red2[3];
  const float mu = s * (1.0f / D_M);
  const float var = sq * (1.0f / D_M) - mu * mu;
  float x = var + EPS;
  float rs = rsqrtf(x);
  rs = rs * (1.5f - 0.5f * x * rs * rs);
  float4 gg = ((const float4*)g)[tid];
  float4 bb = ((const float4*)be)[tid];
  float4 o = {(v0 - mu) * rs * gg.x + bb.x, (v1 - mu) * rs * gg.y + bb.y,
              (v2 - mu) * rs * gg.z + bb.z, (v3 - mu) * rs * gg.w + bb.w};
  ((float4*)(out + row * D_M))[tid] = o;
  if (SPLIT) {
    ushort4 h, l;
    split_f4(o, h, l);
    ((ushort4*)(oh + row * D_M))[tid] = h;
    ((ushort4*)(ol + row * D_M))[tid] = l;
  }
}

extern "C" void kernel_launch(void* const* d_in, const int* in_sizes, int n_in,
                              void* d_out, int out_size, void* d_ws, size_t ws_size,
                              hipStream_t stream) {
  const float* x   = (const float*)d_in[0];
  const float* Wq  = (const float*)d_in[1];
  const float* bq  = (const float*)d_in[2];
  const float* Wk  = (const float*)d_in[3];
  const float* bk  = (const float*)d_in[4];
  const float* Wv  = (const float*)d_in[5];
  const float* bv  = (const float*)d_in[6];
  const float* Wo  = (const float*)d_in[7];
  const float* bo  = (const float*)d_in[8];
  const float* W1  = (const float*)d_in[9];
  const float* b1  = (const float*)d_in[10];
  const float* W2  = (const float*)d_in[11];
  const float* b2  = (const float*)d_in[12];
  const float* g1  = (const float*)d_in[13];
  const float* be1 = (const float*)d_in[14];
  const float* g2  = (const float*)d_in[15];
  const float* be2 = (const float*)d_in[16];

  float* y_out = (float*)d_out;
  float* attn  = (float*)d_out + (size_t)TOK * D_M;

  // ---- workspace: 80 MB ----
  char* p = (char*)d_ws;
  const size_t MB = 1024 * 1024;
  unsigned short* WqT_h = (unsigned short*)(p + 0 * MB);
  unsigned short* WqT_l = (unsigned short*)(p + 2 * MB);
  unsigned short* WkT_h = (unsigned short*)(p + 4 * MB);
  unsigned short* WkT_l = (unsigned short*)(p + 6 * MB);
  unsigned short* WvT_h = (unsigned short*)(p + 8 * MB);
  unsigned short* WvT_l = (unsigned short*)(p + 10 * MB);
  unsigned short* WoT_h = (unsigned short*)(p + 12 * MB);
  unsigned short* WoT_l = (unsigned short*)(p + 14 * MB);
  unsigned short* xh  = (unsigned short*)(p + 16 * MB);
  unsigned short* xl  = (unsigned short*)(p + 24 * MB);
  unsigned short* qh  = (unsigned short*)(p + 32 * MB);
  unsigned short* ql  = (unsigned short*)(p + 40 * MB);
  unsigned short* kh  = (unsigned short*)(p + 48 * MB);
  unsigned short* kl  = (unsigned short*)(p + 56 * MB);
  unsigned short* vth = (unsigned short*)(p + 64 * MB);
  // phase aliases:
  unsigned short* ctxh = (unsigned short*)(p + 16 * MB);  // xh dead after QKV
  unsigned short* ctxl = (unsigned short*)(p + 24 * MB);  // xl dead after QKV
  float* resid = (float*)(p + 32 * MB);                   // qh+ql dead after attn (16 MB)
  float* x1b   = (float*)(p + 48 * MB);                   // kh+kl dead after attn (16 MB)
  unsigned short* x1c_h = (unsigned short*)(p + 64 * MB); // vth dead after attn
  unsigned short* x1c_l = (unsigned short*)(p + 72 * MB); // spare
  unsigned short* W1c_h = (unsigned short*)(p + 0 * MB);  // WT dead after Wo gemm
  unsigned short* W1c_l = (unsigned short*)(p + 8 * MB);
  unsigned short* W2c_h = (unsigned short*)(p + 16 * MB); // ctx dead after Wo gemm
  unsigned short* W2c_l = (unsigned short*)(p + 24 * MB);
  float* ffb = (float*)(p + 32 * MB);                     // resid dead after LN1

  const dim3 blk(256);
  const int n4_act = TOK * D_M / 4;   // 1,048,576

  // ---- prep ----
  transp_convert_k<<<dim3(16, 16), blk, 0, stream>>>(Wq, WqT_h, WqT_l);
  transp_convert_k<<<dim3(16, 16), blk, 0, stream>>>(Wk, WkT_h, WkT_l);
  transp_convert_k<<<dim3(16, 16), blk, 0, stream>>>(Wv, WvT_h, WvT_l);
  transp_convert_k<<<dim3(16, 16), blk, 0, stream>>>(Wo, WoT_h, WoT_l);
  convert_split_k<<<dim3(n4_act / 256), blk, 0, stream>>>(x, xh, xl, n4_act);

  // ---- QKV projections (64x128-tile, all pre-split) ----
  proj_gemm_k<1><<<dim3(TOK / 64, D_M / 128), blk, 0, stream>>>(
      xh, xl, WqT_h, WqT_l, bq, nullptr, qh, ql, TOK, D_M, D_M);
  proj_gemm_k<1><<<dim3(TOK / 64, D_M / 128), blk, 0, stream>>>(
      xh, xl, WkT_h, WkT_l, bk, nullptr, kh, kl, TOK, D_M, D_M);
  proj_gemm_k<2><<<dim3(TOK / 64, D_M / 128), blk, 0, stream>>>(
      xh, xl, WvT_h, WvT_l, bv, nullptr, vth, nullptr, TOK, D_M, D_M);

  // ---- fused attention (ctx emitted pre-split) ----
  fused_attn_k<<<dim3(SQ / 64, BB * NH), blk, 0, stream>>>(qh, ql, kh, kl, vth, attn, ctxh, ctxl);

  // ---- Wo projection + LN1 (LN1 emits split x1) ----
  proj_gemm_k<0><<<dim3(TOK / 64, D_M / 128), blk, 0, stream>>>(
      ctxh, ctxl, WoT_h, WoT_l, bo, resid, nullptr, nullptr, TOK, D_M, D_M);
  add_ln_kernel<1><<<dim3(TOK), blk, 0, stream>>>(x, resid, g1, be1, x1b, x1c_h, x1c_l);

  // ---- per-head FF + LN2 ----
  convert_split_k<<<dim3(n4_act / 256), blk, 0, stream>>>(W1, W1c_h, W1c_l, n4_act);
  convert_split_k<<<dim3(n4_act / 256), blk, 0, stream>>>(W2, W2c_h, W2c_l, n4_act);
  ff_split_k<<<dim3(TOK / 128, NH), blk, 0, stream>>>(x1c_h, x1c_l, W1c_h, W1c_l, b1,
                                                      W2c_h, W2c_l, b2, ffb);
  add_ln_kernel<0><<<dim3(TOK), blk, 0, stream>>>(x1b, ffb, g2, be2, y_out, nullptr, nullptr);
}

// Round 7
// 756.497 us; speedup vs baseline: 3.6055x; 1.0707x over previous
//
#include <hip/hip_runtime.h>
#include <cstddef>

#define D_M 1024
#define NH 16
#define HD 64
#define FFD 4096
#define SQ 2048
#define BB 2
#define TOK (BB*SQ)   // 4096
#define EPS 1e-5f

typedef __attribute__((ext_vector_type(8))) short bf16x8;
typedef __attribute__((ext_vector_type(4))) float f32x4;

__device__ inline unsigned short f32_bf16_rne(float f) {
  unsigned int u = __float_as_uint(f);
  unsigned int r = (u + 0x7fffu + ((u >> 16) & 1u)) >> 16;
  return (unsigned short)r;
}
__device__ inline float bf16_f32(unsigned short h) {
  return __uint_as_float(((unsigned int)h) << 16);
}
__device__ inline void split_f4(float4 v, ushort4& h, ushort4& l) {
  h.x = f32_bf16_rne(v.x); l.x = f32_bf16_rne(v.x - bf16_f32(h.x));
  h.y = f32_bf16_rne(v.y); l.y = f32_bf16_rne(v.y - bf16_f32(h.y));
  h.z = f32_bf16_rne(v.z); l.z = f32_bf16_rne(v.z - bf16_f32(h.z));
  h.w = f32_bf16_rne(v.w); l.w = f32_bf16_rne(v.w - bf16_f32(h.w));
}

__device__ inline float wave_sum(float v) {
  #pragma unroll
  for (int m = 32; m >= 1; m >>= 1) v += __shfl_xor(v, m);
  return v;
}

// ---------------- fp32 -> (hi,lo) bf16 split, layout-preserving ----------------
__global__ __launch_bounds__(256)
void convert_split_k(const float* __restrict__ src, unsigned short* __restrict__ hi,
                     unsigned short* __restrict__ lo, int n4) {
  int i = blockIdx.x * 256 + threadIdx.x;
  if (i >= n4) return;
  float4 v = ((const float4*)src)[i];
  ushort4 h, l;
  split_f4(v, h, l);
  ((ushort4*)hi)[i] = h;
  ((ushort4*)lo)[i] = l;
}

// ---------------- W[K=1024][N=1024] fp32 -> WT hi/lo bf16 [N][K] ----------------
__global__ __launch_bounds__(256)
void transp_convert_k(const float* __restrict__ W, unsigned short* __restrict__ hiT,
                      unsigned short* __restrict__ loT) {
  __shared__ float tile[64][65];
  const int bn = blockIdx.x * 64;
  const int bk = blockIdx.y * 64;
  const int t = threadIdx.x;
  #pragma unroll
  for (int i = 0; i < 4; ++i) {
    int r = (t >> 4) + i * 16, c = (t & 15) * 4;
    float4 v = *(const float4*)&W[(size_t)(bk + r) * D_M + bn + c];
    tile[r][c] = v.x; tile[r][c + 1] = v.y; tile[r][c + 2] = v.z; tile[r][c + 3] = v.w;
  }
  __syncthreads();
  #pragma unroll
  for (int i = 0; i < 4; ++i) {
    int n = (t >> 4) + i * 16, k = (t & 15) * 4;
    float4 v = {tile[k][n], tile[k + 1][n], tile[k + 2][n], tile[k + 3][n]};
    ushort4 h, l;
    split_f4(v, h, l);
    *(ushort4*)&hiT[(size_t)(bn + n) * D_M + bk + k] = h;
    *(ushort4*)&loT[(size_t)(bn + n) * D_M + bk + k] = l;
  }
}

// ------- projection GEMM, 64x128 tile, all operands pre-split bf16 hi/lo -------
// A [M][K] hi/lo, B [N][K] hi/lo. MODE 0: C fp32. MODE 1: split hi/lo out.
// MODE 2: hi-only, V-transposed [b][h][d][s].
// MODE 0/1 use swapped MFMA (D col = token) for vectorized epilogues.
template<int MODE>
__global__ __launch_bounds__(256)
void proj_gemm_k(const unsigned short* __restrict__ Ahi_g, const unsigned short* __restrict__ Alo_g,
                 const unsigned short* __restrict__ Bhi, const unsigned short* __restrict__ Blo,
                 const float* __restrict__ bias, float* __restrict__ C,
                 unsigned short* __restrict__ Ohi, unsigned short* __restrict__ Olo,
                 int M, int N, int K) {
  constexpr int LDK = 40;
  __shared__ unsigned short Ah[64 * LDK], Al[64 * LDK];
  __shared__ unsigned short Bh[128 * LDK], Bl[128 * LDK];
  const int tid = threadIdx.x;
  const int wave = tid >> 6, lane = tid & 63;
  const int wm = (wave >> 1) * 32, wn = (wave & 1) * 64;
  const int bm = blockIdx.x * 64, bn = blockIdx.y * 128;

  f32x4 acc[2][4] = {};
  const int sr = tid >> 2, sk = (tid & 3) * 8;
  const int l15 = lane & 15, k8 = (lane >> 4) * 8;

  for (int k0 = 0; k0 < K; k0 += 32) {
    *(uint4*)&Ah[sr * LDK + sk] = *(const uint4*)&Ahi_g[(size_t)(bm + sr) * K + k0 + sk];
    *(uint4*)&Al[sr * LDK + sk] = *(const uint4*)&Alo_g[(size_t)(bm + sr) * K + k0 + sk];
    #pragma unroll
    for (int c = 0; c < 2; ++c) {
      int r = sr + c * 64;
      *(uint4*)&Bh[r * LDK + sk] = *(const uint4*)&Bhi[(size_t)(bn + r) * K + k0 + sk];
      *(uint4*)&Bl[r * LDK + sk] = *(const uint4*)&Blo[(size_t)(bn + r) * K + k0 + sk];
    }
    __syncthreads();
    bf16x8 af[2][2], bfr[4][2];
    #pragma unroll
    for (int m = 0; m < 2; ++m) {
      af[m][0] = *(bf16x8*)&Ah[(wm + m * 16 + l15) * LDK + k8];
      af[m][1] = *(bf16x8*)&Al[(wm + m * 16 + l15) * LDK + k8];
    }
    #pragma unroll
    for (int n = 0; n < 4; ++n) {
      bfr[n][0] = *(bf16x8*)&Bh[(wn + n * 16 + l15) * LDK + k8];
      bfr[n][1] = *(bf16x8*)&Bl[(wn + n * 16 + l15) * LDK + k8];
    }
    #pragma unroll
    for (int m = 0; m < 2; ++m)
      #pragma unroll
      for (int n = 0; n < 4; ++n) {
        if (MODE == 2) {
          acc[m][n] = __builtin_amdgcn_mfma_f32_16x16x32_bf16(af[m][0], bfr[n][0], acc[m][n], 0, 0, 0);
          acc[m][n] = __builtin_amdgcn_mfma_f32_16x16x32_bf16(af[m][0], bfr[n][1], acc[m][n], 0, 0, 0);
          acc[m][n] = __builtin_amdgcn_mfma_f32_16x16x32_bf16(af[m][1], bfr[n][0], acc[m][n], 0, 0, 0);
        } else {
          // swapped: D col = token (l15), row = n-col (kq*4+r)
          acc[m][n] = __builtin_amdgcn_mfma_f32_16x16x32_bf16(bfr[n][0], af[m][0], acc[m][n], 0, 0, 0);
          acc[m][n] = __builtin_amdgcn_mfma_f32_16x16x32_bf16(bfr[n][1], af[m][0], acc[m][n], 0, 0, 0);
          acc[m][n] = __builtin_amdgcn_mfma_f32_16x16x32_bf16(bfr[n][0], af[m][1], acc[m][n], 0, 0, 0);
        }
      }
    __syncthreads();
  }
  const int kq4 = (lane >> 4) * 4;
  if (MODE == 2) {
    const int cl = lane & 15, rb = kq4;
    #pragma unroll
    for (int n = 0; n < 4; ++n) {
      int col = bn + wn + n * 16 + cl;
      float bv = bias[col];
      #pragma unroll
      for (int m = 0; m < 2; ++m) {
        int row0 = bm + wm + m * 16 + rb;
        ushort4 hv;
        hv.x = f32_bf16_rne(acc[m][n][0] + bv); hv.y = f32_bf16_rne(acc[m][n][1] + bv);
        hv.z = f32_bf16_rne(acc[m][n][2] + bv); hv.w = f32_bf16_rne(acc[m][n][3] + bv);
        size_t idx = (((size_t)(row0 >> 11) * NH + (col >> 6)) * HD + (col & 63)) * SQ + (row0 & 2047);
        *(ushort4*)&Ohi[idx] = hv;
      }
    }
  } else {
    #pragma unroll
    for (int n = 0; n < 4; ++n) {
      int colb = bn + wn + n * 16 + kq4;
      float4 bv4 = *(const float4*)&bias[colb];
      #pragma unroll
      for (int m = 0; m < 2; ++m) {
        int tok = bm + wm + m * 16 + l15;
        float4 v = {acc[m][n][0] + bv4.x, acc[m][n][1] + bv4.y,
                    acc[m][n][2] + bv4.z, acc[m][n][3] + bv4.w};
        if (MODE == 0) {
          *(float4*)&C[(size_t)tok * N + colb] = v;
        } else {
          ushort4 h, l;
          split_f4(v, h, l);
          *(ushort4*)&Ohi[(size_t)tok * N + colb] = h;
          *(ushort4*)&Olo[(size_t)tok * N + colb] = l;
        }
      }
    }
  }
}

// ---------------- fused attention (swapped QK^T: D col = q, rows = k) ----------------
// qh/ql, kh/kl: split bf16 [TOK][1024]; vth: bf16 V transposed [bh*64+d][2048]
// attn out fp32 [B,H,S,S]; ctx out split bf16 hi/lo [TOK][1024]
__global__ __launch_bounds__(256)
void fused_attn_k(const unsigned short* __restrict__ qh, const unsigned short* __restrict__ ql,
                  const unsigned short* __restrict__ kh, const unsigned short* __restrict__ kl,
                  const unsigned short* __restrict__ vth,
                  float* __restrict__ attn,
                  unsigned short* __restrict__ ctxh, unsigned short* __restrict__ ctxl) {
  constexpr int LDK = 72;
  __shared__ unsigned short Kth[64 * LDK], Ktl[64 * LDK];
  __shared__ unsigned short Vts[64 * LDK], Ph[64 * LDK];
  const int tid = threadIdx.x, wave = tid >> 6, lane = tid & 63;
  const int l15 = lane & 15, kq = lane >> 4;
  const int bh = blockIdx.y, b = bh >> 4;
  const int h = bh & 15;
  const int q0 = blockIdx.x * 64;

  const size_t qoff = (size_t)(b * SQ + q0 + wave * 16 + l15) * D_M + h * HD + kq * 8;
  bf16x8 qfh[2], qfl[2];
  qfh[0] = *(const bf16x8*)&qh[qoff];      qfh[1] = *(const bf16x8*)&qh[qoff + 32];
  qfl[0] = *(const bf16x8*)&ql[qoff];      qfl[1] = *(const bf16x8*)&ql[qoff + 32];

  const size_t kbase = (size_t)(b * SQ) * D_M + h * HD;
  const size_t vbase = (size_t)bh * HD * SQ;
  const int srow = tid >> 2, sc = (tid & 3) * 16;

  // ---------- pass A: lsum (hi-only scores; max term cancels) ----------
  float lsum = 0.f;
  for (int t = 0; t < SQ / 64; ++t) {
    __syncthreads();
    {
      const unsigned short* src = &kh[kbase + (size_t)(t * 64 + srow) * D_M + sc];
      *(uint4*)&Kth[srow * LDK + sc] = *(const uint4*)src;
      *(uint4*)&Kth[srow * LDK + sc + 8] = *(const uint4*)(src + 8);
    }
    __syncthreads();
    #pragma unroll
    for (int n = 0; n < 4; ++n) {
      bf16x8 kb0 = *(bf16x8*)&Kth[(n * 16 + l15) * LDK + kq * 8];
      bf16x8 kb1 = *(bf16x8*)&Kth[(n * 16 + l15) * LDK + 32 + kq * 8];
      f32x4 s = {};
      s = __builtin_amdgcn_mfma_f32_16x16x32_bf16(kb0, qfh[0], s, 0, 0, 0);
      s = __builtin_amdgcn_mfma_f32_16x16x32_bf16(kb1, qfh[1], s, 0, 0, 0);
      #pragma unroll
      for (int r = 0; r < 4; ++r) lsum += __expf(s[r] * 0.125f);
    }
  }
  lsum += __shfl_xor(lsum, 16);
  lsum += __shfl_xor(lsum, 32);
  const float invl = 1.0f / lsum;

  // ---------- pass B: split scores, vectorized attn/Ph writes, PV ----------
  f32x4 cacc[4] = {};
  const size_t abase_q = ((size_t)bh * SQ + q0 + wave * 16 + l15) * SQ;
  for (int t = 0; t < SQ / 64; ++t) {
    const int k0 = t * 64;
    __syncthreads();
    {
      const unsigned short* srch = &kh[kbase + (size_t)(k0 + srow) * D_M + sc];
      const unsigned short* srcl = &kl[kbase + (size_t)(k0 + srow) * D_M + sc];
      const unsigned short* srcv = &vth[vbase + (size_t)srow * SQ + k0 + sc];
      *(uint4*)&Kth[srow * LDK + sc] = *(const uint4*)srch;
      *(uint4*)&Kth[srow * LDK + sc + 8] = *(const uint4*)(srch + 8);
      *(uint4*)&Ktl[srow * LDK + sc] = *(const uint4*)srcl;
      *(uint4*)&Ktl[srow * LDK + sc + 8] = *(const uint4*)(srcl + 8);
      *(uint4*)&Vts[srow * LDK + sc] = *(const uint4*)srcv;
      *(uint4*)&Vts[srow * LDK + sc + 8] = *(const uint4*)(srcv + 8);
    }
    __syncthreads();
    #pragma unroll
    for (int n = 0; n < 4; ++n) {
      bf16x8 kbh0 = *(bf16x8*)&Kth[(n * 16 + l15) * LDK + kq * 8];
      bf16x8 kbh1 = *(bf16x8*)&Kth[(n * 16 + l15) * LDK + 32 + kq * 8];
      bf16x8 kbl0 = *(bf16x8*)&Ktl[(n * 16 + l15) * LDK + kq * 8];
      bf16x8 kbl1 = *(bf16x8*)&Ktl[(n * 16 + l15) * LDK + 32 + kq * 8];
      f32x4 s = {};
      s = __builtin_amdgcn_mfma_f32_16x16x32_bf16(kbh0, qfh[0], s, 0, 0, 0);
      s = __builtin_amdgcn_mfma_f32_16x16x32_bf16(kbh1, qfh[1], s, 0, 0, 0);
      s = __builtin_amdgcn_mfma_f32_16x16x32_bf16(kbl0, qfh[0], s, 0, 0, 0);
      s = __builtin_amdgcn_mfma_f32_16x16x32_bf16(kbl1, qfh[1], s, 0, 0, 0);
      s = __builtin_amdgcn_mfma_f32_16x16x32_bf16(kbh0, qfl[0], s, 0, 0, 0);
      s = __builtin_amdgcn_mfma_f32_16x16x32_bf16(kbh1, qfl[1], s, 0, 0, 0);
      float4 pv;
      pv.x = __expf(s[0] * 0.125f) * invl;
      pv.y = __expf(s[1] * 0.125f) * invl;
      pv.z = __expf(s[2] * 0.125f) * invl;
      pv.w = __expf(s[3] * 0.125f) * invl;
      *(float4*)&attn[abase_q + k0 + n * 16 + kq * 4] = pv;
      ushort4 p4;
      p4.x = f32_bf16_rne(pv.x); p4.y = f32_bf16_rne(pv.y);
      p4.z = f32_bf16_rne(pv.z); p4.w = f32_bf16_rne(pv.w);
      *(ushort4*)&Ph[(wave * 16 + l15) * LDK + n * 16 + kq * 4] = p4;
    }
    __syncthreads();
    bf16x8 pa0 = *(bf16x8*)&Ph[(wave * 16 + l15) * LDK + kq * 8];
    bf16x8 pa1 = *(bf16x8*)&Ph[(wave * 16 + l15) * LDK + 32 + kq * 8];
    #pragma unroll
    for (int n = 0; n < 4; ++n) {
      bf16x8 vb0 = *(bf16x8*)&Vts[(n * 16 + l15) * LDK + kq * 8];
      bf16x8 vb1 = *(bf16x8*)&Vts[(n * 16 + l15) * LDK + 32 + kq * 8];
      cacc[n] = __builtin_amdgcn_mfma_f32_16x16x32_bf16(vb0, pa0, cacc[n], 0, 0, 0);
      cacc[n] = __builtin_amdgcn_mfma_f32_16x16x32_bf16(vb1, pa1, cacc[n], 0, 0, 0);
    }
  }
  // ctx epilogue: q = wave*16 + l15, d = n*16 + kq*4 + r (contiguous in r)
  #pragma unroll
  for (int n = 0; n < 4; ++n) {
    float4 v = {cacc[n][0], cacc[n][1], cacc[n][2], cacc[n][3]};
    ushort4 hh, ll;
    split_f4(v, hh, ll);
    size_t off = (size_t)(b * SQ + q0 + wave * 16 + l15) * D_M + h * HD + n * 16 + kq * 4;
    *(ushort4*)&ctxh[off] = hh;
    *(ushort4*)&ctxl[off] = ll;
  }
}

// ---------------- per-head FF, split-bf16 MFMA, swapped phases (vector stores) ----------------
__global__ __launch_bounds__(256)
void ff_split_k(const unsigned short* __restrict__ x1h, const unsigned short* __restrict__ x1l,
                const unsigned short* __restrict__ W1h_, const unsigned short* __restrict__ W1l_,
                const float* __restrict__ b1,
                const unsigned short* __restrict__ W2h_, const unsigned short* __restrict__ W2l_,
                const float* __restrict__ b2, float* __restrict__ out) {
  constexpr int LDW = 72;
  constexpr int LDH = 40;
  __shared__ unsigned short W1sh[2][32 * LDW], W1sl[2][32 * LDW];
  __shared__ unsigned short W2sh[2][64 * LDH], W2sl[2][64 * LDH];
  __shared__ unsigned short Hh[128 * LDH], Hl[128 * LDH];

  const int tid = threadIdx.x;
  const int wave = tid >> 6, lane = tid & 63;
  const int wm = wave >> 1, wf = wave & 1, wd = wave & 1;
  const int h = blockIdx.y;
  const int m0 = blockIdx.x * 128;
  const int l15 = lane & 15, kq = lane >> 4;

  const size_t w1base = (size_t)h * FFD * HD;
  const size_t w2base = (size_t)h * HD * FFD;
  const int r1 = tid >> 3, k1 = (tid & 7) * 8;
  const int r2 = tid >> 2, f2 = (tid & 3) * 8;

  bf16x8 xf[4][2][2];
  #pragma unroll
  for (int m = 0; m < 4; ++m)
    #pragma unroll
    for (int ks = 0; ks < 2; ++ks) {
      size_t gof = (size_t)(m0 + wm * 64 + m * 16 + l15) * D_M + h * HD + ks * 32 + kq * 8;
      xf[m][ks][0] = *(const bf16x8*)&x1h[gof];
      xf[m][ks][1] = *(const bf16x8*)&x1l[gof];
    }

  {
    *(uint4*)&W1sh[0][r1 * LDW + k1] = *(const uint4*)&W1h_[w1base + (size_t)r1 * HD + k1];
    *(uint4*)&W1sl[0][r1 * LDW + k1] = *(const uint4*)&W1l_[w1base + (size_t)r1 * HD + k1];
    *(uint4*)&W2sh[0][r2 * LDH + f2] = *(const uint4*)&W2h_[w2base + (size_t)r2 * FFD + f2];
    *(uint4*)&W2sl[0][r2 * LDH + f2] = *(const uint4*)&W2l_[w2base + (size_t)r2 * FFD + f2];
  }
  __syncthreads();

  f32x4 ffacc[4][2] = {};

  for (int ch = 0; ch < FFD / 32; ++ch) {
    const int buf = ch & 1;
    if (ch + 1 < FFD / 32) {
      const int f0n = (ch + 1) * 32;
      *(uint4*)&W1sh[buf ^ 1][r1 * LDW + k1] = *(const uint4*)&W1h_[w1base + (size_t)(f0n + r1) * HD + k1];
      *(uint4*)&W1sl[buf ^ 1][r1 * LDW + k1] = *(const uint4*)&W1l_[w1base + (size_t)(f0n + r1) * HD + k1];
      *(uint4*)&W2sh[buf ^ 1][r2 * LDH + f2] = *(const uint4*)&W2h_[w2base + (size_t)r2 * FFD + f0n + f2];
      *(uint4*)&W2sl[buf ^ 1][r2 * LDH + f2] = *(const uint4*)&W2l_[w2base + (size_t)r2 * FFD + f0n + f2];
    }
    // phase 1 (swapped): hacc[m] has col = token (l15), rows = f (kq*4+r)
    f32x4 hacc[4] = {};
    #pragma unroll
    for (int ks = 0; ks < 2; ++ks) {
      bf16x8 w1h = *(bf16x8*)&W1sh[buf][(wf * 16 + l15) * LDW + ks * 32 + kq * 8];
      bf16x8 w1l = *(bf16x8*)&W1sl[buf][(wf * 16 + l15) * LDW + ks * 32 + kq * 8];
      #pragma unroll
      for (int m = 0; m < 4; ++m) {
        hacc[m] = __builtin_amdgcn_mfma_f32_16x16x32_bf16(w1h, xf[m][ks][0], hacc[m], 0, 0, 0);
        hacc[m] = __builtin_amdgcn_mfma_f32_16x16x32_bf16(w1l, xf[m][ks][0], hacc[m], 0, 0, 0);
        hacc[m] = __builtin_amdgcn_mfma_f32_16x16x32_bf16(w1h, xf[m][ks][1], hacc[m], 0, 0, 0);
      }
    }
    // bias + relu + split -> H (vectorized ushort4 stores)
    {
      const int fb = wf * 16 + kq * 4;
      float4 b1v = *(const float4*)&b1[(size_t)h * FFD + ch * 32 + fb];
      const float bb[4] = {b1v.x, b1v.y, b1v.z, b1v.w};
      #pragma unroll
      for (int m = 0; m < 4; ++m) {
        int tok = wm * 64 + m * 16 + l15;
        float4 hv = {fmaxf(hacc[m][0] + bb[0], 0.0f), fmaxf(hacc[m][1] + bb[1], 0.0f),
                     fmaxf(hacc[m][2] + bb[2], 0.0f), fmaxf(hacc[m][3] + bb[3], 0.0f)};
        ushort4 hh, hl;
        split_f4(hv, hh, hl);
        *(ushort4*)&Hh[tok * LDH + fb] = hh;
        *(ushort4*)&Hl[tok * LDH + fb] = hl;
      }
    }
    __syncthreads();
    bf16x8 hfr[4][2];
    #pragma unroll
    for (int m = 0; m < 4; ++m) {
      hfr[m][0] = *(bf16x8*)&Hh[(wm * 64 + m * 16 + l15) * LDH + kq * 8];
      hfr[m][1] = *(bf16x8*)&Hl[(wm * 64 + m * 16 + l15) * LDH + kq * 8];
    }
    // phase 2 (swapped): ffacc[m][n] col = token (l15), rows = d (kq*4+r)
    #pragma unroll
    for (int n = 0; n < 2; ++n) {
      bf16x8 w2h = *(bf16x8*)&W2sh[buf][(wd * 32 + n * 16 + l15) * LDH + kq * 8];
      bf16x8 w2l = *(bf16x8*)&W2sl[buf][(wd * 32 + n * 16 + l15) * LDH + kq * 8];
      #pragma unroll
      for (int m = 0; m < 4; ++m) {
        ffacc[m][n] = __builtin_amdgcn_mfma_f32_16x16x32_bf16(w2h, hfr[m][0], ffacc[m][n], 0, 0, 0);
        ffacc[m][n] = __builtin_amdgcn_mfma_f32_16x16x32_bf16(w2l, hfr[m][0], ffacc[m][n], 0, 0, 0);
        ffacc[m][n] = __builtin_amdgcn_mfma_f32_16x16x32_bf16(w2h, hfr[m][1], ffacc[m][n], 0, 0, 0);
      }
    }
    __syncthreads();
  }
  // epilogue: vectorized float4 stores (d contiguous)
  #pragma unroll
  for (int n = 0; n < 2; ++n) {
    int db = wd * 32 + n * 16 + kq * 4;
    float4 b2v = *(const float4*)&b2[(size_t)h * HD + db];
    #pragma unroll
    for (int m = 0; m < 4; ++m) {
      int tok = m0 + wm * 64 + m * 16 + l15;
      float4 v = {ffacc[m][n][0] + b2v.x, ffacc[m][n][1] + b2v.y,
                  ffacc[m][n][2] + b2v.z, ffacc[m][n][3] + b2v.w};
      *(float4*)&out[(size_t)tok * D_M + h * HD + db] = v;
    }
  }
}

// ---------------- out = LayerNorm(a + r) * g + be (optionally + split bf16 out) ----------------
template<int SPLIT>
__global__ __launch_bounds__(256)
void add_ln_kernel(const float* __restrict__ a, const float* __restrict__ r,
                   const float* __restrict__ g, const float* __restrict__ be,
                   float* __restrict__ out,
                   unsigned short* __restrict__ oh, unsigned short* __restrict__ ol) {
  const size_t row = blockIdx.x;
  const int tid = threadIdx.x;
  __shared__ float red1[4];
  __shared__ float red2[4];
  float4 va = ((const float4*)(a + row * D_M))[tid];
  float4 vr = ((const float4*)(r + row * D_M))[tid];
  float v0 = va.x + vr.x, v1 = va.y + vr.y, v2 = va.z + vr.z, v3 = va.w + vr.w;
  float s = v0 + v1 + v2 + v3;
  float sq = v0 * v0 + v1 * v1 + v2 * v2 + v3 * v3;
  s = wave_sum(s);
  sq = wave_sum(sq);
  if ((tid & 63) == 0) { red1[tid >> 6] = s; red2[tid >> 6] = sq; }
  __syncthreads();
  s = red1[0] + red1[1] + red1[2] + red1[3];
  sq = red2[0] + red2[1] + red2[2] + red2[3];
  const float mu = s * (1.0f / D_M);
  const float var = sq * (1.0f / D_M) - mu * mu;
  float x = var + EPS;
  float rs = rsqrtf(x);
  rs = rs * (1.5f - 0.5f * x * rs * rs);
  float4 gg = ((const float4*)g)[tid];
  float4 bb = ((const float4*)be)[tid];
  float4 o = {(v0 - mu) * rs * gg.x + bb.x, (v1 - mu) * rs * gg.y + bb.y,
              (v2 - mu) * rs * gg.z + bb.z, (v3 - mu) * rs * gg.w + bb.w};
  ((float4*)(out + row * D_M))[tid] = o;
  if (SPLIT) {
    ushort4 h, l;
    split_f4(o, h, l);
    ((ushort4*)(oh + row * D_M))[tid] = h;
    ((ushort4*)(ol + row * D_M))[tid] = l;
  }
}

extern "C" void kernel_launch(void* const* d_in, const int* in_sizes, int n_in,
                              void* d_out, int out_size, void* d_ws, size_t ws_size,
                              hipStream_t stream) {
  const float* x   = (const float*)d_in[0];
  const float* Wq  = (const float*)d_in[1];
  const float* bq  = (const float*)d_in[2];
  const float* Wk  = (const float*)d_in[3];
  const float* bk  = (const float*)d_in[4];
  const float* Wv  = (const float*)d_in[5];
  const float* bv  = (const float*)d_in[6];
  const float* Wo  = (const float*)d_in[7];
  const float* bo  = (const float*)d_in[8];
  const float* W1  = (const float*)d_in[9];
  const float* b1  = (const float*)d_in[10];
  const float* W2  = (const float*)d_in[11];
  const float* b2  = (const float*)d_in[12];
  const float* g1  = (const float*)d_in[13];
  const float* be1 = (const float*)d_in[14];
  const float* g2  = (const float*)d_in[15];
  const float* be2 = (const float*)d_in[16];

  float* y_out = (float*)d_out;
  float* attn  = (float*)d_out + (size_t)TOK * D_M;

  // ---- workspace: 80 MB ----
  char* p = (char*)d_ws;
  const size_t MB = 1024 * 1024;
  unsigned short* WqT_h = (unsigned short*)(p + 0 * MB);
  unsigned short* WqT_l = (unsigned short*)(p + 2 * MB);
  unsigned short* WkT_h = (unsigned short*)(p + 4 * MB);
  unsigned short* WkT_l = (unsigned short*)(p + 6 * MB);
  unsigned short* WvT_h = (unsigned short*)(p + 8 * MB);
  unsigned short* WvT_l = (unsigned short*)(p + 10 * MB);
  unsigned short* WoT_h = (unsigned short*)(p + 12 * MB);
  unsigned short* WoT_l = (unsigned short*)(p + 14 * MB);
  unsigned short* xh  = (unsigned short*)(p + 16 * MB);
  unsigned short* xl  = (unsigned short*)(p + 24 * MB);
  unsigned short* qh  = (unsigned short*)(p + 32 * MB);
  unsigned short* ql  = (unsigned short*)(p + 40 * MB);
  unsigned short* kh  = (unsigned short*)(p + 48 * MB);
  unsigned short* kl  = (unsigned short*)(p + 56 * MB);
  unsigned short* vth = (unsigned short*)(p + 64 * MB);
  // phase aliases:
  unsigned short* ctxh = (unsigned short*)(p + 16 * MB);  // xh dead after QKV
  unsigned short* ctxl = (unsigned short*)(p + 24 * MB);  // xl dead after QKV
  float* resid = (float*)(p + 32 * MB);                   // qh+ql dead after attn (16 MB)
  float* x1b   = (float*)(p + 48 * MB);                   // kh+kl dead after attn (16 MB)
  unsigned short* x1c_h = (unsigned short*)(p + 64 * MB); // vth dead after attn
  unsigned short* x1c_l = (unsigned short*)(p + 72 * MB); // spare
  unsigned short* W1c_h = (unsigned short*)(p + 0 * MB);  // WT dead after Wo gemm
  unsigned short* W1c_l = (unsigned short*)(p + 8 * MB);
  unsigned short* W2c_h = (unsigned short*)(p + 16 * MB); // ctx dead after Wo gemm
  unsigned short* W2c_l = (unsigned short*)(p + 24 * MB);
  float* ffb = (float*)(p + 32 * MB);                     // resid dead after LN1

  const dim3 blk(256);
  const int n4_act = TOK * D_M / 4;   // 1,048,576

  // ---- prep ----
  transp_convert_k<<<dim3(16, 16), blk, 0, stream>>>(Wq, WqT_h, WqT_l);
  transp_convert_k<<<dim3(16, 16), blk, 0, stream>>>(Wk, WkT_h, WkT_l);
  transp_convert_k<<<dim3(16, 16), blk, 0, stream>>>(Wv, WvT_h, WvT_l);
  transp_convert_k<<<dim3(16, 16), blk, 0, stream>>>(Wo, WoT_h, WoT_l);
  convert_split_k<<<dim3(n4_act / 256), blk, 0, stream>>>(x, xh, xl, n4_act);

  // ---- QKV projections (64x128-tile, all pre-split) ----
  proj_gemm_k<1><<<dim3(TOK / 64, D_M / 128), blk, 0, stream>>>(
      xh, xl, WqT_h, WqT_l, bq, nullptr, qh, ql, TOK, D_M, D_M);
  proj_gemm_k<1><<<dim3(TOK / 64, D_M / 128), blk, 0, stream>>>(
      xh, xl, WkT_h, WkT_l, bk, nullptr, kh, kl, TOK, D_M, D_M);
  proj_gemm_k<2><<<dim3(TOK / 64, D_M / 128), blk, 0, stream>>>(
      xh, xl, WvT_h, WvT_l, bv, nullptr, vth, nullptr, TOK, D_M, D_M);

  // ---- fused attention (ctx emitted pre-split) ----
  fused_attn_k<<<dim3(SQ / 64, BB * NH), blk, 0, stream>>>(qh, ql, kh, kl, vth, attn, ctxh, ctxl);

  // ---- Wo projection + LN1 (LN1 emits split x1) ----
  proj_gemm_k<0><<<dim3(TOK / 64, D_M / 128), blk, 0, stream>>>(
      ctxh, ctxl, WoT_h, WoT_l, bo, resid, nullptr, nullptr, TOK, D_M, D_M);
  add_ln_kernel<1><<<dim3(TOK), blk, 0, stream>>>(x, resid, g1, be1, x1b, x1c_h, x1c_l);

  // ---- per-head FF + LN2 ----
  convert_split_k<<<dim3(n4_act / 256), blk, 0, stream>>>(W1, W1c_h, W1c_l, n4_act);
  convert_split_k<<<dim3(n4_act / 256), blk, 0, stream>>>(W2, W2c_h, W2c_l, n4_act);
  ff_split_k<<<dim3(TOK / 128, NH), blk, 0, stream>>>(x1c_h, x1c_l, W1c_h, W1c_l, b1,
                                                      W2c_h, W2c_l, b2, ffb);
  add_ln_kernel<0><<<dim3(TOK), blk, 0, stream>>>(x1b, ffb, g2, be2, y_out, nullptr, nullptr);
}

// Round 9
// 675.159 us; speedup vs baseline: 4.0399x; 1.1205x over previous
//
#include <hip/hip_runtime.h>
#include <cstddef>

#define D_M 1024
#define NH 16
#define HD 64
#define FFD 4096
#define SQ 2048
#define BB 2
#define TOK (BB*SQ)   // 4096
#define EPS 1e-5f

typedef __attribute__((ext_vector_type(8))) short bf16x8;
typedef __attribute__((ext_vector_type(4))) float f32x4;

__device__ inline unsigned short f32_bf16_rne(float f) {
  unsigned int u = __float_as_uint(f);
  unsigned int r = (u + 0x7fffu + ((u >> 16) & 1u)) >> 16;
  return (unsigned short)r;
}
__device__ inline float bf16_f32(unsigned short h) {
  return __uint_as_float(((unsigned int)h) << 16);
}
__device__ inline void split_f4(float4 v, ushort4& h, ushort4& l) {
  h.x = f32_bf16_rne(v.x); l.x = f32_bf16_rne(v.x - bf16_f32(h.x));
  h.y = f32_bf16_rne(v.y); l.y = f32_bf16_rne(v.y - bf16_f32(h.y));
  h.z = f32_bf16_rne(v.z); l.z = f32_bf16_rne(v.z - bf16_f32(h.z));
  h.w = f32_bf16_rne(v.w); l.w = f32_bf16_rne(v.w - bf16_f32(h.w));
}

__device__ inline float wave_sum(float v) {
  #pragma unroll
  for (int m = 32; m >= 1; m >>= 1) v += __shfl_xor(v, m);
  return v;
}

// ---------------- fp32 -> (hi,lo) bf16 split, layout-preserving ----------------
__global__ __launch_bounds__(256)
void convert_split_k(const float* __restrict__ src, unsigned short* __restrict__ hi,
                     unsigned short* __restrict__ lo, int n4) {
  int i = blockIdx.x * 256 + threadIdx.x;
  if (i >= n4) return;
  float4 v = ((const float4*)src)[i];
  ushort4 h, l;
  split_f4(v, h, l);
  ((ushort4*)hi)[i] = h;
  ((ushort4*)lo)[i] = l;
}

// ---------------- 4x W[1024][1024] fp32 -> WT hi/lo bf16 [N][K], one launch ----------------
__global__ __launch_bounds__(256)
void transp4_k(const float* __restrict__ W0, const float* __restrict__ W1_,
               const float* __restrict__ W2_, const float* __restrict__ W3,
               unsigned short* __restrict__ h0, unsigned short* __restrict__ l0,
               unsigned short* __restrict__ h1, unsigned short* __restrict__ l1,
               unsigned short* __restrict__ h2, unsigned short* __restrict__ l2,
               unsigned short* __restrict__ h3, unsigned short* __restrict__ l3) {
  const float* W; unsigned short* hT; unsigned short* lT;
  switch (blockIdx.z) {
    case 0: W = W0; hT = h0; lT = l0; break;
    case 1: W = W1_; hT = h1; lT = l1; break;
    case 2: W = W2_; hT = h2; lT = l2; break;
    default: W = W3; hT = h3; lT = l3; break;
  }
  __shared__ float tile[64][65];
  const int bn = blockIdx.x * 64;
  const int bk = blockIdx.y * 64;
  const int t = threadIdx.x;
  #pragma unroll
  for (int i = 0; i < 4; ++i) {
    int r = (t >> 4) + i * 16, c = (t & 15) * 4;
    float4 v = *(const float4*)&W[(size_t)(bk + r) * D_M + bn + c];
    tile[r][c] = v.x; tile[r][c + 1] = v.y; tile[r][c + 2] = v.z; tile[r][c + 3] = v.w;
  }
  __syncthreads();
  #pragma unroll
  for (int i = 0; i < 4; ++i) {
    int n = (t >> 4) + i * 16, k = (t & 15) * 4;
    float4 v = {tile[k][n], tile[k + 1][n], tile[k + 2][n], tile[k + 3][n]};
    ushort4 h, l;
    split_f4(v, h, l);
    *(ushort4*)&hT[(size_t)(bn + n) * D_M + bk + k] = h;
    *(ushort4*)&lT[(size_t)(bn + n) * D_M + bk + k] = l;
  }
}

// ---------------- merged QKV GEMM: one A-tile staging serves 3 weight sets ----------------
// x pre-split [TOK][1024]; weights pre-split [N][K]. Q,K -> split [M][N]; V -> transposed bf16.
__global__ __launch_bounds__(256)
void qkv_gemm_k(const unsigned short* __restrict__ xh_g, const unsigned short* __restrict__ xl_g,
                const unsigned short* __restrict__ Bqh, const unsigned short* __restrict__ Bql,
                const unsigned short* __restrict__ Bkh, const unsigned short* __restrict__ Bkl,
                const unsigned short* __restrict__ Bvh, const unsigned short* __restrict__ Bvl,
                const float* __restrict__ bq, const float* __restrict__ bk, const float* __restrict__ bv,
                unsigned short* __restrict__ qh, unsigned short* __restrict__ ql,
                unsigned short* __restrict__ kh, unsigned short* __restrict__ kl,
                unsigned short* __restrict__ vth) {
  constexpr int LDK = 40;
  __shared__ unsigned short Ah[64 * LDK], Al[64 * LDK];
  __shared__ unsigned short Bh[3][128 * LDK], Bl[3][128 * LDK];
  const int tid = threadIdx.x;
  const int wave = tid >> 6, lane = tid & 63;
  const int wm = (wave >> 1) * 32, wn = (wave & 1) * 64;
  const int bm = blockIdx.x * 64, bn = blockIdx.y * 128;
  const int K = D_M;

  f32x4 acc[3][2][4] = {};
  const int sr = tid >> 2, sk = (tid & 3) * 8;
  const int l15 = lane & 15, k8 = (lane >> 4) * 8;

  const unsigned short* Bhp[3] = {Bqh, Bkh, Bvh};
  const unsigned short* Blp[3] = {Bql, Bkl, Bvl};

  for (int k0 = 0; k0 < K; k0 += 32) {
    *(uint4*)&Ah[sr * LDK + sk] = *(const uint4*)&xh_g[(size_t)(bm + sr) * K + k0 + sk];
    *(uint4*)&Al[sr * LDK + sk] = *(const uint4*)&xl_g[(size_t)(bm + sr) * K + k0 + sk];
    #pragma unroll
    for (int s = 0; s < 3; ++s) {
      #pragma unroll
      for (int c = 0; c < 2; ++c) {
        int r = sr + c * 64;
        *(uint4*)&Bh[s][r * LDK + sk] = *(const uint4*)&Bhp[s][(size_t)(bn + r) * K + k0 + sk];
        *(uint4*)&Bl[s][r * LDK + sk] = *(const uint4*)&Blp[s][(size_t)(bn + r) * K + k0 + sk];
      }
    }
    __syncthreads();
    bf16x8 af[2][2];
    #pragma unroll
    for (int m = 0; m < 2; ++m) {
      af[m][0] = *(bf16x8*)&Ah[(wm + m * 16 + l15) * LDK + k8];
      af[m][1] = *(bf16x8*)&Al[(wm + m * 16 + l15) * LDK + k8];
    }
    #pragma unroll
    for (int s = 0; s < 3; ++s) {
      #pragma unroll
      for (int n = 0; n < 4; ++n) {
        bf16x8 b0 = *(bf16x8*)&Bh[s][(wn + n * 16 + l15) * LDK + k8];
        bf16x8 b1 = *(bf16x8*)&Bl[s][(wn + n * 16 + l15) * LDK + k8];
        #pragma unroll
        for (int m = 0; m < 2; ++m) {
          if (s == 2) {  // V: unswapped (D col = weight col, rows = token)
            acc[s][m][n] = __builtin_amdgcn_mfma_f32_16x16x32_bf16(af[m][0], b0, acc[s][m][n], 0, 0, 0);
            acc[s][m][n] = __builtin_amdgcn_mfma_f32_16x16x32_bf16(af[m][0], b1, acc[s][m][n], 0, 0, 0);
            acc[s][m][n] = __builtin_amdgcn_mfma_f32_16x16x32_bf16(af[m][1], b0, acc[s][m][n], 0, 0, 0);
          } else {       // Q,K: swapped (D col = token, rows = weight col)
            acc[s][m][n] = __builtin_amdgcn_mfma_f32_16x16x32_bf16(b0, af[m][0], acc[s][m][n], 0, 0, 0);
            acc[s][m][n] = __builtin_amdgcn_mfma_f32_16x16x32_bf16(b1, af[m][0], acc[s][m][n], 0, 0, 0);
            acc[s][m][n] = __builtin_amdgcn_mfma_f32_16x16x32_bf16(b0, af[m][1], acc[s][m][n], 0, 0, 0);
          }
        }
      }
    }
    __syncthreads();
  }
  const int kq4 = (lane >> 4) * 4;
  // Q, K epilogues (swapped layout, vectorized split stores)
  #pragma unroll
  for (int s = 0; s < 2; ++s) {
    const float* bias = (s == 0) ? bq : bk;
    unsigned short* oh = (s == 0) ? qh : kh;
    unsigned short* ol = (s == 0) ? ql : kl;
    #pragma unroll
    for (int n = 0; n < 4; ++n) {
      int colb = bn + wn + n * 16 + kq4;
      float4 bv4 = *(const float4*)&bias[colb];
      #pragma unroll
      for (int m = 0; m < 2; ++m) {
        int tok = bm + wm + m * 16 + l15;
        float4 v = {acc[s][m][n][0] + bv4.x, acc[s][m][n][1] + bv4.y,
                    acc[s][m][n][2] + bv4.z, acc[s][m][n][3] + bv4.w};
        ushort4 h, l;
        split_f4(v, h, l);
        *(ushort4*)&oh[(size_t)tok * D_M + colb] = h;
        *(ushort4*)&ol[(size_t)tok * D_M + colb] = l;
      }
    }
  }
  // V epilogue (unswapped, transposed store [b][h][d][s])
  #pragma unroll
  for (int n = 0; n < 4; ++n) {
    int col = bn + wn + n * 16 + l15;
    float bvv = bv[col];
    #pragma unroll
    for (int m = 0; m < 2; ++m) {
      int row0 = bm + wm + m * 16 + kq4;
      ushort4 hv;
      hv.x = f32_bf16_rne(acc[2][m][n][0] + bvv); hv.y = f32_bf16_rne(acc[2][m][n][1] + bvv);
      hv.z = f32_bf16_rne(acc[2][m][n][2] + bvv); hv.w = f32_bf16_rne(acc[2][m][n][3] + bvv);
      size_t idx = (((size_t)(row0 >> 11) * NH + (col >> 6)) * HD + (col & 63)) * SQ + (row0 & 2047);
      *(ushort4*)&vth[idx] = hv;
    }
  }
}

// ------- projection GEMM (Wo), 64x128 tile, all operands pre-split, swapped MFMA -------
__global__ __launch_bounds__(256)
void proj_gemm_k(const unsigned short* __restrict__ Ahi_g, const unsigned short* __restrict__ Alo_g,
                 const unsigned short* __restrict__ Bhi, const unsigned short* __restrict__ Blo,
                 const float* __restrict__ bias, float* __restrict__ C,
                 int M, int N, int K) {
  constexpr int LDK = 40;
  __shared__ unsigned short Ah[64 * LDK], Al[64 * LDK];
  __shared__ unsigned short Bh[128 * LDK], Bl[128 * LDK];
  const int tid = threadIdx.x;
  const int wave = tid >> 6, lane = tid & 63;
  const int wm = (wave >> 1) * 32, wn = (wave & 1) * 64;
  const int bm = blockIdx.x * 64, bn = blockIdx.y * 128;

  f32x4 acc[2][4] = {};
  const int sr = tid >> 2, sk = (tid & 3) * 8;
  const int l15 = lane & 15, k8 = (lane >> 4) * 8;

  for (int k0 = 0; k0 < K; k0 += 32) {
    *(uint4*)&Ah[sr * LDK + sk] = *(const uint4*)&Ahi_g[(size_t)(bm + sr) * K + k0 + sk];
    *(uint4*)&Al[sr * LDK + sk] = *(const uint4*)&Alo_g[(size_t)(bm + sr) * K + k0 + sk];
    #pragma unroll
    for (int c = 0; c < 2; ++c) {
      int r = sr + c * 64;
      *(uint4*)&Bh[r * LDK + sk] = *(const uint4*)&Bhi[(size_t)(bn + r) * K + k0 + sk];
      *(uint4*)&Bl[r * LDK + sk] = *(const uint4*)&Blo[(size_t)(bn + r) * K + k0 + sk];
    }
    __syncthreads();
    bf16x8 af[2][2], bfr[4][2];
    #pragma unroll
    for (int m = 0; m < 2; ++m) {
      af[m][0] = *(bf16x8*)&Ah[(wm + m * 16 + l15) * LDK + k8];
      af[m][1] = *(bf16x8*)&Al[(wm + m * 16 + l15) * LDK + k8];
    }
    #pragma unroll
    for (int n = 0; n < 4; ++n) {
      bfr[n][0] = *(bf16x8*)&Bh[(wn + n * 16 + l15) * LDK + k8];
      bfr[n][1] = *(bf16x8*)&Bl[(wn + n * 16 + l15) * LDK + k8];
    }
    #pragma unroll
    for (int m = 0; m < 2; ++m)
      #pragma unroll
      for (int n = 0; n < 4; ++n) {
        acc[m][n] = __builtin_amdgcn_mfma_f32_16x16x32_bf16(bfr[n][0], af[m][0], acc[m][n], 0, 0, 0);
        acc[m][n] = __builtin_amdgcn_mfma_f32_16x16x32_bf16(bfr[n][1], af[m][0], acc[m][n], 0, 0, 0);
        acc[m][n] = __builtin_amdgcn_mfma_f32_16x16x32_bf16(bfr[n][0], af[m][1], acc[m][n], 0, 0, 0);
      }
    __syncthreads();
  }
  const int kq4 = (lane >> 4) * 4;
  #pragma unroll
  for (int n = 0; n < 4; ++n) {
    int colb = bn + wn + n * 16 + kq4;
    float4 bv4 = *(const float4*)&bias[colb];
    #pragma unroll
    for (int m = 0; m < 2; ++m) {
      int tok = bm + wm + m * 16 + l15;
      float4 v = {acc[m][n][0] + bv4.x, acc[m][n][1] + bv4.y,
                  acc[m][n][2] + bv4.z, acc[m][n][3] + bv4.w};
      *(float4*)&C[(size_t)tok * N + colb] = v;
    }
  }
}

// ---------------- fused attention, q-tile 128, double-buffered K/V staging ----------------
__global__ __launch_bounds__(256)
void fused_attn_k(const unsigned short* __restrict__ qh, const unsigned short* __restrict__ ql,
                  const unsigned short* __restrict__ kh, const unsigned short* __restrict__ kl,
                  const unsigned short* __restrict__ vth,
                  float* __restrict__ attn,
                  unsigned short* __restrict__ ctxh, unsigned short* __restrict__ ctxl) {
  constexpr int LDK = 72;
  constexpr int NT = SQ / 64;
  __shared__ unsigned short Kth[2][64 * LDK], Ktl[2][64 * LDK], Vts[2][64 * LDK];
  __shared__ unsigned short Ph[128 * LDK];
  const int tid = threadIdx.x, wave = tid >> 6, lane = tid & 63;
  const int l15 = lane & 15, kq = lane >> 4;
  const int bh = blockIdx.y, b = bh >> 4;
  const int h = bh & 15;
  const int q0 = blockIdx.x * 128;

  // Q fragments for 2 q-subtiles of 16 (wave owns 32 q)
  bf16x8 qfh[2][2], qfl[2][2];
  #pragma unroll
  for (int qi = 0; qi < 2; ++qi) {
    const size_t qoff = (size_t)(b * SQ + q0 + wave * 32 + qi * 16 + l15) * D_M + h * HD + kq * 8;
    qfh[qi][0] = *(const bf16x8*)&qh[qoff];  qfh[qi][1] = *(const bf16x8*)&qh[qoff + 32];
    qfl[qi][0] = *(const bf16x8*)&ql[qoff];  qfl[qi][1] = *(const bf16x8*)&ql[qoff + 32];
  }

  const size_t kbase = (size_t)(b * SQ) * D_M + h * HD;
  const size_t vbase = (size_t)bh * HD * SQ;
  const int srow = tid >> 2, sc = (tid & 3) * 16;

  // ---------- pass A: per-q row sums (hi-only scores; max term cancels) ----------
  float lsum[2] = {0.f, 0.f};
  {
    const unsigned short* src = &kh[kbase + (size_t)srow * D_M + sc];
    *(uint4*)&Kth[0][srow * LDK + sc] = *(const uint4*)src;
    *(uint4*)&Kth[0][srow * LDK + sc + 8] = *(const uint4*)(src + 8);
  }
  __syncthreads();
  for (int t = 0; t < NT; ++t) {
    const int cur = t & 1;
    const bool pf = (t + 1 < NT);
    uint4 r0, r1;
    if (pf) {
      const unsigned short* src = &kh[kbase + (size_t)((t + 1) * 64 + srow) * D_M + sc];
      r0 = *(const uint4*)src;
      r1 = *(const uint4*)(src + 8);
    }
    #pragma unroll
    for (int n = 0; n < 4; ++n) {
      bf16x8 kb0 = *(bf16x8*)&Kth[cur][(n * 16 + l15) * LDK + kq * 8];
      bf16x8 kb1 = *(bf16x8*)&Kth[cur][(n * 16 + l15) * LDK + 32 + kq * 8];
      #pragma unroll
      for (int qi = 0; qi < 2; ++qi) {
        f32x4 s = {};
        s = __builtin_amdgcn_mfma_f32_16x16x32_bf16(kb0, qfh[qi][0], s, 0, 0, 0);
        s = __builtin_amdgcn_mfma_f32_16x16x32_bf16(kb1, qfh[qi][1], s, 0, 0, 0);
        #pragma unroll
        for (int r = 0; r < 4; ++r) lsum[qi] += __expf(s[r] * 0.125f);
      }
    }
    if (pf) {
      *(uint4*)&Kth[cur ^ 1][srow * LDK + sc] = r0;
      *(uint4*)&Kth[cur ^ 1][srow * LDK + sc + 8] = r1;
    }
    __syncthreads();
  }
  float invl[2];
  #pragma unroll
  for (int qi = 0; qi < 2; ++qi) {
    float l = lsum[qi];
    l += __shfl_xor(l, 16);
    l += __shfl_xor(l, 32);
    invl[qi] = 1.0f / l;
  }

  // ---------- pass B: split scores, attn write, PV ----------
  f32x4 cacc[2][4] = {};
  {
    const unsigned short* srch = &kh[kbase + (size_t)srow * D_M + sc];
    const unsigned short* srcl = &kl[kbase + (size_t)srow * D_M + sc];
    const unsigned short* srcv = &vth[vbase + (size_t)srow * SQ + sc];
    *(uint4*)&Kth[0][srow * LDK + sc] = *(const uint4*)srch;
    *(uint4*)&Kth[0][srow * LDK + sc + 8] = *(const uint4*)(srch + 8);
    *(uint4*)&Ktl[0][srow * LDK + sc] = *(const uint4*)srcl;
    *(uint4*)&Ktl[0][srow * LDK + sc + 8] = *(const uint4*)(srcl + 8);
    *(uint4*)&Vts[0][srow * LDK + sc] = *(const uint4*)srcv;
    *(uint4*)&Vts[0][srow * LDK + sc + 8] = *(const uint4*)(srcv + 8);
  }
  __syncthreads();
  for (int t = 0; t < NT; ++t) {
    const int cur = t & 1;
    const int k0 = t * 64;
    const bool pf = (t + 1 < NT);
    uint4 rk0, rk1, rl0, rl1, rv0, rv1;
    if (pf) {
      const unsigned short* srch = &kh[kbase + (size_t)(k0 + 64 + srow) * D_M + sc];
      const unsigned short* srcl = &kl[kbase + (size_t)(k0 + 64 + srow) * D_M + sc];
      const unsigned short* srcv = &vth[vbase + (size_t)srow * SQ + k0 + 64 + sc];
      rk0 = *(const uint4*)srch; rk1 = *(const uint4*)(srch + 8);
      rl0 = *(const uint4*)srcl; rl1 = *(const uint4*)(srcl + 8);
      rv0 = *(const uint4*)srcv; rv1 = *(const uint4*)(srcv + 8);
    }
    #pragma unroll
    for (int n = 0; n < 4; ++n) {
      bf16x8 kbh0 = *(bf16x8*)&Kth[cur][(n * 16 + l15) * LDK + kq * 8];
      bf16x8 kbh1 = *(bf16x8*)&Kth[cur][(n * 16 + l15) * LDK + 32 + kq * 8];
      bf16x8 kbl0 = *(bf16x8*)&Ktl[cur][(n * 16 + l15) * LDK + kq * 8];
      bf16x8 kbl1 = *(bf16x8*)&Ktl[cur][(n * 16 + l15) * LDK + 32 + kq * 8];
      #pragma unroll
      for (int qi = 0; qi < 2; ++qi) {
        f32x4 s = {};
        s = __builtin_amdgcn_mfma_f32_16x16x32_bf16(kbh0, qfh[qi][0], s, 0, 0, 0);
        s = __builtin_amdgcn_mfma_f32_16x16x32_bf16(kbh1, qfh[qi][1], s, 0, 0, 0);
        s = __builtin_amdgcn_mfma_f32_16x16x32_bf16(kbl0, qfh[qi][0], s, 0, 0, 0);
        s = __builtin_amdgcn_mfma_f32_16x16x32_bf16(kbl1, qfh[qi][1], s, 0, 0, 0);
        s = __builtin_amdgcn_mfma_f32_16x16x32_bf16(kbh0, qfl[qi][0], s, 0, 0, 0);
        s = __builtin_amdgcn_mfma_f32_16x16x32_bf16(kbh1, qfl[qi][1], s, 0, 0, 0);
        float4 pv;
        pv.x = __expf(s[0] * 0.125f) * invl[qi];
        pv.y = __expf(s[1] * 0.125f) * invl[qi];
        pv.z = __expf(s[2] * 0.125f) * invl[qi];
        pv.w = __expf(s[3] * 0.125f) * invl[qi];
        const int qrow = wave * 32 + qi * 16 + l15;
        *(float4*)&attn[((size_t)bh * SQ + q0 + qrow) * SQ + k0 + n * 16 + kq * 4] = pv;
        ushort4 p4;
        p4.x = f32_bf16_rne(pv.x); p4.y = f32_bf16_rne(pv.y);
        p4.z = f32_bf16_rne(pv.z); p4.w = f32_bf16_rne(pv.w);
        *(ushort4*)&Ph[qrow * LDK + n * 16 + kq * 4] = p4;
      }
    }
    __syncthreads();
    #pragma unroll
    for (int qi = 0; qi < 2; ++qi) {
      bf16x8 pa0 = *(bf16x8*)&Ph[(wave * 32 + qi * 16 + l15) * LDK + kq * 8];
      bf16x8 pa1 = *(bf16x8*)&Ph[(wave * 32 + qi * 16 + l15) * LDK + 32 + kq * 8];
      #pragma unroll
      for (int n = 0; n < 4; ++n) {
        bf16x8 vb0 = *(bf16x8*)&Vts[cur][(n * 16 + l15) * LDK + kq * 8];
        bf16x8 vb1 = *(bf16x8*)&Vts[cur][(n * 16 + l15) * LDK + 32 + kq * 8];
        cacc[qi][n] = __builtin_amdgcn_mfma_f32_16x16x32_bf16(vb0, pa0, cacc[qi][n], 0, 0, 0);
        cacc[qi][n] = __builtin_amdgcn_mfma_f32_16x16x32_bf16(vb1, pa1, cacc[qi][n], 0, 0, 0);
      }
    }
    if (pf) {
      *(uint4*)&Kth[cur ^ 1][srow * LDK + sc] = rk0;
      *(uint4*)&Kth[cur ^ 1][srow * LDK + sc + 8] = rk1;
      *(uint4*)&Ktl[cur ^ 1][srow * LDK + sc] = rl0;
      *(uint4*)&Ktl[cur ^ 1][srow * LDK + sc + 8] = rl1;
      *(uint4*)&Vts[cur ^ 1][srow * LDK + sc] = rv0;
      *(uint4*)&Vts[cur ^ 1][srow * LDK + sc + 8] = rv1;
    }
    __syncthreads();
  }
  // ctx epilogue: q = q0 + wave*32 + qi*16 + l15, d = n*16 + kq*4 + r
  #pragma unroll
  for (int qi = 0; qi < 2; ++qi)
    #pragma unroll
    for (int n = 0; n < 4; ++n) {
      float4 v = {cacc[qi][n][0], cacc[qi][n][1], cacc[qi][n][2], cacc[qi][n][3]};
      ushort4 hh, ll;
      split_f4(v, hh, ll);
      size_t off = (size_t)(b * SQ + q0 + wave * 32 + qi * 16 + l15) * D_M + h * HD + n * 16 + kq * 4;
      *(ushort4*)&ctxh[off] = hh;
      *(ushort4*)&ctxl[off] = ll;
    }
}

// ---------------- per-head FF, split-bf16 MFMA, reg-staged W (issue-early/write-late) ----------------
__global__ __launch_bounds__(256)
void ff_split_k(const unsigned short* __restrict__ x1h, const unsigned short* __restrict__ x1l,
                const unsigned short* __restrict__ W1h_, const unsigned short* __restrict__ W1l_,
                const float* __restrict__ b1,
                const unsigned short* __restrict__ W2h_, const unsigned short* __restrict__ W2l_,
                const float* __restrict__ b2, float* __restrict__ out) {
  constexpr int LDW = 72;
  constexpr int LDH = 40;
  __shared__ unsigned short W1sh[2][32 * LDW], W1sl[2][32 * LDW];
  __shared__ unsigned short W2sh[2][64 * LDH], W2sl[2][64 * LDH];
  __shared__ unsigned short Hh[128 * LDH], Hl[128 * LDH];

  const int tid = threadIdx.x;
  const int wave = tid >> 6, lane = tid & 63;
  const int wm = wave >> 1, wf = wave & 1, wd = wave & 1;
  const int h = blockIdx.y;
  const int m0 = blockIdx.x * 128;
  const int l15 = lane & 15, kq = lane >> 4;

  const size_t w1base = (size_t)h * FFD * HD;
  const size_t w2base = (size_t)h * HD * FFD;
  const int r1 = tid >> 3, k1 = (tid & 7) * 8;
  const int r2 = tid >> 2, f2 = (tid & 3) * 8;

  bf16x8 xf[4][2][2];
  #pragma unroll
  for (int m = 0; m < 4; ++m)
    #pragma unroll
    for (int ks = 0; ks < 2; ++ks) {
      size_t gof = (size_t)(m0 + wm * 64 + m * 16 + l15) * D_M + h * HD + ks * 32 + kq * 8;
      xf[m][ks][0] = *(const bf16x8*)&x1h[gof];
      xf[m][ks][1] = *(const bf16x8*)&x1l[gof];
    }

  {
    *(uint4*)&W1sh[0][r1 * LDW + k1] = *(const uint4*)&W1h_[w1base + (size_t)r1 * HD + k1];
    *(uint4*)&W1sl[0][r1 * LDW + k1] = *(const uint4*)&W1l_[w1base + (size_t)r1 * HD + k1];
    *(uint4*)&W2sh[0][r2 * LDH + f2] = *(const uint4*)&W2h_[w2base + (size_t)r2 * FFD + f2];
    *(uint4*)&W2sl[0][r2 * LDH + f2] = *(const uint4*)&W2l_[w2base + (size_t)r2 * FFD + f2];
  }
  __syncthreads();

  f32x4 ffacc[4][2] = {};

  for (int ch = 0; ch < FFD / 32; ++ch) {
    const int buf = ch & 1;
    const bool pf = (ch + 1 < FFD / 32);
    uint4 w1h_r, w1l_r, w2h_r, w2l_r;
    if (pf) {
      const int f0n = (ch + 1) * 32;
      w1h_r = *(const uint4*)&W1h_[w1base + (size_t)(f0n + r1) * HD + k1];
      w1l_r = *(const uint4*)&W1l_[w1base + (size_t)(f0n + r1) * HD + k1];
      w2h_r = *(const uint4*)&W2h_[w2base + (size_t)r2 * FFD + f0n + f2];
      w2l_r = *(const uint4*)&W2l_[w2base + (size_t)r2 * FFD + f0n + f2];
    }
    // phase 1 (swapped): hacc[m] col = token (l15), rows = f (kq*4+r)
    f32x4 hacc[4] = {};
    #pragma unroll
    for (int ks = 0; ks < 2; ++ks) {
      bf16x8 w1h = *(bf16x8*)&W1sh[buf][(wf * 16 + l15) * LDW + ks * 32 + kq * 8];
      bf16x8 w1l = *(bf16x8*)&W1sl[buf][(wf * 16 + l15) * LDW + ks * 32 + kq * 8];
      #pragma unroll
      for (int m = 0; m < 4; ++m) {
        hacc[m] = __builtin_amdgcn_mfma_f32_16x16x32_bf16(w1h, xf[m][ks][0], hacc[m], 0, 0, 0);
        hacc[m] = __builtin_amdgcn_mfma_f32_16x16x32_bf16(w1l, xf[m][ks][0], hacc[m], 0, 0, 0);
        hacc[m] = __builtin_amdgcn_mfma_f32_16x16x32_bf16(w1h, xf[m][ks][1], hacc[m], 0, 0, 0);
      }
    }
    // bias + relu + split -> H (vectorized)
    {
      const int fb = wf * 16 + kq * 4;
      float4 b1v = *(const float4*)&b1[(size_t)h * FFD + ch * 32 + fb];
      const float bb[4] = {b1v.x, b1v.y, b1v.z, b1v.w};
      #pragma unroll
      for (int m = 0; m < 4; ++m) {
        int tok = wm * 64 + m * 16 + l15;
        float4 hv = {fmaxf(hacc[m][0] + bb[0], 0.0f), fmaxf(hacc[m][1] + bb[1], 0.0f),
                     fmaxf(hacc[m][2] + bb[2], 0.0f), fmaxf(hacc[m][3] + bb[3], 0.0f)};
        ushort4 hh, hl;
        split_f4(hv, hh, hl);
        *(ushort4*)&Hh[tok * LDH + fb] = hh;
        *(ushort4*)&Hl[tok * LDH + fb] = hl;
      }
    }
    __syncthreads();
    bf16x8 hfr[4][2];
    #pragma unroll
    for (int m = 0; m < 4; ++m) {
      hfr[m][0] = *(bf16x8*)&Hh[(wm * 64 + m * 16 + l15) * LDH + kq * 8];
      hfr[m][1] = *(bf16x8*)&Hl[(wm * 64 + m * 16 + l15) * LDH + kq * 8];
    }
    // phase 2 (swapped): ffacc col = token, rows = d
    #pragma unroll
    for (int n = 0; n < 2; ++n) {
      bf16x8 w2h = *(bf16x8*)&W2sh[buf][(wd * 32 + n * 16 + l15) * LDH + kq * 8];
      bf16x8 w2l = *(bf16x8*)&W2sl[buf][(wd * 32 + n * 16 + l15) * LDH + kq * 8];
      #pragma unroll
      for (int m = 0; m < 4; ++m) {
        ffacc[m][n] = __builtin_amdgcn_mfma_f32_16x16x32_bf16(w2h, hfr[m][0], ffacc[m][n], 0, 0, 0);
        ffacc[m][n] = __builtin_amdgcn_mfma_f32_16x16x32_bf16(w2l, hfr[m][0], ffacc[m][n], 0, 0, 0);
        ffacc[m][n] = __builtin_amdgcn_mfma_f32_16x16x32_bf16(w2h, hfr[m][1], ffacc[m][n], 0, 0, 0);
      }
    }
    // write-late: park next W tiles into buf^1 after compute
    if (pf) {
      *(uint4*)&W1sh[buf ^ 1][r1 * LDW + k1] = w1h_r;
      *(uint4*)&W1sl[buf ^ 1][r1 * LDW + k1] = w1l_r;
      *(uint4*)&W2sh[buf ^ 1][r2 * LDH + f2] = w2h_r;
      *(uint4*)&W2sl[buf ^ 1][r2 * LDH + f2] = w2l_r;
    }
    __syncthreads();
  }
  // epilogue: vectorized float4 stores
  #pragma unroll
  for (int n = 0; n < 2; ++n) {
    int db = wd * 32 + n * 16 + kq * 4;
    float4 b2v = *(const float4*)&b2[(size_t)h * HD + db];
    #pragma unroll
    for (int m = 0; m < 4; ++m) {
      int tok = m0 + wm * 64 + m * 16 + l15;
      float4 v = {ffacc[m][n][0] + b2v.x, ffacc[m][n][1] + b2v.y,
                  ffacc[m][n][2] + b2v.z, ffacc[m][n][3] + b2v.w};
      *(float4*)&out[(size_t)tok * D_M + h * HD + db] = v;
    }
  }
}

// ---------------- out = LayerNorm(a + r) * g + be (optionally + split bf16 out) ----------------
template<int SPLIT>
__global__ __launch_bounds__(256)
void add_ln_kernel(const float* __restrict__ a, const float* __restrict__ r,
                   const float* __restrict__ g, const float* __restrict__ be,
                   float* __restrict__ out,
                   unsigned short* __restrict__ oh, unsigned short* __restrict__ ol) {
  const size_t row = blockIdx.x;
  const int tid = threadIdx.x;
  __shared__ float red1[4];
  __shared__ float red2[4];
  float4 va = ((const float4*)(a + row * D_M))[tid];
  float4 vr = ((const float4*)(r + row * D_M))[tid];
  float v0 = va.x + vr.x, v1 = va.y + vr.y, v2 = va.z + vr.z, v3 = va.w + vr.w;
  float s = v0 + v1 + v2 + v3;
  float sq = v0 * v0 + v1 * v1 + v2 * v2 + v3 * v3;
  s = wave_sum(s);
  sq = wave_sum(sq);
  if ((tid & 63) == 0) { red1[tid >> 6] = s; red2[tid >> 6] = sq; }
  __syncthreads();
  s = red1[0] + red1[1] + red1[2] + red1[3];
  sq = red2[0] + red2[1] + red2[2] + red2[3];
  const float mu = s * (1.0f / D_M);
  const float var = sq * (1.0f / D_M) - mu * mu;
  float x = var + EPS;
  float rs = rsqrtf(x);
  rs = rs * (1.5f - 0.5f * x * rs * rs);
  float4 gg = ((const float4*)g)[tid];
  float4 bb = ((const float4*)be)[tid];
  float4 o = {(v0 - mu) * rs * gg.x + bb.x, (v1 - mu) * rs * gg.y + bb.y,
              (v2 - mu) * rs * gg.z + bb.z, (v3 - mu) * rs * gg.w + bb.w};
  ((float4*)(out + row * D_M))[tid] = o;
  if (SPLIT) {
    ushort4 h, l;
    split_f4(o, h, l);
    ((ushort4*)(oh + row * D_M))[tid] = h;
    ((ushort4*)(ol + row * D_M))[tid] = l;
  }
}

extern "C" void kernel_launch(void* const* d_in, const int* in_sizes, int n_in,
                              void* d_out, int out_size, void* d_ws, size_t ws_size,
                              hipStream_t stream) {
  const float* x   = (const float*)d_in[0];
  const float* Wq  = (const float*)d_in[1];
  const float* bq  = (const float*)d_in[2];
  const float* Wk  = (const float*)d_in[3];
  const float* bk  = (const float*)d_in[4];
  const float* Wv  = (const float*)d_in[5];
  const float* bv  = (const float*)d_in[6];
  const float* Wo  = (const float*)d_in[7];
  const float* bo  = (const float*)d_in[8];
  const float* W1  = (const float*)d_in[9];
  const float* b1  = (const float*)d_in[10];
  const float* W2  = (const float*)d_in[11];
  const float* b2  = (const float*)d_in[12];
  const float* g1  = (const float*)d_in[13];
  const float* be1 = (const float*)d_in[14];
  const float* g2  = (const float*)d_in[15];
  const float* be2 = (const float*)d_in[16];

  float* y_out = (float*)d_out;
  float* attn  = (float*)d_out + (size_t)TOK * D_M;

  // ---- workspace: 80 MB ----
  char* p = (char*)d_ws;
  const size_t MB = 1024 * 1024;
  unsigned short* WqT_h = (unsigned short*)(p + 0 * MB);
  unsigned short* WqT_l = (unsigned short*)(p + 2 * MB);
  unsigned short* WkT_h = (unsigned short*)(p + 4 * MB);
  unsigned short* WkT_l = (unsigned short*)(p + 6 * MB);
  unsigned short* WvT_h = (unsigned short*)(p + 8 * MB);
  unsigned short* WvT_l = (unsigned short*)(p + 10 * MB);
  unsigned short* WoT_h = (unsigned short*)(p + 12 * MB);
  unsigned short* WoT_l = (unsigned short*)(p + 14 * MB);
  unsigned short* xh  = (unsigned short*)(p + 16 * MB);
  unsigned short* xl  = (unsigned short*)(p + 24 * MB);
  unsigned short* qh  = (unsigned short*)(p + 32 * MB);
  unsigned short* ql  = (unsigned short*)(p + 40 * MB);
  unsigned short* kh  = (unsigned short*)(p + 48 * MB);
  unsigned short* kl  = (unsigned short*)(p + 56 * MB);
  unsigned short* vth = (unsigned short*)(p + 64 * MB);
  // phase aliases:
  unsigned short* ctxh = (unsigned short*)(p + 16 * MB);  // xh dead after QKV
  unsigned short* ctxl = (unsigned short*)(p + 24 * MB);  // xl dead after QKV
  float* resid = (float*)(p + 32 * MB);                   // qh+ql dead after attn (16 MB)
  float* x1b   = (float*)(p + 48 * MB);                   // kh+kl dead after attn (16 MB)
  unsigned short* x1c_h = (unsigned short*)(p + 64 * MB); // vth dead after attn
  unsigned short* x1c_l = (unsigned short*)(p + 72 * MB); // spare
  unsigned short* W1c_h = (unsigned short*)(p + 0 * MB);  // WT dead after Wo gemm
  unsigned short* W1c_l = (unsigned short*)(p + 8 * MB);
  unsigned short* W2c_h = (unsigned short*)(p + 16 * MB); // ctx dead after Wo gemm
  unsigned short* W2c_l = (unsigned short*)(p + 24 * MB);
  float* ffb = (float*)(p + 32 * MB);                     // resid dead after LN1

  const dim3 blk(256);
  const int n4_act = TOK * D_M / 4;   // 1,048,576

  // ---- prep: 4 weight transposes in one launch + x split ----
  transp4_k<<<dim3(16, 16, 4), blk, 0, stream>>>(Wq, Wk, Wv, Wo,
      WqT_h, WqT_l, WkT_h, WkT_l, WvT_h, WvT_l, WoT_h, WoT_l);
  convert_split_k<<<dim3(n4_act / 256), blk, 0, stream>>>(x, xh, xl, n4_act);

  // ---- merged QKV projection ----
  qkv_gemm_k<<<dim3(TOK / 64, D_M / 128), blk, 0, stream>>>(
      xh, xl, WqT_h, WqT_l, WkT_h, WkT_l, WvT_h, WvT_l,
      bq, bk, bv, qh, ql, kh, kl, vth);

  // ---- fused attention (q-tile 128, double-buffered staging) ----
  fused_attn_k<<<dim3(SQ / 128, BB * NH), blk, 0, stream>>>(qh, ql, kh, kl, vth, attn, ctxh, ctxl);

  // ---- Wo projection + LN1 (LN1 emits split x1) ----
  proj_gemm_k<<<dim3(TOK / 64, D_M / 128), blk, 0, stream>>>(
      ctxh, ctxl, WoT_h, WoT_l, bo, resid, TOK, D_M, D_M);
  add_ln_kernel<1><<<dim3(TOK), blk, 0, stream>>>(x, resid, g1, be1, x1b, x1c_h, x1c_l);

  // ---- per-head FF + LN2 ----
  convert_split_k<<<dim3(n4_act / 256), blk, 0, stream>>>(W1, W1c_h, W1c_l, n4_act);
  convert_split_k<<<dim3(n4_act / 256), blk, 0, stream>>>(W2, W2c_h, W2c_l, n4_act);
  ff_split_k<<<dim3(TOK / 128, NH), blk, 0, stream>>>(x1c_h, x1c_l, W1c_h, W1c_l, b1,
                                                      W2c_h, W2c_l, b2, ffb);
  add_ln_kernel<0><<<dim3(TOK), blk, 0, stream>>>(x1b, ffb, g2, be2, y_out, nullptr, nullptr);
}

// Round 10
// 660.149 us; speedup vs baseline: 4.1318x; 1.0227x over previous
//
#include <hip/hip_runtime.h>
#include <cstddef>

#define D_M 1024
#define NH 16
#define HD 64
#define FFD 4096
#define SQ 2048
#define BB 2
#define TOK (BB*SQ)   // 4096
#define EPS 1e-5f

typedef __attribute__((ext_vector_type(8))) short bf16x8;
typedef __attribute__((ext_vector_type(4))) float f32x4;

__device__ inline unsigned short f32_bf16_rne(float f) {
  unsigned int u = __float_as_uint(f);
  unsigned int r = (u + 0x7fffu + ((u >> 16) & 1u)) >> 16;
  return (unsigned short)r;
}
__device__ inline float bf16_f32(unsigned short h) {
  return __uint_as_float(((unsigned int)h) << 16);
}
__device__ inline void split_f4(float4 v, ushort4& h, ushort4& l) {
  h.x = f32_bf16_rne(v.x); l.x = f32_bf16_rne(v.x - bf16_f32(h.x));
  h.y = f32_bf16_rne(v.y); l.y = f32_bf16_rne(v.y - bf16_f32(h.y));
  h.z = f32_bf16_rne(v.z); l.z = f32_bf16_rne(v.z - bf16_f32(h.z));
  h.w = f32_bf16_rne(v.w); l.w = f32_bf16_rne(v.w - bf16_f32(h.w));
}

__device__ inline float wave_sum(float v) {
  #pragma unroll
  for (int m = 32; m >= 1; m >>= 1) v += __shfl_xor(v, m);
  return v;
}

// ---------------- fp32 -> (hi,lo) bf16 split, layout-preserving ----------------
__global__ __launch_bounds__(256)
void convert_split_k(const float* __restrict__ src, unsigned short* __restrict__ hi,
                     unsigned short* __restrict__ lo, int n4) {
  int i = blockIdx.x * 256 + threadIdx.x;
  if (i >= n4) return;
  float4 v = ((const float4*)src)[i];
  ushort4 h, l;
  split_f4(v, h, l);
  ((ushort4*)hi)[i] = h;
  ((ushort4*)lo)[i] = l;
}

// ---------------- 4x W[1024][1024] fp32 -> WT hi/lo bf16 [N][K], one launch ----------------
__global__ __launch_bounds__(256)
void transp4_k(const float* __restrict__ W0, const float* __restrict__ W1_,
               const float* __restrict__ W2_, const float* __restrict__ W3,
               unsigned short* __restrict__ h0, unsigned short* __restrict__ l0,
               unsigned short* __restrict__ h1, unsigned short* __restrict__ l1,
               unsigned short* __restrict__ h2, unsigned short* __restrict__ l2,
               unsigned short* __restrict__ h3, unsigned short* __restrict__ l3) {
  const float* W; unsigned short* hT; unsigned short* lT;
  switch (blockIdx.z) {
    case 0: W = W0; hT = h0; lT = l0; break;
    case 1: W = W1_; hT = h1; lT = l1; break;
    case 2: W = W2_; hT = h2; lT = l2; break;
    default: W = W3; hT = h3; lT = l3; break;
  }
  __shared__ float tile[64][65];
  const int bn = blockIdx.x * 64;
  const int bk = blockIdx.y * 64;
  const int t = threadIdx.x;
  #pragma unroll
  for (int i = 0; i < 4; ++i) {
    int r = (t >> 4) + i * 16, c = (t & 15) * 4;
    float4 v = *(const float4*)&W[(size_t)(bk + r) * D_M + bn + c];
    tile[r][c] = v.x; tile[r][c + 1] = v.y; tile[r][c + 2] = v.z; tile[r][c + 3] = v.w;
  }
  __syncthreads();
  #pragma unroll
  for (int i = 0; i < 4; ++i) {
    int n = (t >> 4) + i * 16, k = (t & 15) * 4;
    float4 v = {tile[k][n], tile[k + 1][n], tile[k + 2][n], tile[k + 3][n]};
    ushort4 h, l;
    split_f4(v, h, l);
    *(ushort4*)&hT[(size_t)(bn + n) * D_M + bk + k] = h;
    *(ushort4*)&lT[(size_t)(bn + n) * D_M + bk + k] = l;
  }
}

// ---------------- merged QKV GEMM: one A-tile staging serves 3 weight sets ----------------
// x pre-split [TOK][1024]; weights pre-split [N][K]. Q,K -> hi-only bf16 [M][N]; V -> transposed bf16.
__global__ __launch_bounds__(256)
void qkv_gemm_k(const unsigned short* __restrict__ xh_g, const unsigned short* __restrict__ xl_g,
                const unsigned short* __restrict__ Bqh, const unsigned short* __restrict__ Bql,
                const unsigned short* __restrict__ Bkh, const unsigned short* __restrict__ Bkl,
                const unsigned short* __restrict__ Bvh, const unsigned short* __restrict__ Bvl,
                const float* __restrict__ bq, const float* __restrict__ bk, const float* __restrict__ bv,
                unsigned short* __restrict__ qh, unsigned short* __restrict__ kh,
                unsigned short* __restrict__ vth) {
  constexpr int LDK = 40;
  __shared__ unsigned short Ah[64 * LDK], Al[64 * LDK];
  __shared__ unsigned short Bh[3][128 * LDK], Bl[3][128 * LDK];
  const int tid = threadIdx.x;
  const int wave = tid >> 6, lane = tid & 63;
  const int wm = (wave >> 1) * 32, wn = (wave & 1) * 64;
  const int bm = blockIdx.x * 64, bn = blockIdx.y * 128;
  const int K = D_M;

  f32x4 acc[3][2][4] = {};
  const int sr = tid >> 2, sk = (tid & 3) * 8;
  const int l15 = lane & 15, k8 = (lane >> 4) * 8;

  const unsigned short* Bhp[3] = {Bqh, Bkh, Bvh};
  const unsigned short* Blp[3] = {Bql, Bkl, Bvl};

  for (int k0 = 0; k0 < K; k0 += 32) {
    *(uint4*)&Ah[sr * LDK + sk] = *(const uint4*)&xh_g[(size_t)(bm + sr) * K + k0 + sk];
    *(uint4*)&Al[sr * LDK + sk] = *(const uint4*)&xl_g[(size_t)(bm + sr) * K + k0 + sk];
    #pragma unroll
    for (int s = 0; s < 3; ++s) {
      #pragma unroll
      for (int c = 0; c < 2; ++c) {
        int r = sr + c * 64;
        *(uint4*)&Bh[s][r * LDK + sk] = *(const uint4*)&Bhp[s][(size_t)(bn + r) * K + k0 + sk];
        *(uint4*)&Bl[s][r * LDK + sk] = *(const uint4*)&Blp[s][(size_t)(bn + r) * K + k0 + sk];
      }
    }
    __syncthreads();
    bf16x8 af[2][2];
    #pragma unroll
    for (int m = 0; m < 2; ++m) {
      af[m][0] = *(bf16x8*)&Ah[(wm + m * 16 + l15) * LDK + k8];
      af[m][1] = *(bf16x8*)&Al[(wm + m * 16 + l15) * LDK + k8];
    }
    #pragma unroll
    for (int s = 0; s < 3; ++s) {
      #pragma unroll
      for (int n = 0; n < 4; ++n) {
        bf16x8 b0 = *(bf16x8*)&Bh[s][(wn + n * 16 + l15) * LDK + k8];
        bf16x8 b1 = *(bf16x8*)&Bl[s][(wn + n * 16 + l15) * LDK + k8];
        #pragma unroll
        for (int m = 0; m < 2; ++m) {
          if (s == 2) {  // V: unswapped (D col = weight col, rows = token)
            acc[s][m][n] = __builtin_amdgcn_mfma_f32_16x16x32_bf16(af[m][0], b0, acc[s][m][n], 0, 0, 0);
            acc[s][m][n] = __builtin_amdgcn_mfma_f32_16x16x32_bf16(af[m][0], b1, acc[s][m][n], 0, 0, 0);
            acc[s][m][n] = __builtin_amdgcn_mfma_f32_16x16x32_bf16(af[m][1], b0, acc[s][m][n], 0, 0, 0);
          } else {       // Q,K: swapped (D col = token, rows = weight col)
            acc[s][m][n] = __builtin_amdgcn_mfma_f32_16x16x32_bf16(b0, af[m][0], acc[s][m][n], 0, 0, 0);
            acc[s][m][n] = __builtin_amdgcn_mfma_f32_16x16x32_bf16(b1, af[m][0], acc[s][m][n], 0, 0, 0);
            acc[s][m][n] = __builtin_amdgcn_mfma_f32_16x16x32_bf16(b0, af[m][1], acc[s][m][n], 0, 0, 0);
          }
        }
      }
    }
    __syncthreads();
  }
  const int kq4 = (lane >> 4) * 4;
  // Q, K epilogues (swapped layout, hi-only vectorized stores)
  #pragma unroll
  for (int s = 0; s < 2; ++s) {
    const float* bias = (s == 0) ? bq : bk;
    unsigned short* oh = (s == 0) ? qh : kh;
    #pragma unroll
    for (int n = 0; n < 4; ++n) {
      int colb = bn + wn + n * 16 + kq4;
      float4 bv4 = *(const float4*)&bias[colb];
      #pragma unroll
      for (int m = 0; m < 2; ++m) {
        int tok = bm + wm + m * 16 + l15;
        ushort4 h;
        h.x = f32_bf16_rne(acc[s][m][n][0] + bv4.x);
        h.y = f32_bf16_rne(acc[s][m][n][1] + bv4.y);
        h.z = f32_bf16_rne(acc[s][m][n][2] + bv4.z);
        h.w = f32_bf16_rne(acc[s][m][n][3] + bv4.w);
        *(ushort4*)&oh[(size_t)tok * D_M + colb] = h;
      }
    }
  }
  // V epilogue (unswapped, transposed store [b][h][d][s])
  #pragma unroll
  for (int n = 0; n < 4; ++n) {
    int col = bn + wn + n * 16 + l15;
    float bvv = bv[col];
    #pragma unroll
    for (int m = 0; m < 2; ++m) {
      int row0 = bm + wm + m * 16 + kq4;
      ushort4 hv;
      hv.x = f32_bf16_rne(acc[2][m][n][0] + bvv); hv.y = f32_bf16_rne(acc[2][m][n][1] + bvv);
      hv.z = f32_bf16_rne(acc[2][m][n][2] + bvv); hv.w = f32_bf16_rne(acc[2][m][n][3] + bvv);
      size_t idx = (((size_t)(row0 >> 11) * NH + (col >> 6)) * HD + (col & 63)) * SQ + (row0 & 2047);
      *(ushort4*)&vth[idx] = hv;
    }
  }
}

// ------- projection GEMM (Wo), 64x128 tile, all operands pre-split, swapped MFMA -------
__global__ __launch_bounds__(256)
void proj_gemm_k(const unsigned short* __restrict__ Ahi_g, const unsigned short* __restrict__ Alo_g,
                 const unsigned short* __restrict__ Bhi, const unsigned short* __restrict__ Blo,
                 const float* __restrict__ bias, float* __restrict__ C,
                 int M, int N, int K) {
  constexpr int LDK = 40;
  __shared__ unsigned short Ah[64 * LDK], Al[64 * LDK];
  __shared__ unsigned short Bh[128 * LDK], Bl[128 * LDK];
  const int tid = threadIdx.x;
  const int wave = tid >> 6, lane = tid & 63;
  const int wm = (wave >> 1) * 32, wn = (wave & 1) * 64;
  const int bm = blockIdx.x * 64, bn = blockIdx.y * 128;

  f32x4 acc[2][4] = {};
  const int sr = tid >> 2, sk = (tid & 3) * 8;
  const int l15 = lane & 15, k8 = (lane >> 4) * 8;

  for (int k0 = 0; k0 < K; k0 += 32) {
    *(uint4*)&Ah[sr * LDK + sk] = *(const uint4*)&Ahi_g[(size_t)(bm + sr) * K + k0 + sk];
    *(uint4*)&Al[sr * LDK + sk] = *(const uint4*)&Alo_g[(size_t)(bm + sr) * K + k0 + sk];
    #pragma unroll
    for (int c = 0; c < 2; ++c) {
      int r = sr + c * 64;
      *(uint4*)&Bh[r * LDK + sk] = *(const uint4*)&Bhi[(size_t)(bn + r) * K + k0 + sk];
      *(uint4*)&Bl[r * LDK + sk] = *(const uint4*)&Blo[(size_t)(bn + r) * K + k0 + sk];
    }
    __syncthreads();
    bf16x8 af[2][2], bfr[4][2];
    #pragma unroll
    for (int m = 0; m < 2; ++m) {
      af[m][0] = *(bf16x8*)&Ah[(wm + m * 16 + l15) * LDK + k8];
      af[m][1] = *(bf16x8*)&Al[(wm + m * 16 + l15) * LDK + k8];
    }
    #pragma unroll
    for (int n = 0; n < 4; ++n) {
      bfr[n][0] = *(bf16x8*)&Bh[(wn + n * 16 + l15) * LDK + k8];
      bfr[n][1] = *(bf16x8*)&Bl[(wn + n * 16 + l15) * LDK + k8];
    }
    #pragma unroll
    for (int m = 0; m < 2; ++m)
      #pragma unroll
      for (int n = 0; n < 4; ++n) {
        acc[m][n] = __builtin_amdgcn_mfma_f32_16x16x32_bf16(bfr[n][0], af[m][0], acc[m][n], 0, 0, 0);
        acc[m][n] = __builtin_amdgcn_mfma_f32_16x16x32_bf16(bfr[n][1], af[m][0], acc[m][n], 0, 0, 0);
        acc[m][n] = __builtin_amdgcn_mfma_f32_16x16x32_bf16(bfr[n][0], af[m][1], acc[m][n], 0, 0, 0);
      }
    __syncthreads();
  }
  const int kq4 = (lane >> 4) * 4;
  #pragma unroll
  for (int n = 0; n < 4; ++n) {
    int colb = bn + wn + n * 16 + kq4;
    float4 bv4 = *(const float4*)&bias[colb];
    #pragma unroll
    for (int m = 0; m < 2; ++m) {
      int tok = bm + wm + m * 16 + l15;
      float4 v = {acc[m][n][0] + bv4.x, acc[m][n][1] + bv4.y,
                  acc[m][n][2] + bv4.z, acc[m][n][3] + bv4.w};
      *(float4*)&C[(size_t)tok * N + colb] = v;
    }
  }
}

// ---------------- fused attention, hi-only scores, q-tile 128, double-buffered K/V ----------------
__global__ __launch_bounds__(256)
void fused_attn_k(const unsigned short* __restrict__ qh,
                  const unsigned short* __restrict__ kh,
                  const unsigned short* __restrict__ vth,
                  float* __restrict__ attn,
                  unsigned short* __restrict__ ctxh, unsigned short* __restrict__ ctxl) {
  constexpr int LDK = 72;
  constexpr int NT = SQ / 64;
  __shared__ unsigned short Kth[2][64 * LDK], Vts[2][64 * LDK];
  __shared__ unsigned short Ph[128 * LDK];
  const int tid = threadIdx.x, wave = tid >> 6, lane = tid & 63;
  const int l15 = lane & 15, kq = lane >> 4;
  const int bh = blockIdx.y, b = bh >> 4;
  const int h = bh & 15;
  const int q0 = blockIdx.x * 128;

  // Q fragments for 2 q-subtiles of 16 (wave owns 32 q)
  bf16x8 qfh[2][2];
  #pragma unroll
  for (int qi = 0; qi < 2; ++qi) {
    const size_t qoff = (size_t)(b * SQ + q0 + wave * 32 + qi * 16 + l15) * D_M + h * HD + kq * 8;
    qfh[qi][0] = *(const bf16x8*)&qh[qoff];  qfh[qi][1] = *(const bf16x8*)&qh[qoff + 32];
  }

  const size_t kbase = (size_t)(b * SQ) * D_M + h * HD;
  const size_t vbase = (size_t)bh * HD * SQ;
  const int srow = tid >> 2, sc = (tid & 3) * 16;

  // ---------- pass A: per-q row sums (max term cancels with m == 0) ----------
  float lsum[2] = {0.f, 0.f};
  {
    const unsigned short* src = &kh[kbase + (size_t)srow * D_M + sc];
    *(uint4*)&Kth[0][srow * LDK + sc] = *(const uint4*)src;
    *(uint4*)&Kth[0][srow * LDK + sc + 8] = *(const uint4*)(src + 8);
  }
  __syncthreads();
  for (int t = 0; t < NT; ++t) {
    const int cur = t & 1;
    const bool pf = (t + 1 < NT);
    uint4 r0, r1;
    if (pf) {
      const unsigned short* src = &kh[kbase + (size_t)((t + 1) * 64 + srow) * D_M + sc];
      r0 = *(const uint4*)src;
      r1 = *(const uint4*)(src + 8);
    }
    #pragma unroll
    for (int n = 0; n < 4; ++n) {
      bf16x8 kb0 = *(bf16x8*)&Kth[cur][(n * 16 + l15) * LDK + kq * 8];
      bf16x8 kb1 = *(bf16x8*)&Kth[cur][(n * 16 + l15) * LDK + 32 + kq * 8];
      #pragma unroll
      for (int qi = 0; qi < 2; ++qi) {
        f32x4 s = {};
        s = __builtin_amdgcn_mfma_f32_16x16x32_bf16(kb0, qfh[qi][0], s, 0, 0, 0);
        s = __builtin_amdgcn_mfma_f32_16x16x32_bf16(kb1, qfh[qi][1], s, 0, 0, 0);
        #pragma unroll
        for (int r = 0; r < 4; ++r) lsum[qi] += __expf(s[r] * 0.125f);
      }
    }
    if (pf) {
      *(uint4*)&Kth[cur ^ 1][srow * LDK + sc] = r0;
      *(uint4*)&Kth[cur ^ 1][srow * LDK + sc + 8] = r1;
    }
    __syncthreads();
  }
  float invl[2];
  #pragma unroll
  for (int qi = 0; qi < 2; ++qi) {
    float l = lsum[qi];
    l += __shfl_xor(l, 16);
    l += __shfl_xor(l, 32);
    invl[qi] = 1.0f / l;
  }

  // ---------- pass B: hi-only scores, attn write, PV ----------
  f32x4 cacc[2][4] = {};
  {
    const unsigned short* srch = &kh[kbase + (size_t)srow * D_M + sc];
    const unsigned short* srcv = &vth[vbase + (size_t)srow * SQ + sc];
    *(uint4*)&Kth[0][srow * LDK + sc] = *(const uint4*)srch;
    *(uint4*)&Kth[0][srow * LDK + sc + 8] = *(const uint4*)(srch + 8);
    *(uint4*)&Vts[0][srow * LDK + sc] = *(const uint4*)srcv;
    *(uint4*)&Vts[0][srow * LDK + sc + 8] = *(const uint4*)(srcv + 8);
  }
  __syncthreads();
  for (int t = 0; t < NT; ++t) {
    const int cur = t & 1;
    const int k0 = t * 64;
    const bool pf = (t + 1 < NT);
    uint4 rk0, rk1, rv0, rv1;
    if (pf) {
      const unsigned short* srch = &kh[kbase + (size_t)(k0 + 64 + srow) * D_M + sc];
      const unsigned short* srcv = &vth[vbase + (size_t)srow * SQ + k0 + 64 + sc];
      rk0 = *(const uint4*)srch; rk1 = *(const uint4*)(srch + 8);
      rv0 = *(const uint4*)srcv; rv1 = *(const uint4*)(srcv + 8);
    }
    #pragma unroll
    for (int n = 0; n < 4; ++n) {
      bf16x8 kb0 = *(bf16x8*)&Kth[cur][(n * 16 + l15) * LDK + kq * 8];
      bf16x8 kb1 = *(bf16x8*)&Kth[cur][(n * 16 + l15) * LDK + 32 + kq * 8];
      #pragma unroll
      for (int qi = 0; qi < 2; ++qi) {
        f32x4 s = {};
        s = __builtin_amdgcn_mfma_f32_16x16x32_bf16(kb0, qfh[qi][0], s, 0, 0, 0);
        s = __builtin_amdgcn_mfma_f32_16x16x32_bf16(kb1, qfh[qi][1], s, 0, 0, 0);
        float4 pv;
        pv.x = __expf(s[0] * 0.125f) * invl[qi];
        pv.y = __expf(s[1] * 0.125f) * invl[qi];
        pv.z = __expf(s[2] * 0.125f) * invl[qi];
        pv.w = __expf(s[3] * 0.125f) * invl[qi];
        const int qrow = wave * 32 + qi * 16 + l15;
        *(float4*)&attn[((size_t)bh * SQ + q0 + qrow) * SQ + k0 + n * 16 + kq * 4] = pv;
        ushort4 p4;
        p4.x = f32_bf16_rne(pv.x); p4.y = f32_bf16_rne(pv.y);
        p4.z = f32_bf16_rne(pv.z); p4.w = f32_bf16_rne(pv.w);
        *(ushort4*)&Ph[qrow * LDK + n * 16 + kq * 4] = p4;
      }
    }
    __syncthreads();
    #pragma unroll
    for (int qi = 0; qi < 2; ++qi) {
      bf16x8 pa0 = *(bf16x8*)&Ph[(wave * 32 + qi * 16 + l15) * LDK + kq * 8];
      bf16x8 pa1 = *(bf16x8*)&Ph[(wave * 32 + qi * 16 + l15) * LDK + 32 + kq * 8];
      #pragma unroll
      for (int n = 0; n < 4; ++n) {
        bf16x8 vb0 = *(bf16x8*)&Vts[cur][(n * 16 + l15) * LDK + kq * 8];
        bf16x8 vb1 = *(bf16x8*)&Vts[cur][(n * 16 + l15) * LDK + 32 + kq * 8];
        cacc[qi][n] = __builtin_amdgcn_mfma_f32_16x16x32_bf16(vb0, pa0, cacc[qi][n], 0, 0, 0);
        cacc[qi][n] = __builtin_amdgcn_mfma_f32_16x16x32_bf16(vb1, pa1, cacc[qi][n], 0, 0, 0);
      }
    }
    if (pf) {
      *(uint4*)&Kth[cur ^ 1][srow * LDK + sc] = rk0;
      *(uint4*)&Kth[cur ^ 1][srow * LDK + sc + 8] = rk1;
      *(uint4*)&Vts[cur ^ 1][srow * LDK + sc] = rv0;
      *(uint4*)&Vts[cur ^ 1][srow * LDK + sc + 8] = rv1;
    }
    __syncthreads();
  }
  // ctx epilogue: q = q0 + wave*32 + qi*16 + l15, d = n*16 + kq*4 + r
  #pragma unroll
  for (int qi = 0; qi < 2; ++qi)
    #pragma unroll
    for (int n = 0; n < 4; ++n) {
      float4 v = {cacc[qi][n][0], cacc[qi][n][1], cacc[qi][n][2], cacc[qi][n][3]};
      ushort4 hh, ll;
      split_f4(v, hh, ll);
      size_t off = (size_t)(b * SQ + q0 + wave * 32 + qi * 16 + l15) * D_M + h * HD + n * 16 + kq * 4;
      *(ushort4*)&ctxh[off] = hh;
      *(ushort4*)&ctxl[off] = ll;
    }
}

// ---------------- per-head FF, split-bf16 MFMA, reg-staged W (issue-early/write-late) ----------------
__global__ __launch_bounds__(256)
void ff_split_k(const unsigned short* __restrict__ x1h, const unsigned short* __restrict__ x1l,
                const unsigned short* __restrict__ W1h_, const unsigned short* __restrict__ W1l_,
                const float* __restrict__ b1,
                const unsigned short* __restrict__ W2h_, const unsigned short* __restrict__ W2l_,
                const float* __restrict__ b2, float* __restrict__ out) {
  constexpr int LDW = 72;
  constexpr int LDH = 40;
  __shared__ unsigned short W1sh[2][32 * LDW], W1sl[2][32 * LDW];
  __shared__ unsigned short W2sh[2][64 * LDH], W2sl[2][64 * LDH];
  __shared__ unsigned short Hh[128 * LDH], Hl[128 * LDH];

  const int tid = threadIdx.x;
  const int wave = tid >> 6, lane = tid & 63;
  const int wm = wave >> 1, wf = wave & 1, wd = wave & 1;
  const int h = blockIdx.y;
  const int m0 = blockIdx.x * 128;
  const int l15 = lane & 15, kq = lane >> 4;

  const size_t w1base = (size_t)h * FFD * HD;
  const size_t w2base = (size_t)h * HD * FFD;
  const int r1 = tid >> 3, k1 = (tid & 7) * 8;
  const int r2 = tid >> 2, f2 = (tid & 3) * 8;

  bf16x8 xf[4][2][2];
  #pragma unroll
  for (int m = 0; m < 4; ++m)
    #pragma unroll
    for (int ks = 0; ks < 2; ++ks) {
      size_t gof = (size_t)(m0 + wm * 64 + m * 16 + l15) * D_M + h * HD + ks * 32 + kq * 8;
      xf[m][ks][0] = *(const bf16x8*)&x1h[gof];
      xf[m][ks][1] = *(const bf16x8*)&x1l[gof];
    }

  {
    *(uint4*)&W1sh[0][r1 * LDW + k1] = *(const uint4*)&W1h_[w1base + (size_t)r1 * HD + k1];
    *(uint4*)&W1sl[0][r1 * LDW + k1] = *(const uint4*)&W1l_[w1base + (size_t)r1 * HD + k1];
    *(uint4*)&W2sh[0][r2 * LDH + f2] = *(const uint4*)&W2h_[w2base + (size_t)r2 * FFD + f2];
    *(uint4*)&W2sl[0][r2 * LDH + f2] = *(const uint4*)&W2l_[w2base + (size_t)r2 * FFD + f2];
  }
  __syncthreads();

  f32x4 ffacc[4][2] = {};

  for (int ch = 0; ch < FFD / 32; ++ch) {
    const int buf = ch & 1;
    const bool pf = (ch + 1 < FFD / 32);
    uint4 w1h_r, w1l_r, w2h_r, w2l_r;
    if (pf) {
      const int f0n = (ch + 1) * 32;
      w1h_r = *(const uint4*)&W1h_[w1base + (size_t)(f0n + r1) * HD + k1];
      w1l_r = *(const uint4*)&W1l_[w1base + (size_t)(f0n + r1) * HD + k1];
      w2h_r = *(const uint4*)&W2h_[w2base + (size_t)r2 * FFD + f0n + f2];
      w2l_r = *(const uint4*)&W2l_[w2base + (size_t)r2 * FFD + f0n + f2];
    }
    // phase 1 (swapped): hacc[m] col = token (l15), rows = f (kq*4+r)
    f32x4 hacc[4] = {};
    #pragma unroll
    for (int ks = 0; ks < 2; ++ks) {
      bf16x8 w1h = *(bf16x8*)&W1sh[buf][(wf * 16 + l15) * LDW + ks * 32 + kq * 8];
      bf16x8 w1l = *(bf16x8*)&W1sl[buf][(wf * 16 + l15) * LDW + ks * 32 + kq * 8];
      #pragma unroll
      for (int m = 0; m < 4; ++m) {
        hacc[m] = __builtin_amdgcn_mfma_f32_16x16x32_bf16(w1h, xf[m][ks][0], hacc[m], 0, 0, 0);
        hacc[m] = __builtin_amdgcn_mfma_f32_16x16x32_bf16(w1l, xf[m][ks][0], hacc[m], 0, 0, 0);
        hacc[m] = __builtin_amdgcn_mfma_f32_16x16x32_bf16(w1h, xf[m][ks][1], hacc[m], 0, 0, 0);
      }
    }
    // bias + relu + split -> H (vectorized)
    {
      const int fb = wf * 16 + kq * 4;
      float4 b1v = *(const float4*)&b1[(size_t)h * FFD + ch * 32 + fb];
      const float bb[4] = {b1v.x, b1v.y, b1v.z, b1v.w};
      #pragma unroll
      for (int m = 0; m < 4; ++m) {
        int tok = wm * 64 + m * 16 + l15;
        float4 hv = {fmaxf(hacc[m][0] + bb[0], 0.0f), fmaxf(hacc[m][1] + bb[1], 0.0f),
                     fmaxf(hacc[m][2] + bb[2], 0.0f), fmaxf(hacc[m][3] + bb[3], 0.0f)};
        ushort4 hh, hl;
        split_f4(hv, hh, hl);
        *(ushort4*)&Hh[tok * LDH + fb] = hh;
        *(ushort4*)&Hl[tok * LDH + fb] = hl;
      }
    }
    __syncthreads();
    bf16x8 hfr[4][2];
    #pragma unroll
    for (int m = 0; m < 4; ++m) {
      hfr[m][0] = *(bf16x8*)&Hh[(wm * 64 + m * 16 + l15) * LDH + kq * 8];
      hfr[m][1] = *(bf16x8*)&Hl[(wm * 64 + m * 16 + l15) * LDH + kq * 8];
    }
    // phase 2 (swapped): ffacc col = token, rows = d
    #pragma unroll
    for (int n = 0; n < 2; ++n) {
      bf16x8 w2h = *(bf16x8*)&W2sh[buf][(wd * 32 + n * 16 + l15) * LDH + kq * 8];
      bf16x8 w2l = *(bf16x8*)&W2sl[buf][(wd * 32 + n * 16 + l15) * LDH + kq * 8];
      #pragma unroll
      for (int m = 0; m < 4; ++m) {
        ffacc[m][n] = __builtin_amdgcn_mfma_f32_16x16x32_bf16(w2h, hfr[m][0], ffacc[m][n], 0, 0, 0);
        ffacc[m][n] = __builtin_amdgcn_mfma_f32_16x16x32_bf16(w2l, hfr[m][0], ffacc[m][n], 0, 0, 0);
        ffacc[m][n] = __builtin_amdgcn_mfma_f32_16x16x32_bf16(w2h, hfr[m][1], ffacc[m][n], 0, 0, 0);
      }
    }
    // write-late: park next W tiles into buf^1 after compute
    if (pf) {
      *(uint4*)&W1sh[buf ^ 1][r1 * LDW + k1] = w1h_r;
      *(uint4*)&W1sl[buf ^ 1][r1 * LDW + k1] = w1l_r;
      *(uint4*)&W2sh[buf ^ 1][r2 * LDH + f2] = w2h_r;
      *(uint4*)&W2sl[buf ^ 1][r2 * LDH + f2] = w2l_r;
    }
    __syncthreads();
  }
  // epilogue: vectorized float4 stores
  #pragma unroll
  for (int n = 0; n < 2; ++n) {
    int db = wd * 32 + n * 16 + kq * 4;
    float4 b2v = *(const float4*)&b2[(size_t)h * HD + db];
    #pragma unroll
    for (int m = 0; m < 4; ++m) {
      int tok = m0 + wm * 64 + m * 16 + l15;
      float4 v = {ffacc[m][n][0] + b2v.x, ffacc[m][n][1] + b2v.y,
                  ffacc[m][n][2] + b2v.z, ffacc[m][n][3] + b2v.w};
      *(float4*)&out[(size_t)tok * D_M + h * HD + db] = v;
    }
  }
}

// ---------------- out = LayerNorm(a + r) * g + be (optionally + split bf16 out) ----------------
template<int SPLIT>
__global__ __launch_bounds__(256)
void add_ln_kernel(const float* __restrict__ a, const float* __restrict__ r,
                   const float* __restrict__ g, const float* __restrict__ be,
                   float* __restrict__ out,
                   unsigned short* __restrict__ oh, unsigned short* __restrict__ ol) {
  const size_t row = blockIdx.x;
  const int tid = threadIdx.x;
  __shared__ float red1[4];
  __shared__ float red2[4];
  float4 va = ((const float4*)(a + row * D_M))[tid];
  float4 vr = ((const float4*)(r + row * D_M))[tid];
  float v0 = va.x + vr.x, v1 = va.y + vr.y, v2 = va.z + vr.z, v3 = va.w + vr.w;
  float s = v0 + v1 + v2 + v3;
  float sq = v0 * v0 + v1 * v1 + v2 * v2 + v3 * v3;
  s = wave_sum(s);
  sq = wave_sum(sq);
  if ((tid & 63) == 0) { red1[tid >> 6] = s; red2[tid >> 6] = sq; }
  __syncthreads();
  s = red1[0] + red1[1] + red1[2] + red1[3];
  sq = red2[0] + red2[1] + red2[2] + red2[3];
  const float mu = s * (1.0f / D_M);
  const float var = sq * (1.0f / D_M) - mu * mu;
  float x = var + EPS;
  float rs = rsqrtf(x);
  rs = rs * (1.5f - 0.5f * x * rs * rs);
  float4 gg = ((const float4*)g)[tid];
  float4 bb = ((const float4*)be)[tid];
  float4 o = {(v0 - mu) * rs * gg.x + bb.x, (v1 - mu) * rs * gg.y + bb.y,
              (v2 - mu) * rs * gg.z + bb.z, (v3 - mu) * rs * gg.w + bb.w};
  ((float4*)(out + row * D_M))[tid] = o;
  if (SPLIT) {
    ushort4 h, l;
    split_f4(o, h, l);
    ((ushort4*)(oh + row * D_M))[tid] = h;
    ((ushort4*)(ol + row * D_M))[tid] = l;
  }
}

extern "C" void kernel_launch(void* const* d_in, const int* in_sizes, int n_in,
                              void* d_out, int out_size, void* d_ws, size_t ws_size,
                              hipStream_t stream) {
  const float* x   = (const float*)d_in[0];
  const float* Wq  = (const float*)d_in[1];
  const float* bq  = (const float*)d_in[2];
  const float* Wk  = (const float*)d_in[3];
  const float* bk  = (const float*)d_in[4];
  const float* Wv  = (const float*)d_in[5];
  const float* bv  = (const float*)d_in[6];
  const float* Wo  = (const float*)d_in[7];
  const float* bo  = (const float*)d_in[8];
  const float* W1  = (const float*)d_in[9];
  const float* b1  = (const float*)d_in[10];
  const float* W2  = (const float*)d_in[11];
  const float* b2  = (const float*)d_in[12];
  const float* g1  = (const float*)d_in[13];
  const float* be1 = (const float*)d_in[14];
  const float* g2  = (const float*)d_in[15];
  const float* be2 = (const float*)d_in[16];

  float* y_out = (float*)d_out;
  float* attn  = (float*)d_out + (size_t)TOK * D_M;

  // ---- workspace: 80 MB ----
  char* p = (char*)d_ws;
  const size_t MB = 1024 * 1024;
  unsigned short* WqT_h = (unsigned short*)(p + 0 * MB);
  unsigned short* WqT_l = (unsigned short*)(p + 2 * MB);
  unsigned short* WkT_h = (unsigned short*)(p + 4 * MB);
  unsigned short* WkT_l = (unsigned short*)(p + 6 * MB);
  unsigned short* WvT_h = (unsigned short*)(p + 8 * MB);
  unsigned short* WvT_l = (unsigned short*)(p + 10 * MB);
  unsigned short* WoT_h = (unsigned short*)(p + 12 * MB);
  unsigned short* WoT_l = (unsigned short*)(p + 14 * MB);
  unsigned short* xh  = (unsigned short*)(p + 16 * MB);
  unsigned short* xl  = (unsigned short*)(p + 24 * MB);
  unsigned short* qh  = (unsigned short*)(p + 32 * MB);   // 8 MB (hi-only now)
  unsigned short* kh  = (unsigned short*)(p + 48 * MB);   // 8 MB (hi-only now)
  unsigned short* vth = (unsigned short*)(p + 64 * MB);   // 8 MB
  // phase aliases:
  unsigned short* ctxh = (unsigned short*)(p + 16 * MB);  // xh dead after QKV
  unsigned short* ctxl = (unsigned short*)(p + 24 * MB);  // xl dead after QKV
  float* resid = (float*)(p + 32 * MB);                   // qh region dead after attn (16 MB)
  float* x1b   = (float*)(p + 48 * MB);                   // kh region dead after attn (16 MB)
  unsigned short* x1c_h = (unsigned short*)(p + 64 * MB); // vth dead after attn
  unsigned short* x1c_l = (unsigned short*)(p + 72 * MB); // spare
  unsigned short* W1c_h = (unsigned short*)(p + 0 * MB);  // WT dead after Wo gemm
  unsigned short* W1c_l = (unsigned short*)(p + 8 * MB);
  unsigned short* W2c_h = (unsigned short*)(p + 16 * MB); // ctx dead after Wo gemm
  unsigned short* W2c_l = (unsigned short*)(p + 24 * MB);
  float* ffb = (float*)(p + 32 * MB);                     // resid dead after LN1

  const dim3 blk(256);
  const int n4_act = TOK * D_M / 4;   // 1,048,576

  // ---- prep: 4 weight transposes in one launch + x split ----
  transp4_k<<<dim3(16, 16, 4), blk, 0, stream>>>(Wq, Wk, Wv, Wo,
      WqT_h, WqT_l, WkT_h, WkT_l, WvT_h, WvT_l, WoT_h, WoT_l);
  convert_split_k<<<dim3(n4_act / 256), blk, 0, stream>>>(x, xh, xl, n4_act);

  // ---- merged QKV projection (split compute; Q,K emitted hi-only) ----
  qkv_gemm_k<<<dim3(TOK / 64, D_M / 128), blk, 0, stream>>>(
      xh, xl, WqT_h, WqT_l, WkT_h, WkT_l, WvT_h, WvT_l,
      bq, bk, bv, qh, kh, vth);

  // ---- fused attention (hi-only scores, q-tile 128, double-buffered staging) ----
  fused_attn_k<<<dim3(SQ / 128, BB * NH), blk, 0, stream>>>(qh, kh, vth, attn, ctxh, ctxl);

  // ---- Wo projection + LN1 (LN1 emits split x1) ----
  proj_gemm_k<<<dim3(TOK / 64, D_M / 128), blk, 0, stream>>>(
      ctxh, ctxl, WoT_h, WoT_l, bo, resid, TOK, D_M, D_M);
  add_ln_kernel<1><<<dim3(TOK), blk, 0, stream>>>(x, resid, g1, be1, x1b, x1c_h, x1c_l);

  // ---- per-head FF + LN2 ----
  convert_split_k<<<dim3(n4_act / 256), blk, 0, stream>>>(W1, W1c_h, W1c_l, n4_act);
  convert_split_k<<<dim3(n4_act / 256), blk, 0, stream>>>(W2, W2c_h, W2c_l, n4_act);
  ff_split_k<<<dim3(TOK / 128, NH), blk, 0, stream>>>(x1c_h, x1c_l, W1c_h, W1c_l, b1,
                                                      W2c_h, W2c_l, b2, ffb);
  add_ln_kernel<0><<<dim3(TOK), blk, 0, stream>>>(x1b, ffb, g2, be2, y_out, nullptr, nullptr);
}

// Round 11
// 493.176 us; speedup vs baseline: 5.5307x; 1.3386x over previous
//
#include <hip/hip_runtime.h>
#include <cstddef>

#define D_M 1024
#define NH 16
#define HD 64
#define FFD 4096
#define SQ 2048
#define BB 2
#define TOK (BB*SQ)   // 4096
#define EPS 1e-5f

typedef __attribute__((ext_vector_type(8))) short bf16x8;
typedef __attribute__((ext_vector_type(4))) float f32x4;

__device__ inline unsigned short f32_bf16_rne(float f) {
  unsigned int u = __float_as_uint(f);
  unsigned int r = (u + 0x7fffu + ((u >> 16) & 1u)) >> 16;
  return (unsigned short)r;
}

__device__ inline float wave_sum(float v) {
  #pragma unroll
  for (int m = 32; m >= 1; m >>= 1) v += __shfl_xor(v, m);
  return v;
}

// ---------------- fp32 -> bf16 (RNE), vectorized ----------------
__global__ __launch_bounds__(256)
void convert_bf16_k(const float* __restrict__ src, unsigned short* __restrict__ dst, int n4) {
  int i = blockIdx.x * 256 + threadIdx.x;
  if (i >= n4) return;
  float4 v = ((const float4*)src)[i];
  ushort4 h;
  h.x = f32_bf16_rne(v.x); h.y = f32_bf16_rne(v.y);
  h.z = f32_bf16_rne(v.z); h.w = f32_bf16_rne(v.w);
  ((ushort4*)dst)[i] = h;
}

// ---------------- 4x W[1024][1024] fp32 -> WT bf16 [N][K], one launch ----------------
__global__ __launch_bounds__(256)
void transp4_k(const float* __restrict__ W0, const float* __restrict__ W1_,
               const float* __restrict__ W2_, const float* __restrict__ W3,
               unsigned short* __restrict__ h0, unsigned short* __restrict__ h1,
               unsigned short* __restrict__ h2, unsigned short* __restrict__ h3) {
  const float* W; unsigned short* hT;
  switch (blockIdx.z) {
    case 0: W = W0; hT = h0; break;
    case 1: W = W1_; hT = h1; break;
    case 2: W = W2_; hT = h2; break;
    default: W = W3; hT = h3; break;
  }
  __shared__ float tile[64][65];
  const int bn = blockIdx.x * 64;
  const int bk = blockIdx.y * 64;
  const int t = threadIdx.x;
  #pragma unroll
  for (int i = 0; i < 4; ++i) {
    int r = (t >> 4) + i * 16, c = (t & 15) * 4;
    float4 v = *(const float4*)&W[(size_t)(bk + r) * D_M + bn + c];
    tile[r][c] = v.x; tile[r][c + 1] = v.y; tile[r][c + 2] = v.z; tile[r][c + 3] = v.w;
  }
  __syncthreads();
  #pragma unroll
  for (int i = 0; i < 4; ++i) {
    int n = (t >> 4) + i * 16, k = (t & 15) * 4;
    ushort4 h;
    h.x = f32_bf16_rne(tile[k][n]);     h.y = f32_bf16_rne(tile[k + 1][n]);
    h.z = f32_bf16_rne(tile[k + 2][n]); h.w = f32_bf16_rne(tile[k + 3][n]);
    *(ushort4*)&hT[(size_t)(bn + n) * D_M + bk + k] = h;
  }
}

// ---------------- merged QKV GEMM, bf16 hi-only, one A-tile for 3 weight sets ----------------
// grid: (panel = N/128, mblock = TOK/64) -> panel pinned per-XCD
__global__ __launch_bounds__(256)
void qkv_gemm_k(const unsigned short* __restrict__ xh_g,
                const unsigned short* __restrict__ Bqh, const unsigned short* __restrict__ Bkh,
                const unsigned short* __restrict__ Bvh,
                const float* __restrict__ bq, const float* __restrict__ bk, const float* __restrict__ bv,
                unsigned short* __restrict__ qh, unsigned short* __restrict__ kh,
                unsigned short* __restrict__ vth) {
  constexpr int LDK = 40;
  __shared__ unsigned short Ah[64 * LDK];
  __shared__ unsigned short Bh[3][128 * LDK];
  const int tid = threadIdx.x;
  const int wave = tid >> 6, lane = tid & 63;
  const int wm = (wave >> 1) * 32, wn = (wave & 1) * 64;
  const int bn = blockIdx.x * 128, bm = blockIdx.y * 64;
  const int K = D_M;

  f32x4 acc[3][2][4] = {};
  const int sr = tid >> 2, sk = (tid & 3) * 8;
  const int l15 = lane & 15, k8 = (lane >> 4) * 8;

  const unsigned short* Bhp[3] = {Bqh, Bkh, Bvh};

  for (int k0 = 0; k0 < K; k0 += 32) {
    *(uint4*)&Ah[sr * LDK + sk] = *(const uint4*)&xh_g[(size_t)(bm + sr) * K + k0 + sk];
    #pragma unroll
    for (int s = 0; s < 3; ++s) {
      #pragma unroll
      for (int c = 0; c < 2; ++c) {
        int r = sr + c * 64;
        *(uint4*)&Bh[s][r * LDK + sk] = *(const uint4*)&Bhp[s][(size_t)(bn + r) * K + k0 + sk];
      }
    }
    __syncthreads();
    bf16x8 af[2];
    #pragma unroll
    for (int m = 0; m < 2; ++m)
      af[m] = *(bf16x8*)&Ah[(wm + m * 16 + l15) * LDK + k8];
    #pragma unroll
    for (int s = 0; s < 3; ++s) {
      #pragma unroll
      for (int n = 0; n < 4; ++n) {
        bf16x8 b0 = *(bf16x8*)&Bh[s][(wn + n * 16 + l15) * LDK + k8];
        #pragma unroll
        for (int m = 0; m < 2; ++m) {
          if (s == 2) {  // V: unswapped (D col = weight col, rows = token)
            acc[s][m][n] = __builtin_amdgcn_mfma_f32_16x16x32_bf16(af[m], b0, acc[s][m][n], 0, 0, 0);
          } else {       // Q,K: swapped (D col = token, rows = weight col)
            acc[s][m][n] = __builtin_amdgcn_mfma_f32_16x16x32_bf16(b0, af[m], acc[s][m][n], 0, 0, 0);
          }
        }
      }
    }
    __syncthreads();
  }
  const int kq4 = (lane >> 4) * 4;
  // Q, K epilogues (swapped layout, vectorized bf16 stores)
  #pragma unroll
  for (int s = 0; s < 2; ++s) {
    const float* bias = (s == 0) ? bq : bk;
    unsigned short* oh = (s == 0) ? qh : kh;
    #pragma unroll
    for (int n = 0; n < 4; ++n) {
      int colb = bn + wn + n * 16 + kq4;
      float4 bv4 = *(const float4*)&bias[colb];
      #pragma unroll
      for (int m = 0; m < 2; ++m) {
        int tok = bm + wm + m * 16 + l15;
        ushort4 h;
        h.x = f32_bf16_rne(acc[s][m][n][0] + bv4.x);
        h.y = f32_bf16_rne(acc[s][m][n][1] + bv4.y);
        h.z = f32_bf16_rne(acc[s][m][n][2] + bv4.z);
        h.w = f32_bf16_rne(acc[s][m][n][3] + bv4.w);
        *(ushort4*)&oh[(size_t)tok * D_M + colb] = h;
      }
    }
  }
  // V epilogue (unswapped, transposed store [b][h][d][s])
  #pragma unroll
  for (int n = 0; n < 4; ++n) {
    int col = bn + wn + n * 16 + l15;
    float bvv = bv[col];
    #pragma unroll
    for (int m = 0; m < 2; ++m) {
      int row0 = bm + wm + m * 16 + kq4;
      ushort4 hv;
      hv.x = f32_bf16_rne(acc[2][m][n][0] + bvv); hv.y = f32_bf16_rne(acc[2][m][n][1] + bvv);
      hv.z = f32_bf16_rne(acc[2][m][n][2] + bvv); hv.w = f32_bf16_rne(acc[2][m][n][3] + bvv);
      size_t idx = (((size_t)(row0 >> 11) * NH + (col >> 6)) * HD + (col & 63)) * SQ + (row0 & 2047);
      *(ushort4*)&vth[idx] = hv;
    }
  }
}

// ------- projection GEMM (Wo), bf16 hi-only, swapped MFMA, C fp32 -------
// grid: (panel = N/128, mblock = M/64)
__global__ __launch_bounds__(256)
void proj_gemm_k(const unsigned short* __restrict__ Ah_g,
                 const unsigned short* __restrict__ Bh_g,
                 const float* __restrict__ bias, float* __restrict__ C,
                 int M, int N, int K) {
  constexpr int LDK = 40;
  __shared__ unsigned short Ah[64 * LDK];
  __shared__ unsigned short Bh[128 * LDK];
  const int tid = threadIdx.x;
  const int wave = tid >> 6, lane = tid & 63;
  const int wm = (wave >> 1) * 32, wn = (wave & 1) * 64;
  const int bn = blockIdx.x * 128, bm = blockIdx.y * 64;

  f32x4 acc[2][4] = {};
  const int sr = tid >> 2, sk = (tid & 3) * 8;
  const int l15 = lane & 15, k8 = (lane >> 4) * 8;

  for (int k0 = 0; k0 < K; k0 += 32) {
    *(uint4*)&Ah[sr * LDK + sk] = *(const uint4*)&Ah_g[(size_t)(bm + sr) * K + k0 + sk];
    #pragma unroll
    for (int c = 0; c < 2; ++c) {
      int r = sr + c * 64;
      *(uint4*)&Bh[r * LDK + sk] = *(const uint4*)&Bh_g[(size_t)(bn + r) * K + k0 + sk];
    }
    __syncthreads();
    bf16x8 af[2], bfr[4];
    #pragma unroll
    for (int m = 0; m < 2; ++m)
      af[m] = *(bf16x8*)&Ah[(wm + m * 16 + l15) * LDK + k8];
    #pragma unroll
    for (int n = 0; n < 4; ++n)
      bfr[n] = *(bf16x8*)&Bh[(wn + n * 16 + l15) * LDK + k8];
    #pragma unroll
    for (int m = 0; m < 2; ++m)
      #pragma unroll
      for (int n = 0; n < 4; ++n)
        acc[m][n] = __builtin_amdgcn_mfma_f32_16x16x32_bf16(bfr[n], af[m], acc[m][n], 0, 0, 0);
    __syncthreads();
  }
  const int kq4 = (lane >> 4) * 4;
  #pragma unroll
  for (int n = 0; n < 4; ++n) {
    int colb = bn + wn + n * 16 + kq4;
    float4 bv4 = *(const float4*)&bias[colb];
    #pragma unroll
    for (int m = 0; m < 2; ++m) {
      int tok = bm + wm + m * 16 + l15;
      float4 v = {acc[m][n][0] + bv4.x, acc[m][n][1] + bv4.y,
                  acc[m][n][2] + bv4.z, acc[m][n][3] + bv4.w};
      *(float4*)&C[(size_t)tok * N + colb] = v;
    }
  }
}

// ---------------- fused attention, bf16 scores, q-tile 128, double-buffered K/V ----------------
// grid: (bh, q-tile) -> bh pinned per-XCD (K/V L2-resident)
__global__ __launch_bounds__(256)
void fused_attn_k(const unsigned short* __restrict__ qh,
                  const unsigned short* __restrict__ kh,
                  const unsigned short* __restrict__ vth,
                  float* __restrict__ attn,
                  unsigned short* __restrict__ ctxh) {
  constexpr int LDK = 72;
  constexpr int NT = SQ / 64;
  __shared__ unsigned short Kth[2][64 * LDK], Vts[2][64 * LDK];
  __shared__ unsigned short Ph[128 * LDK];
  const int tid = threadIdx.x, wave = tid >> 6, lane = tid & 63;
  const int l15 = lane & 15, kq = lane >> 4;
  const int bh = blockIdx.x, b = bh >> 4;
  const int h = bh & 15;
  const int q0 = blockIdx.y * 128;

  bf16x8 qfh[2][2];
  #pragma unroll
  for (int qi = 0; qi < 2; ++qi) {
    const size_t qoff = (size_t)(b * SQ + q0 + wave * 32 + qi * 16 + l15) * D_M + h * HD + kq * 8;
    qfh[qi][0] = *(const bf16x8*)&qh[qoff];  qfh[qi][1] = *(const bf16x8*)&qh[qoff + 32];
  }

  const size_t kbase = (size_t)(b * SQ) * D_M + h * HD;
  const size_t vbase = (size_t)bh * HD * SQ;
  const int srow = tid >> 2, sc = (tid & 3) * 16;

  // ---------- pass A: per-q row sums (max term cancels with m == 0) ----------
  float lsum[2] = {0.f, 0.f};
  {
    const unsigned short* src = &kh[kbase + (size_t)srow * D_M + sc];
    *(uint4*)&Kth[0][srow * LDK + sc] = *(const uint4*)src;
    *(uint4*)&Kth[0][srow * LDK + sc + 8] = *(const uint4*)(src + 8);
  }
  __syncthreads();
  for (int t = 0; t < NT; ++t) {
    const int cur = t & 1;
    const bool pf = (t + 1 < NT);
    uint4 r0, r1;
    if (pf) {
      const unsigned short* src = &kh[kbase + (size_t)((t + 1) * 64 + srow) * D_M + sc];
      r0 = *(const uint4*)src;
      r1 = *(const uint4*)(src + 8);
    }
    #pragma unroll
    for (int n = 0; n < 4; ++n) {
      bf16x8 kb0 = *(bf16x8*)&Kth[cur][(n * 16 + l15) * LDK + kq * 8];
      bf16x8 kb1 = *(bf16x8*)&Kth[cur][(n * 16 + l15) * LDK + 32 + kq * 8];
      #pragma unroll
      for (int qi = 0; qi < 2; ++qi) {
        f32x4 s = {};
        s = __builtin_amdgcn_mfma_f32_16x16x32_bf16(kb0, qfh[qi][0], s, 0, 0, 0);
        s = __builtin_amdgcn_mfma_f32_16x16x32_bf16(kb1, qfh[qi][1], s, 0, 0, 0);
        #pragma unroll
        for (int r = 0; r < 4; ++r) lsum[qi] += __expf(s[r] * 0.125f);
      }
    }
    if (pf) {
      *(uint4*)&Kth[cur ^ 1][srow * LDK + sc] = r0;
      *(uint4*)&Kth[cur ^ 1][srow * LDK + sc + 8] = r1;
    }
    __syncthreads();
  }
  float invl[2];
  #pragma unroll
  for (int qi = 0; qi < 2; ++qi) {
    float l = lsum[qi];
    l += __shfl_xor(l, 16);
    l += __shfl_xor(l, 32);
    invl[qi] = 1.0f / l;
  }

  // ---------- pass B: scores, attn write, PV ----------
  f32x4 cacc[2][4] = {};
  {
    const unsigned short* srch = &kh[kbase + (size_t)srow * D_M + sc];
    const unsigned short* srcv = &vth[vbase + (size_t)srow * SQ + sc];
    *(uint4*)&Kth[0][srow * LDK + sc] = *(const uint4*)srch;
    *(uint4*)&Kth[0][srow * LDK + sc + 8] = *(const uint4*)(srch + 8);
    *(uint4*)&Vts[0][srow * LDK + sc] = *(const uint4*)srcv;
    *(uint4*)&Vts[0][srow * LDK + sc + 8] = *(const uint4*)(srcv + 8);
  }
  __syncthreads();
  for (int t = 0; t < NT; ++t) {
    const int cur = t & 1;
    const int k0 = t * 64;
    const bool pf = (t + 1 < NT);
    uint4 rk0, rk1, rv0, rv1;
    if (pf) {
      const unsigned short* srch = &kh[kbase + (size_t)(k0 + 64 + srow) * D_M + sc];
      const unsigned short* srcv = &vth[vbase + (size_t)srow * SQ + k0 + 64 + sc];
      rk0 = *(const uint4*)srch; rk1 = *(const uint4*)(srch + 8);
      rv0 = *(const uint4*)srcv; rv1 = *(const uint4*)(srcv + 8);
    }
    #pragma unroll
    for (int n = 0; n < 4; ++n) {
      bf16x8 kb0 = *(bf16x8*)&Kth[cur][(n * 16 + l15) * LDK + kq * 8];
      bf16x8 kb1 = *(bf16x8*)&Kth[cur][(n * 16 + l15) * LDK + 32 + kq * 8];
      #pragma unroll
      for (int qi = 0; qi < 2; ++qi) {
        f32x4 s = {};
        s = __builtin_amdgcn_mfma_f32_16x16x32_bf16(kb0, qfh[qi][0], s, 0, 0, 0);
        s = __builtin_amdgcn_mfma_f32_16x16x32_bf16(kb1, qfh[qi][1], s, 0, 0, 0);
        float4 pv;
        pv.x = __expf(s[0] * 0.125f) * invl[qi];
        pv.y = __expf(s[1] * 0.125f) * invl[qi];
        pv.z = __expf(s[2] * 0.125f) * invl[qi];
        pv.w = __expf(s[3] * 0.125f) * invl[qi];
        const int qrow = wave * 32 + qi * 16 + l15;
        *(float4*)&attn[((size_t)bh * SQ + q0 + qrow) * SQ + k0 + n * 16 + kq * 4] = pv;
        ushort4 p4;
        p4.x = f32_bf16_rne(pv.x); p4.y = f32_bf16_rne(pv.y);
        p4.z = f32_bf16_rne(pv.z); p4.w = f32_bf16_rne(pv.w);
        *(ushort4*)&Ph[qrow * LDK + n * 16 + kq * 4] = p4;
      }
    }
    __syncthreads();
    #pragma unroll
    for (int qi = 0; qi < 2; ++qi) {
      bf16x8 pa0 = *(bf16x8*)&Ph[(wave * 32 + qi * 16 + l15) * LDK + kq * 8];
      bf16x8 pa1 = *(bf16x8*)&Ph[(wave * 32 + qi * 16 + l15) * LDK + 32 + kq * 8];
      #pragma unroll
      for (int n = 0; n < 4; ++n) {
        bf16x8 vb0 = *(bf16x8*)&Vts[cur][(n * 16 + l15) * LDK + kq * 8];
        bf16x8 vb1 = *(bf16x8*)&Vts[cur][(n * 16 + l15) * LDK + 32 + kq * 8];
        cacc[qi][n] = __builtin_amdgcn_mfma_f32_16x16x32_bf16(vb0, pa0, cacc[qi][n], 0, 0, 0);
        cacc[qi][n] = __builtin_amdgcn_mfma_f32_16x16x32_bf16(vb1, pa1, cacc[qi][n], 0, 0, 0);
      }
    }
    if (pf) {
      *(uint4*)&Kth[cur ^ 1][srow * LDK + sc] = rk0;
      *(uint4*)&Kth[cur ^ 1][srow * LDK + sc + 8] = rk1;
      *(uint4*)&Vts[cur ^ 1][srow * LDK + sc] = rv0;
      *(uint4*)&Vts[cur ^ 1][srow * LDK + sc + 8] = rv1;
    }
    __syncthreads();
  }
  // ctx epilogue: q = q0 + wave*32 + qi*16 + l15, d = n*16 + kq*4 + r (bf16 hi-only)
  #pragma unroll
  for (int qi = 0; qi < 2; ++qi)
    #pragma unroll
    for (int n = 0; n < 4; ++n) {
      ushort4 hh;
      hh.x = f32_bf16_rne(cacc[qi][n][0]); hh.y = f32_bf16_rne(cacc[qi][n][1]);
      hh.z = f32_bf16_rne(cacc[qi][n][2]); hh.w = f32_bf16_rne(cacc[qi][n][3]);
      size_t off = (size_t)(b * SQ + q0 + wave * 32 + qi * 16 + l15) * D_M + h * HD + n * 16 + kq * 4;
      *(ushort4*)&ctxh[off] = hh;
    }
}

// ---------------- per-head FF, bf16 hi-only, reg-staged W (issue-early/write-late) ----------------
// grid: (head, mblock) -> head pinned per-XCD (weights L2-resident)
__global__ __launch_bounds__(256)
void ff_bf16_k(const unsigned short* __restrict__ x1h,
               const unsigned short* __restrict__ W1h_, const float* __restrict__ b1,
               const unsigned short* __restrict__ W2h_, const float* __restrict__ b2,
               float* __restrict__ out) {
  constexpr int LDW = 72;
  constexpr int LDH = 40;
  __shared__ unsigned short W1sh[2][32 * LDW];
  __shared__ unsigned short W2sh[2][64 * LDH];
  __shared__ unsigned short Hh[128 * LDH];

  const int tid = threadIdx.x;
  const int wave = tid >> 6, lane = tid & 63;
  const int wm = wave >> 1, wf = wave & 1, wd = wave & 1;
  const int h = blockIdx.x;
  const int m0 = blockIdx.y * 128;
  const int l15 = lane & 15, kq = lane >> 4;

  const size_t w1base = (size_t)h * FFD * HD;
  const size_t w2base = (size_t)h * HD * FFD;
  const int r1 = tid >> 3, k1 = (tid & 7) * 8;
  const int r2 = tid >> 2, f2 = (tid & 3) * 8;

  bf16x8 xf[4][2];
  #pragma unroll
  for (int m = 0; m < 4; ++m)
    #pragma unroll
    for (int ks = 0; ks < 2; ++ks) {
      size_t gof = (size_t)(m0 + wm * 64 + m * 16 + l15) * D_M + h * HD + ks * 32 + kq * 8;
      xf[m][ks] = *(const bf16x8*)&x1h[gof];
    }

  {
    *(uint4*)&W1sh[0][r1 * LDW + k1] = *(const uint4*)&W1h_[w1base + (size_t)r1 * HD + k1];
    *(uint4*)&W2sh[0][r2 * LDH + f2] = *(const uint4*)&W2h_[w2base + (size_t)r2 * FFD + f2];
  }
  __syncthreads();

  f32x4 ffacc[4][2] = {};

  for (int ch = 0; ch < FFD / 32; ++ch) {
    const int buf = ch & 1;
    const bool pf = (ch + 1 < FFD / 32);
    uint4 w1h_r, w2h_r;
    if (pf) {
      const int f0n = (ch + 1) * 32;
      w1h_r = *(const uint4*)&W1h_[w1base + (size_t)(f0n + r1) * HD + k1];
      w2h_r = *(const uint4*)&W2h_[w2base + (size_t)r2 * FFD + f0n + f2];
    }
    // phase 1 (swapped): hacc[m] col = token (l15), rows = f (kq*4+r)
    f32x4 hacc[4] = {};
    #pragma unroll
    for (int ks = 0; ks < 2; ++ks) {
      bf16x8 w1h = *(bf16x8*)&W1sh[buf][(wf * 16 + l15) * LDW + ks * 32 + kq * 8];
      #pragma unroll
      for (int m = 0; m < 4; ++m)
        hacc[m] = __builtin_amdgcn_mfma_f32_16x16x32_bf16(w1h, xf[m][ks], hacc[m], 0, 0, 0);
    }
    // bias + relu -> H bf16 (vectorized)
    {
      const int fb = wf * 16 + kq * 4;
      float4 b1v = *(const float4*)&b1[(size_t)h * FFD + ch * 32 + fb];
      const float bb[4] = {b1v.x, b1v.y, b1v.z, b1v.w};
      #pragma unroll
      for (int m = 0; m < 4; ++m) {
        int tok = wm * 64 + m * 16 + l15;
        ushort4 hh;
        hh.x = f32_bf16_rne(fmaxf(hacc[m][0] + bb[0], 0.0f));
        hh.y = f32_bf16_rne(fmaxf(hacc[m][1] + bb[1], 0.0f));
        hh.z = f32_bf16_rne(fmaxf(hacc[m][2] + bb[2], 0.0f));
        hh.w = f32_bf16_rne(fmaxf(hacc[m][3] + bb[3], 0.0f));
        *(ushort4*)&Hh[tok * LDH + fb] = hh;
      }
    }
    __syncthreads();
    bf16x8 hfr[4];
    #pragma unroll
    for (int m = 0; m < 4; ++m)
      hfr[m] = *(bf16x8*)&Hh[(wm * 64 + m * 16 + l15) * LDH + kq * 8];
    // phase 2 (swapped): ffacc col = token, rows = d
    #pragma unroll
    for (int n = 0; n < 2; ++n) {
      bf16x8 w2h = *(bf16x8*)&W2sh[buf][(wd * 32 + n * 16 + l15) * LDH + kq * 8];
      #pragma unroll
      for (int m = 0; m < 4; ++m)
        ffacc[m][n] = __builtin_amdgcn_mfma_f32_16x16x32_bf16(w2h, hfr[m], ffacc[m][n], 0, 0, 0);
    }
    // write-late: park next W tiles into buf^1 after compute
    if (pf) {
      *(uint4*)&W1sh[buf ^ 1][r1 * LDW + k1] = w1h_r;
      *(uint4*)&W2sh[buf ^ 1][r2 * LDH + f2] = w2h_r;
    }
    __syncthreads();
  }
  // epilogue: vectorized float4 stores
  #pragma unroll
  for (int n = 0; n < 2; ++n) {
    int db = wd * 32 + n * 16 + kq * 4;
    float4 b2v = *(const float4*)&b2[(size_t)h * HD + db];
    #pragma unroll
    for (int m = 0; m < 4; ++m) {
      int tok = m0 + wm * 64 + m * 16 + l15;
      float4 v = {ffacc[m][n][0] + b2v.x, ffacc[m][n][1] + b2v.y,
                  ffacc[m][n][2] + b2v.z, ffacc[m][n][3] + b2v.w};
      *(float4*)&out[(size_t)tok * D_M + h * HD + db] = v;
    }
  }
}

// ---------------- out = LayerNorm(a + r) * g + be (optionally + bf16 out) ----------------
template<int BF16OUT>
__global__ __launch_bounds__(256)
void add_ln_kernel(const float* __restrict__ a, const float* __restrict__ r,
                   const float* __restrict__ g, const float* __restrict__ be,
                   float* __restrict__ out, unsigned short* __restrict__ oh) {
  const size_t row = blockIdx.x;
  const int tid = threadIdx.x;
  __shared__ float red1[4];
  __shared__ float red2[4];
  float4 va = ((const float4*)(a + row * D_M))[tid];
  float4 vr = ((const float4*)(r + row * D_M))[tid];
  float v0 = va.x + vr.x, v1 = va.y + vr.y, v2 = va.z + vr.z, v3 = va.w + vr.w;
  float s = v0 + v1 + v2 + v3;
  float sq = v0 * v0 + v1 * v1 + v2 * v2 + v3 * v3;
  s = wave_sum(s);
  sq = wave_sum(sq);
  if ((tid & 63) == 0) { red1[tid >> 6] = s; red2[tid >> 6] = sq; }
  __syncthreads();
  s = red1[0] + red1[1] + red1[2] + red1[3];
  sq = red2[0] + red2[1] + red2[2] + red2[3];
  const float mu = s * (1.0f / D_M);
  const float var = sq * (1.0f / D_M) - mu * mu;
  float x = var + EPS;
  float rs = rsqrtf(x);
  rs = rs * (1.5f - 0.5f * x * rs * rs);
  float4 gg = ((const float4*)g)[tid];
  float4 bb = ((const float4*)be)[tid];
  float4 o = {(v0 - mu) * rs * gg.x + bb.x, (v1 - mu) * rs * gg.y + bb.y,
              (v2 - mu) * rs * gg.z + bb.z, (v3 - mu) * rs * gg.w + bb.w};
  ((float4*)(out + row * D_M))[tid] = o;
  if (BF16OUT) {
    ushort4 h;
    h.x = f32_bf16_rne(o.x); h.y = f32_bf16_rne(o.y);
    h.z = f32_bf16_rne(o.z); h.w = f32_bf16_rne(o.w);
    ((ushort4*)(oh + row * D_M))[tid] = h;
  }
}

extern "C" void kernel_launch(void* const* d_in, const int* in_sizes, int n_in,
                              void* d_out, int out_size, void* d_ws, size_t ws_size,
                              hipStream_t stream) {
  const float* x   = (const float*)d_in[0];
  const float* Wq  = (const float*)d_in[1];
  const float* bq  = (const float*)d_in[2];
  const float* Wk  = (const float*)d_in[3];
  const float* bk  = (const float*)d_in[4];
  const float* Wv  = (const float*)d_in[5];
  const float* bv  = (const float*)d_in[6];
  const float* Wo  = (const float*)d_in[7];
  const float* bo  = (const float*)d_in[8];
  const float* W1  = (const float*)d_in[9];
  const float* b1  = (const float*)d_in[10];
  const float* W2  = (const float*)d_in[11];
  const float* b2  = (const float*)d_in[12];
  const float* g1  = (const float*)d_in[13];
  const float* be1 = (const float*)d_in[14];
  const float* g2  = (const float*)d_in[15];
  const float* be2 = (const float*)d_in[16];

  float* y_out = (float*)d_out;
  float* attn  = (float*)d_out + (size_t)TOK * D_M;

  // ---- workspace: 80 MB ----
  char* p = (char*)d_ws;
  const size_t MB = 1024 * 1024;
  unsigned short* WqT = (unsigned short*)(p + 0 * MB);    // 2 MB each
  unsigned short* WkT = (unsigned short*)(p + 2 * MB);
  unsigned short* WvT = (unsigned short*)(p + 4 * MB);
  unsigned short* WoT = (unsigned short*)(p + 6 * MB);
  unsigned short* xh  = (unsigned short*)(p + 8 * MB);    // 8 MB
  unsigned short* qh  = (unsigned short*)(p + 16 * MB);   // 8 MB
  unsigned short* kh  = (unsigned short*)(p + 24 * MB);   // 8 MB
  unsigned short* vth = (unsigned short*)(p + 32 * MB);   // 8 MB
  unsigned short* ctxh = (unsigned short*)(p + 40 * MB);  // 8 MB
  float* resid = (float*)(p + 48 * MB);                   // 16 MB
  float* x1b   = (float*)(p + 64 * MB);                   // 16 MB
  // phase aliases (after attention / Wo):
  unsigned short* x1c_h = (unsigned short*)(p + 8 * MB);  // xh dead after QKV
  unsigned short* W1c_h = (unsigned short*)(p + 16 * MB); // qh dead after attn
  unsigned short* W2c_h = (unsigned short*)(p + 24 * MB); // kh dead after attn
  float* ffb = (float*)(p + 32 * MB);                     // vth+ctxh dead after Wo gemm (16 MB)

  const dim3 blk(256);
  const int n4_act = TOK * D_M / 4;   // 1,048,576

  // ---- prep: 4 weight transposes (bf16) + x convert ----
  transp4_k<<<dim3(16, 16, 4), blk, 0, stream>>>(Wq, Wk, Wv, Wo, WqT, WkT, WvT, WoT);
  convert_bf16_k<<<dim3(n4_act / 256), blk, 0, stream>>>(x, xh, n4_act);

  // ---- merged QKV projection (bf16), panel-pinned grid ----
  qkv_gemm_k<<<dim3(D_M / 128, TOK / 64), blk, 0, stream>>>(
      xh, WqT, WkT, WvT, bq, bk, bv, qh, kh, vth);

  // ---- fused attention (bh-pinned grid) ----
  fused_attn_k<<<dim3(BB * NH, SQ / 128), blk, 0, stream>>>(qh, kh, vth, attn, ctxh);

  // ---- Wo projection + LN1 (LN1 emits bf16 x1) ----
  proj_gemm_k<<<dim3(D_M / 128, TOK / 64), blk, 0, stream>>>(
      ctxh, WoT, bo, resid, TOK, D_M, D_M);
  add_ln_kernel<1><<<dim3(TOK), blk, 0, stream>>>(x, resid, g1, be1, x1b, x1c_h);

  // ---- per-head FF (head-pinned grid) + LN2 ----
  convert_bf16_k<<<dim3(n4_act / 256), blk, 0, stream>>>(W1, W1c_h, n4_act);
  convert_bf16_k<<<dim3(n4_act / 256), blk, 0, stream>>>(W2, W2c_h, n4_act);
  ff_bf16_k<<<dim3(NH, TOK / 128), blk, 0, stream>>>(x1c_h, W1c_h, b1, W2c_h, b2, ffb);
  add_ln_kernel<0><<<dim3(TOK), blk, 0, stream>>>(x1b, ffb, g2, be2, y_out, nullptr);
}